// Round 15
// baseline (201.471 us; speedup 1.0000x reference)
//
#include <hip/hip_runtime.h>
#include <hip/hip_bf16.h>
#include <math.h>

#define N_TOK 8192
#define DIM 1024
#define NEXP 16
#define CAP 1280
#define FDIM 512
#define NROUTE (N_TOK * 2)
#define NCHUNK 64
#define ECAP (NEXP * CAP)        /* 20480 */
#define TOTROW (ECAP + N_TOK)    /* 28672 */

typedef __hip_bfloat16 bf16;
typedef unsigned short ushort_t;
typedef __attribute__((ext_vector_type(8))) short bf16x8;
typedef __attribute__((ext_vector_type(4))) float f32x4;

// tanh-approx gelu via sigmoid; |err| vs erf-gelu ~1e-3 << tolerance.
__device__ __forceinline__ float gelu_fast(float x) {
    float u = 1.5957691216057308f * (x + 0.044715f * x * x * x);
    return x / (1.f + __expf(-u));
}

__device__ __forceinline__ float bf2f(unsigned short u) {
    union { float f; unsigned int i; } v; v.i = ((unsigned int)u) << 16; return v.f;
}

__device__ __forceinline__ unsigned short f2b(float f) {
    union { __hip_bfloat16 h; unsigned short u; } v;
    v.h = __float2bfloat16(f);
    return v.u;
}

__device__ __forceinline__ void gload16(const void* g, void* l) {
    __builtin_amdgcn_global_load_lds(
        (const __attribute__((address_space(1))) unsigned int*)g,
        (__attribute__((address_space(3))) unsigned int*)l,
        16, 0, 0);
}

// T2 both-sides swizzle (verified: SQ_LDS_BANK_CONFLICT -> 0, rounds 5-14)
__device__ __forceinline__ int swz_addr16(int r, int q) {
    return ((r >> 1) << 3) + ((r & 1) << 2) + (q ^ ((r >> 1) & 3));
}

// ---------------- gather expert rows from bf16 copy ----------------
__global__ __launch_bounds__(256) void gather_x_kernel(
    const ushort_t* __restrict__ x_bf, const int* __restrict__ slot_token,
    const int* __restrict__ counts_cap, ushort_t* __restrict__ xg)
{
    int row = blockIdx.x;            // [0, ECAP)
    int e = row / CAP;
    int pos = row - e * CAP;
    int tok = (pos < counts_cap[e]) ? slot_token[row] : 0;
    if ((unsigned)tok >= N_TOK) tok = 0;   // poison guard (gate==0 slots)
    int c = threadIdx.x * 4;
    ushort4 v = *reinterpret_cast<const ushort4*>(x_bf + (size_t)tok * DIM + c);
    *reinterpret_cast<ushort4*>(xg + (size_t)row * DIM + c) = v;
}

// ---------------- transpose+convert weights: fp32 [K][N] -> bf16 [N][K] ----------------
__global__ __launch_bounds__(256) void transpose_w_kernel(
    const float* __restrict__ w1, const float* __restrict__ w2,
    const float* __restrict__ sw1, const float* __restrict__ sw2,
    ushort_t* __restrict__ w1t, ushort_t* __restrict__ w2t,
    ushort_t* __restrict__ sw1t, ushort_t* __restrict__ sw2t)
{
    __shared__ float tileT[64][65];   // [n][k]
    int bx = blockIdx.x;
    const float* src; ushort_t* dst; int K, N, kt, nt;
    if (bx < 2048) {                      // w1: per-expert [1024][512]
        int e = bx >> 7, r = bx & 127;
        K = 1024; N = 512; kt = r >> 3; nt = r & 7;
        src = w1 + (size_t)e * K * N; dst = w1t + (size_t)e * K * N;
    } else if (bx < 4096) {               // w2: per-expert [512][1024]
        int b2 = bx - 2048, e = b2 >> 7, r = b2 & 127;
        K = 512; N = 1024; kt = r >> 4; nt = r & 15;
        src = w2 + (size_t)e * K * N; dst = w2t + (size_t)e * K * N;
    } else if (bx < 4224) {               // sw1 [1024][512]
        int r = bx - 4096;
        K = 1024; N = 512; kt = r >> 3; nt = r & 7;
        src = sw1; dst = sw1t;
    } else {                              // sw2 [512][1024]
        int r = bx - 4224;
        K = 512; N = 1024; kt = r >> 4; nt = r & 15;
        src = sw2; dst = sw2t;
    }
    int t = threadIdx.x;
    int tr = t >> 4;
    int tc = (t & 15) * 4;
#pragma unroll
    for (int i = 0; i < 4; ++i) {
        int k = kt * 64 + i * 16 + tr;
        float4 v = *reinterpret_cast<const float4*>(src + (size_t)k * N + nt * 64 + tc);
        tileT[tc + 0][i * 16 + tr] = v.x;
        tileT[tc + 1][i * 16 + tr] = v.y;
        tileT[tc + 2][i * 16 + tr] = v.z;
        tileT[tc + 3][i * 16 + tr] = v.w;
    }
    __syncthreads();
    int wr = t >> 3;
    int wc = (t & 7) * 8;
#pragma unroll
    for (int i = 0; i < 2; ++i) {
        int n = wr + i * 32;
        bf16x8 o;
#pragma unroll
        for (int j = 0; j < 8; ++j) o[j] = (short)f2b(tileT[n][wc + j]);
        *reinterpret_cast<bf16x8*>(dst + (size_t)(nt * 64 + n) * K + kt * 64 + wc) = o;
    }
}

// ---------------- router v5: expert-vectorized, d-split across 4 waves ----------------
__global__ __launch_bounds__(256) void router_kernel(
    const float* __restrict__ x, const float* __restrict__ rw,
    const float* __restrict__ sgw,
    float* __restrict__ scores,
    int* __restrict__ topk_idx,
    float* __restrict__ topk_val,
    float* __restrict__ g_shared,
    ushort_t* __restrict__ x_bf)
{
    __shared__ float lds_acc[4][16][4][4];   // [wave][tok][e4][4]
    __shared__ float lds_g[4][16];           // [wave][tok]

    int tid = threadIdx.x;
    int w = tid >> 6;
    int lane = tid & 63;
    int tok0 = blockIdx.x * 16;

    // ---- pass 1: x_bf conversion + shared-gate partials (coalesced) ----
    {
        int dq = w * 256 + lane * 4;
        float4 gv = *reinterpret_cast<const float4*>(sgw + dq);
#pragma unroll 4
        for (int tt = 0; tt < 16; ++tt) {
            const float* xr = x + (size_t)(tok0 + tt) * DIM + dq;
            float4 xv = *reinterpret_cast<const float4*>(xr);
            ushort4 o;
            o.x = f2b(xv.x); o.y = f2b(xv.y); o.z = f2b(xv.z); o.w = f2b(xv.w);
            *reinterpret_cast<ushort4*>(x_bf + (size_t)(tok0 + tt) * DIM + dq) = o;
            float dg = xv.x * gv.x + xv.y * gv.y + xv.z * gv.z + xv.w * gv.w;
#pragma unroll
            for (int m = 1; m < 64; m <<= 1) dg += __shfl_xor(dg, m, 64);
            if (lane == 0) lds_g[w][tt] = dg;
        }
    }

    // ---- pass 2: logits (4 experts per lane, float4 rw loads) ----
    int tok = lane >> 2;
    int e4 = lane & 3;
    int token = tok0 + tok;
    {
        const float* xr = x + (size_t)token * DIM + w * 256;
        const float* rwb = rw + (size_t)(w * 256) * NEXP + e4 * 4;
        float4 a0 = {0,0,0,0}, a1 = {0,0,0,0}, a2 = {0,0,0,0}, a3 = {0,0,0,0};
#pragma unroll 4
        for (int i = 0; i < 64; ++i) {
            float4 xv = *reinterpret_cast<const float4*>(xr + i * 4);
            const float* rp = rwb + (size_t)i * 4 * NEXP;
            float4 w0 = *reinterpret_cast<const float4*>(rp);
            float4 w1 = *reinterpret_cast<const float4*>(rp + NEXP);
            float4 w2 = *reinterpret_cast<const float4*>(rp + 2 * NEXP);
            float4 w3 = *reinterpret_cast<const float4*>(rp + 3 * NEXP);
            a0.x += xv.x * w0.x; a0.y += xv.x * w0.y; a0.z += xv.x * w0.z; a0.w += xv.x * w0.w;
            a1.x += xv.y * w1.x; a1.y += xv.y * w1.y; a1.z += xv.y * w1.z; a1.w += xv.y * w1.w;
            a2.x += xv.z * w2.x; a2.y += xv.z * w2.y; a2.z += xv.z * w2.z; a2.w += xv.z * w2.w;
            a3.x += xv.w * w3.x; a3.y += xv.w * w3.y; a3.z += xv.w * w3.z; a3.w += xv.w * w3.w;
        }
        lds_acc[w][tok][e4][0] = (a0.x + a1.x) + (a2.x + a3.x);
        lds_acc[w][tok][e4][1] = (a0.y + a1.y) + (a2.y + a3.y);
        lds_acc[w][tok][e4][2] = (a0.z + a1.z) + (a2.z + a3.z);
        lds_acc[w][tok][e4][3] = (a0.w + a1.w) + (a2.w + a3.w);
    }
    __syncthreads();

    if (w != 0) return;

    float L0 = lds_acc[0][tok][e4][0] + lds_acc[1][tok][e4][0]
             + lds_acc[2][tok][e4][0] + lds_acc[3][tok][e4][0];
    float L1 = lds_acc[0][tok][e4][1] + lds_acc[1][tok][e4][1]
             + lds_acc[2][tok][e4][1] + lds_acc[3][tok][e4][1];
    float L2 = lds_acc[0][tok][e4][2] + lds_acc[1][tok][e4][2]
             + lds_acc[2][tok][e4][2] + lds_acc[3][tok][e4][2];
    float L3 = lds_acc[0][tok][e4][3] + lds_acc[1][tok][e4][3]
             + lds_acc[2][tok][e4][3] + lds_acc[3][tok][e4][3];

    float mx = fmaxf(fmaxf(L0, L1), fmaxf(L2, L3));
    mx = fmaxf(mx, __shfl_xor(mx, 1, 4));
    mx = fmaxf(mx, __shfl_xor(mx, 2, 4));
    float P0 = expf(L0 - mx), P1 = expf(L1 - mx);
    float P2 = expf(L2 - mx), P3 = expf(L3 - mx);
    float s = (P0 + P1) + (P2 + P3);
    s += __shfl_xor(s, 1, 4);
    s += __shfl_xor(s, 2, 4);
    float inv = 1.f / s;
    P0 *= inv; P1 *= inv; P2 *= inv; P3 *= inv;

    float4 Pv = {P0, P1, P2, P3};
    *reinterpret_cast<float4*>(scores + (size_t)token * NEXP + e4 * 4) = Pv;

    int base = e4 * 4;
    float v = P0; int idx = base;
    if (P1 > v) { v = P1; idx = base + 1; }
    if (P2 > v) { v = P2; idx = base + 2; }
    if (P3 > v) { v = P3; idx = base + 3; }
#pragma unroll
    for (int m = 1; m < 4; m <<= 1) {
        float vo = __shfl_xor(v, m, 4);
        int io = __shfl_xor(idx, m, 4);
        if (vo > v || (vo == v && io < idx)) { v = vo; idx = io; }
    }
    int i0 = idx; float v0 = v;
    float q0 = (base + 0 == i0) ? -1.f : P0;
    float q1 = (base + 1 == i0) ? -1.f : P1;
    float q2 = (base + 2 == i0) ? -1.f : P2;
    float q3 = (base + 3 == i0) ? -1.f : P3;
    v = q0; idx = base;
    if (q1 > v) { v = q1; idx = base + 1; }
    if (q2 > v) { v = q2; idx = base + 2; }
    if (q3 > v) { v = q3; idx = base + 3; }
#pragma unroll
    for (int m = 1; m < 4; m <<= 1) {
        float vo = __shfl_xor(v, m, 4);
        int io = __shfl_xor(idx, m, 4);
        if (vo > v || (vo == v && io < idx)) { v = vo; idx = io; }
    }
    if (e4 == 0) {
        topk_idx[2 * token] = i0; topk_idx[2 * token + 1] = idx;
        topk_val[2 * token] = v0; topk_val[2 * token + 1] = v;
        float ag = (lds_g[0][tok] + lds_g[1][tok]) + (lds_g[2][tok] + lds_g[3][tok]);
        g_shared[token] = 1.f / (1.f + expf(-ag));
    }
}

// ---------------- per-chunk expert histogram ----------------
__global__ __launch_bounds__(256) void hist_kernel(
    const int* __restrict__ topk_idx, int* __restrict__ chunk_hist)
{
    __shared__ int h[NEXP];
    int tid = threadIdx.x;
    if (tid < NEXP) h[tid] = 0;
    __syncthreads();
    int r = blockIdx.x * 256 + tid;
    atomicAdd(&h[topk_idx[r]], 1);
    __syncthreads();
    if (tid < NEXP) chunk_hist[blockIdx.x * NEXP + tid] = h[tid];
}

// ---------------- scan chunk histograms ----------------
__global__ __launch_bounds__(64) void scan_kernel(
    const int* __restrict__ chunk_hist, int* __restrict__ chunk_off,
    int* __restrict__ counts_cap, float* __restrict__ out_tail)
{
    int e = threadIdx.x;
    if (e >= NEXP) return;
    int run = 0;
    for (int b = 0; b < NCHUNK; ++b) {
        chunk_off[b * NEXP + e] = run;
        run += chunk_hist[b * NEXP + e];
    }
    counts_cap[e] = run < CAP ? run : CAP;
    out_tail[NEXP + e] = (float)((double)run / 16384.0);
}

// ---------------- deterministic slot assignment ----------------
__global__ __launch_bounds__(256) void assign_kernel(
    const int* __restrict__ topk_idx, const float* __restrict__ topk_val,
    const int* __restrict__ chunk_off,
    int* __restrict__ route_slot, int* __restrict__ slot_token)
{
    __shared__ int wave_cnt[4][NEXP];
    int tid = threadIdx.x;
    int lane = tid & 63;
    int w = tid >> 6;
    int r = blockIdx.x * 256 + tid;
    int e = topk_idx[r];
    float gate = topk_val[r];
    int rank_w = 0;
#pragma unroll
    for (int e16 = 0; e16 < NEXP; ++e16) {
        unsigned long long bal = __ballot(e == e16);
        if (e == e16) rank_w = __popcll(bal & ((1ull << lane) - 1ull));
        if (lane == 0) wave_cnt[w][e16] = __popcll(bal);
    }
    __syncthreads();
    int rank = rank_w;
#pragma unroll
    for (int w2 = 0; w2 < 3; ++w2)
        if (w2 < w) rank += wave_cnt[w2][e];
    int pos = chunk_off[blockIdx.x * NEXP + e] + rank;
    int slot = -1;
    if (pos < CAP && gate != 0.f) {
        slot = e * CAP + pos;
        slot_token[slot] = r >> 1;
    }
    route_slot[r] = slot;
}

// ---------------- importance reduction ----------------
__global__ __launch_bounds__(256) void importance_kernel(
    const float* __restrict__ scores, float* __restrict__ out_tail)
{
    __shared__ float red[256];
    int e = blockIdx.x;
    float s = 0.f;
    for (int t = threadIdx.x; t < N_TOK; t += 256) s += scores[t * NEXP + e];
    red[threadIdx.x] = s;
    __syncthreads();
    for (int st = 128; st > 0; st >>= 1) {
        if (threadIdx.x < st) red[threadIdx.x] += red[threadIdx.x + st];
        __syncthreads();
    }
    if (threadIdx.x == 0) out_tail[e] = red[0] / (float)N_TOK;
}

// ================= MFMA grouped GEMM 1: h = gelu(Xg @ W1) =================
// 256x256 tile, 8 waves (2Mx4N, wave = 128x64 out), BK=32, 3-buffer LDS,
// counted vmcnt(4), setprio, T1+T2. 32 MFMA + 12 ds_read_b128 per K-step.
#define G1_GX (NEXP * 5 + N_TOK / 256)      /* 112 */
#define G1_NWG (G1_GX * (FDIM / 256))       /* 224 */
__global__ __launch_bounds__(512) void gemm1_mfma(
    const ushort_t* __restrict__ xg,        // [ECAP][DIM] bf16 (expert rows)
    const ushort_t* __restrict__ x_bf,      // [N_TOK][DIM] bf16 (shared rows)
    const ushort_t* __restrict__ w1t,       // [16][FDIM][DIM] bf16 n-major
    const ushort_t* __restrict__ sw1t,      // [FDIM][DIM]
    const int* __restrict__ counts_cap,
    ushort_t* __restrict__ h_buf)           // [TOTROW][FDIM] bf16
{
    __shared__ ushort_t As[3][256 * 32];    // 16KB x3
    __shared__ ushort_t Bs[3][256 * 32];    // 16KB x3

    int flat = blockIdx.x;
    int wg = (flat & 7) * (G1_NWG / 8) + (flat >> 3);   // T1 (224 % 8 == 0)
    int by = wg & 1;
    int bxg = wg >> 1;

    int g, rb;
    if (bxg < NEXP * 5) { g = bxg / 5; rb = bxg % 5; }
    else { g = NEXP; rb = bxg - NEXP * 5; }
    int Mg = (g < NEXP) ? counts_cap[g] : N_TOK;
    int m0 = rb * 256;
    if (m0 >= Mg) return;
    const ushort_t* Arows = (g < NEXP) ? (xg + ((size_t)g * CAP + m0) * DIM)
                                       : (x_bf + (size_t)m0 * DIM);
    const ushort_t* Bt = (g < NEXP) ? (w1t + (size_t)g * DIM * FDIM) : sw1t;
    int n0 = by * 256;
    int t = threadIdx.x;

    const ushort_t* asrc[2];
    const ushort_t* bsrc[2];
#pragma unroll
    for (int i = 0; i < 2; ++i) {
        int s = t + i * 512;
        int lr = ((s >> 3) << 1) | ((s >> 2) & 1);
        int qq = (s & 3) ^ ((s >> 3) & 3);
        asrc[i] = Arows + (size_t)lr * DIM + qq * 8;
        bsrc[i] = Bt + (size_t)(n0 + lr) * DIM + qq * 8;
    }

    int lane = t & 63;
    int w = t >> 6;
    int wm = (w & 1) * 128, wn = (w >> 1) * 64;
    int l15 = lane & 15, q = lane >> 4;

    int aoff[8], boff[4];
#pragma unroll
    for (int m = 0; m < 8; ++m) aoff[m] = swz_addr16(wm + m * 16 + l15, q) << 3;
#pragma unroll
    for (int n = 0; n < 4; ++n) boff[n] = swz_addr16(wn + n * 16 + l15, q) << 3;

    f32x4 acc[8][4];
#pragma unroll
    for (int m = 0; m < 8; ++m)
#pragma unroll
        for (int n = 0; n < 4; ++n) acc[m][n] = (f32x4){0.f, 0.f, 0.f, 0.f};

    auto STAGE = [&](int buf, int koff) {
        gload16(asrc[0] + koff, &As[buf][t * 8]);
        gload16(asrc[1] + koff, &As[buf][t * 8 + 4096]);
        gload16(bsrc[0] + koff, &Bs[buf][t * 8]);
        gload16(bsrc[1] + koff, &Bs[buf][t * 8 + 4096]);
    };

    const int NSTEP = DIM / 32;   // 32
    STAGE(0, 0);
    STAGE(1, 32);
    asm volatile("s_waitcnt vmcnt(4)" ::: "memory");
    __builtin_amdgcn_s_barrier();
    asm volatile("" ::: "memory");

    int cur = 0, b2 = 2;
    for (int kt = 0; kt < NSTEP; ++kt) {
        if (kt + 2 < NSTEP) STAGE(b2, (kt + 2) * 32);
        const ushort_t* asb = &As[cur][0];
        const ushort_t* bsb = &Bs[cur][0];
        bf16x8 bfr[4];
#pragma unroll
        for (int n = 0; n < 4; ++n)
            bfr[n] = *reinterpret_cast<const bf16x8*>(bsb + boff[n]);
        __builtin_amdgcn_s_setprio(1);
#pragma unroll
        for (int m = 0; m < 8; ++m) {
            bf16x8 af = *reinterpret_cast<const bf16x8*>(asb + aoff[m]);
#pragma unroll
            for (int n = 0; n < 4; ++n)
                acc[m][n] = __builtin_amdgcn_mfma_f32_16x16x32_bf16(
                    af, bfr[n], acc[m][n], 0, 0, 0);
        }
        __builtin_amdgcn_s_setprio(0);
        if (kt + 1 < NSTEP) {
            if (kt + 2 < NSTEP) asm volatile("s_waitcnt vmcnt(4)" ::: "memory");
            else                asm volatile("s_waitcnt vmcnt(0)" ::: "memory");
            __builtin_amdgcn_s_barrier();
            asm volatile("" ::: "memory");
        }
        cur = (cur == 2) ? 0 : cur + 1;
        b2  = (b2 == 2) ? 0 : b2 + 1;
    }

    size_t obase = ((g < NEXP) ? (size_t)g * CAP : (size_t)ECAP) + m0;
#pragma unroll
    for (int m = 0; m < 8; ++m) {
#pragma unroll
        for (int r = 0; r < 4; ++r) {
            int grow = wm + m * 16 + q * 4 + r;
            ushort_t* orow = h_buf + (obase + grow) * FDIM + n0 + wn + l15;
#pragma unroll
            for (int n = 0; n < 4; ++n)
                orow[n * 16] = f2b(gelu_fast(acc[m][n][r]));
        }
    }
}

// ================= MFMA grouped GEMM 2: out = H @ W2 =================
// 256x256 tile, 8 waves (128x64/wave), BK=32, 3-buffer, vmcnt(4), setprio, T1+T2.
#define G2_NWG (G1_GX * (DIM / 256))        /* 448 */
__global__ __launch_bounds__(512) void gemm2_mfma(
    const ushort_t* __restrict__ h_buf,     // [TOTROW][FDIM] bf16
    const ushort_t* __restrict__ w2t,       // [16][DIM][FDIM] bf16 n-major
    const ushort_t* __restrict__ sw2t,      // [DIM][FDIM]
    const int* __restrict__ counts_cap,
    const float* __restrict__ g_shared,
    ushort_t* __restrict__ out_buf,         // [ECAP][DIM] bf16
    ushort_t* __restrict__ sh_out)          // [N_TOK][DIM] bf16 (x_bf reuse)
{
    __shared__ ushort_t As[3][256 * 32];
    __shared__ ushort_t Bs[3][256 * 32];

    int flat = blockIdx.x;
    int wg = (flat & 7) * (G2_NWG / 8) + (flat >> 3);   // 448 % 8 == 0
    int by = wg & 3;
    int bxg = wg >> 2;

    int g, rb;
    if (bxg < NEXP * 5) { g = bxg / 5; rb = bxg % 5; }
    else { g = NEXP; rb = bxg - NEXP * 5; }
    int Mg = (g < NEXP) ? counts_cap[g] : N_TOK;
    int m0 = rb * 256;
    if (m0 >= Mg) return;
    size_t abase = ((g < NEXP) ? (size_t)g * CAP : (size_t)ECAP) + m0;
    const ushort_t* Bt = (g < NEXP) ? (w2t + (size_t)g * FDIM * DIM) : sw2t;
    int n0 = by * 256;
    int t = threadIdx.x;

    const ushort_t* asrc[2];
    const ushort_t* bsrc[2];
#pragma unroll
    for (int i = 0; i < 2; ++i) {
        int s = t + i * 512;
        int lr = ((s >> 3) << 1) | ((s >> 2) & 1);
        int qq = (s & 3) ^ ((s >> 3) & 3);
        asrc[i] = h_buf + (abase + lr) * FDIM + qq * 8;
        bsrc[i] = Bt + (size_t)(n0 + lr) * FDIM + qq * 8;
    }

    int lane = t & 63;
    int w = t >> 6;
    int wm = (w & 1) * 128, wn = (w >> 1) * 64;
    int l15 = lane & 15, q = lane >> 4;

    int aoff[8], boff[4];
#pragma unroll
    for (int m = 0; m < 8; ++m) aoff[m] = swz_addr16(wm + m * 16 + l15, q) << 3;
#pragma unroll
    for (int n = 0; n < 4; ++n) boff[n] = swz_addr16(wn + n * 16 + l15, q) << 3;

    f32x4 acc[8][4];
#pragma unroll
    for (int m = 0; m < 8; ++m)
#pragma unroll
        for (int n = 0; n < 4; ++n) acc[m][n] = (f32x4){0.f, 0.f, 0.f, 0.f};

    auto STAGE = [&](int buf, int koff) {
        gload16(asrc[0] + koff, &As[buf][t * 8]);
        gload16(asrc[1] + koff, &As[buf][t * 8 + 4096]);
        gload16(bsrc[0] + koff, &Bs[buf][t * 8]);
        gload16(bsrc[1] + koff, &Bs[buf][t * 8 + 4096]);
    };

    const int NSTEP = FDIM / 32;  // 16
    STAGE(0, 0);
    STAGE(1, 32);
    asm volatile("s_waitcnt vmcnt(4)" ::: "memory");
    __builtin_amdgcn_s_barrier();
    asm volatile("" ::: "memory");

    int cur = 0, b2 = 2;
    for (int kt = 0; kt < NSTEP; ++kt) {
        if (kt + 2 < NSTEP) STAGE(b2, (kt + 2) * 32);
        const ushort_t* asb = &As[cur][0];
        const ushort_t* bsb = &Bs[cur][0];
        bf16x8 bfr[4];
#pragma unroll
        for (int n = 0; n < 4; ++n)
            bfr[n] = *reinterpret_cast<const bf16x8*>(bsb + boff[n]);
        __builtin_amdgcn_s_setprio(1);
#pragma unroll
        for (int m = 0; m < 8; ++m) {
            bf16x8 af = *reinterpret_cast<const bf16x8*>(asb + aoff[m]);
#pragma unroll
            for (int n = 0; n < 4; ++n)
                acc[m][n] = __builtin_amdgcn_mfma_f32_16x16x32_bf16(
                    af, bfr[n], acc[m][n], 0, 0, 0);
        }
        __builtin_amdgcn_s_setprio(0);
        if (kt + 1 < NSTEP) {
            if (kt + 2 < NSTEP) asm volatile("s_waitcnt vmcnt(4)" ::: "memory");
            else                asm volatile("s_waitcnt vmcnt(0)" ::: "memory");
            __builtin_amdgcn_s_barrier();
            asm volatile("" ::: "memory");
        }
        cur = (cur == 2) ? 0 : cur + 1;
        b2  = (b2 == 2) ? 0 : b2 + 1;
    }

    if (g < NEXP) {
#pragma unroll
        for (int m = 0; m < 8; ++m) {
#pragma unroll
            for (int r = 0; r < 4; ++r) {
                int grow = wm + m * 16 + q * 4 + r;
                ushort_t* orow = out_buf + (abase + grow) * DIM + n0 + wn + l15;
#pragma unroll
                for (int n = 0; n < 4; ++n)
                    orow[n * 16] = f2b(acc[m][n][r]);
            }
        }
    } else {
#pragma unroll
        for (int m = 0; m < 8; ++m) {
#pragma unroll
            for (int r = 0; r < 4; ++r) {
                int tok = m0 + wm + m * 16 + q * 4 + r;
                float gs = g_shared[tok];
                ushort_t* orow = sh_out + (size_t)tok * DIM + n0 + wn + l15;
#pragma unroll
                for (int n = 0; n < 4; ++n)
                    orow[n * 16] = f2b(gs * acc[m][n][r]);
            }
        }
    }
}

// ---------------- combine: y = sh_out + sum(gate * expert_out), write-only ----------------
__global__ __launch_bounds__(256) void combine_kernel(
    const ushort_t* __restrict__ out_buf, const ushort_t* __restrict__ sh_out,
    const int* __restrict__ route_slot, const float* __restrict__ topk_val,
    float* __restrict__ y)
{
    int token = blockIdx.x;
    int c = threadIdx.x * 4;
    ushort4 sv = *reinterpret_cast<const ushort4*>(sh_out + (size_t)token * DIM + c);
    float y0 = bf2f(sv.x), y1 = bf2f(sv.y), y2 = bf2f(sv.z), y3 = bf2f(sv.w);
#pragma unroll
    for (int k = 0; k < 2; ++k) {
        int s = route_slot[2 * token + k];
        if (s >= 0) {
            float gate = topk_val[2 * token + k];
            ushort4 rv = *reinterpret_cast<const ushort4*>(out_buf + (size_t)s * DIM + c);
            y0 += gate * bf2f(rv.x); y1 += gate * bf2f(rv.y);
            y2 += gate * bf2f(rv.z); y3 += gate * bf2f(rv.w);
        }
    }
    float4 o; o.x = y0; o.y = y1; o.z = y2; o.w = y3;
    *reinterpret_cast<float4*>(y + (size_t)token * DIM + c) = o;
}

extern "C" void kernel_launch(void* const* d_in, const int* in_sizes, int n_in,
                              void* d_out, int out_size, void* d_ws, size_t ws_size,
                              hipStream_t stream) {
    const float* x   = (const float*)d_in[0];
    const float* rw  = (const float*)d_in[1];
    const float* sgw = (const float*)d_in[2];
    const float* w1  = (const float*)d_in[3];
    const float* w2  = (const float*)d_in[4];
    const float* sw1 = (const float*)d_in[5];
    const float* sw2 = (const float*)d_in[6];
    float* y = (float*)d_out;
    float* out_tail = y + (size_t)N_TOK * DIM;

    size_t off = 0;
    char* wsb = (char*)d_ws;
    auto alloc = [&](size_t bytes) -> void* {
        void* p = wsb + off;
        off += (bytes + 255) & ~(size_t)255;
        return p;
    };
    float*    scores     = (float*)alloc((size_t)N_TOK * NEXP * 4);
    int*      topk_idx   = (int*)alloc((size_t)NROUTE * 4);
    float*    topk_val   = (float*)alloc((size_t)NROUTE * 4);
    float*    g_shared   = (float*)alloc((size_t)N_TOK * 4);
    int*      chunk_hist = (int*)alloc((size_t)NCHUNK * NEXP * 4);
    int*      chunk_off  = (int*)alloc((size_t)NCHUNK * NEXP * 4);
    int*      counts_cap = (int*)alloc((size_t)NEXP * 4);
    int*      route_slot = (int*)alloc((size_t)NROUTE * 4);
    int*      slot_token = (int*)alloc((size_t)ECAP * 4);
    // xg [ECAP][DIM] aliased with out_buf: xg dead after gemm1.
    char*     xg_union   = (char*)alloc((size_t)ECAP * DIM * 2);
    ushort_t* xg         = (ushort_t*)xg_union;
    ushort_t* out_buf    = (ushort_t*)xg_union;
    // x_bf [N_TOK][DIM] reused as sh_out after gemm1 (x_bf dead post-gemm1).
    ushort_t* x_bf       = (ushort_t*)alloc((size_t)N_TOK * DIM * 2);
    ushort_t* sh_out     = x_bf;
    ushort_t* w1t        = (ushort_t*)alloc((size_t)NEXP * DIM * FDIM * 2);
    ushort_t* w2t        = (ushort_t*)alloc((size_t)NEXP * DIM * FDIM * 2);
    ushort_t* sw1t       = (ushort_t*)alloc((size_t)DIM * FDIM * 2);
    ushort_t* sw2t       = (ushort_t*)alloc((size_t)DIM * FDIM * 2);
    ushort_t* h_buf      = (ushort_t*)alloc((size_t)TOTROW * FDIM * 2);
    (void)ws_size; (void)in_sizes; (void)n_in; (void)out_size;

    transpose_w_kernel<<<4352, 256, 0, stream>>>(w1, w2, sw1, sw2,
                                                 w1t, w2t, sw1t, sw2t);
    router_kernel<<<N_TOK / 16, 256, 0, stream>>>(x, rw, sgw, scores, topk_idx,
                                                  topk_val, g_shared, x_bf);
    hist_kernel<<<NCHUNK, 256, 0, stream>>>(topk_idx, chunk_hist);
    scan_kernel<<<1, 64, 0, stream>>>(chunk_hist, chunk_off, counts_cap, out_tail);
    assign_kernel<<<NCHUNK, 256, 0, stream>>>(topk_idx, topk_val, chunk_off, route_slot, slot_token);
    importance_kernel<<<NEXP, 256, 0, stream>>>(scores, out_tail);
    gather_x_kernel<<<ECAP, 256, 0, stream>>>(x_bf, slot_token, counts_cap, xg);

    gemm1_mfma<<<G1_NWG, 512, 0, stream>>>(xg, x_bf, w1t, sw1t, counts_cap, h_buf);
    gemm2_mfma<<<G2_NWG, 512, 0, stream>>>(h_buf, w2t, sw2t, counts_cap, g_shared, out_buf, sh_out);

    combine_kernel<<<N_TOK, 256, 0, stream>>>(out_buf, sh_out, route_slot, topk_val, y);
}

// Round 16
// 199.917 us; speedup vs baseline: 1.0078x; 1.0078x over previous
//
#include <hip/hip_runtime.h>
#include <hip/hip_bf16.h>
#include <math.h>

#define N_TOK 8192
#define DIM 1024
#define NEXP 16
#define CAP 1280
#define FDIM 512
#define NROUTE (N_TOK * 2)
#define NCHUNK 64
#define ECAP (NEXP * CAP)        /* 20480 */
#define TOTROW (ECAP + N_TOK)    /* 28672 */

typedef __hip_bfloat16 bf16;
typedef unsigned short ushort_t;
typedef __attribute__((ext_vector_type(8))) short bf16x8;
typedef __attribute__((ext_vector_type(4))) float f32x4;

// tanh-approx gelu via sigmoid; |err| vs erf-gelu ~1e-3 << tolerance.
__device__ __forceinline__ float gelu_fast(float x) {
    float u = 1.5957691216057308f * (x + 0.044715f * x * x * x);
    return x / (1.f + __expf(-u));
}

__device__ __forceinline__ float bf2f(unsigned short u) {
    union { float f; unsigned int i; } v; v.i = ((unsigned int)u) << 16; return v.f;
}

__device__ __forceinline__ unsigned short f2b(float f) {
    union { __hip_bfloat16 h; unsigned short u; } v;
    v.h = __float2bfloat16(f);
    return v.u;
}

__device__ __forceinline__ void gload16(const void* g, void* l) {
    __builtin_amdgcn_global_load_lds(
        (const __attribute__((address_space(1))) unsigned int*)g,
        (__attribute__((address_space(3))) unsigned int*)l,
        16, 0, 0);
}

// T2 both-sides swizzle (verified: SQ_LDS_BANK_CONFLICT -> 0, rounds 5-15)
__device__ __forceinline__ int swz_addr16(int r, int q) {
    return ((r >> 1) << 3) + ((r & 1) << 2) + (q ^ ((r >> 1) & 3));
}

// ---------------- gather expert rows from bf16 copy ----------------
__global__ __launch_bounds__(256) void gather_x_kernel(
    const ushort_t* __restrict__ x_bf, const int* __restrict__ slot_token,
    const int* __restrict__ counts_cap, ushort_t* __restrict__ xg)
{
    int row = blockIdx.x;            // [0, ECAP)
    int e = row / CAP;
    int pos = row - e * CAP;
    int tok = (pos < counts_cap[e]) ? slot_token[row] : 0;
    if ((unsigned)tok >= N_TOK) tok = 0;   // poison guard (gate==0 slots)
    int c = threadIdx.x * 4;
    ushort4 v = *reinterpret_cast<const ushort4*>(x_bf + (size_t)tok * DIM + c);
    *reinterpret_cast<ushort4*>(xg + (size_t)row * DIM + c) = v;
}

// ---------------- transpose+convert weights: fp32 [K][N] -> bf16 [N][K] ----------------
__global__ __launch_bounds__(256) void transpose_w_kernel(
    const float* __restrict__ w1, const float* __restrict__ w2,
    const float* __restrict__ sw1, const float* __restrict__ sw2,
    ushort_t* __restrict__ w1t, ushort_t* __restrict__ w2t,
    ushort_t* __restrict__ sw1t, ushort_t* __restrict__ sw2t)
{
    __shared__ float tileT[64][65];   // [n][k]
    int bx = blockIdx.x;
    const float* src; ushort_t* dst; int K, N, kt, nt;
    if (bx < 2048) {                      // w1: per-expert [1024][512]
        int e = bx >> 7, r = bx & 127;
        K = 1024; N = 512; kt = r >> 3; nt = r & 7;
        src = w1 + (size_t)e * K * N; dst = w1t + (size_t)e * K * N;
    } else if (bx < 4096) {               // w2: per-expert [512][1024]
        int b2 = bx - 2048, e = b2 >> 7, r = b2 & 127;
        K = 512; N = 1024; kt = r >> 4; nt = r & 15;
        src = w2 + (size_t)e * K * N; dst = w2t + (size_t)e * K * N;
    } else if (bx < 4224) {               // sw1 [1024][512]
        int r = bx - 4096;
        K = 1024; N = 512; kt = r >> 3; nt = r & 7;
        src = sw1; dst = sw1t;
    } else {                              // sw2 [512][1024]
        int r = bx - 4224;
        K = 512; N = 1024; kt = r >> 4; nt = r & 15;
        src = sw2; dst = sw2t;
    }
    int t = threadIdx.x;
    int tr = t >> 4;
    int tc = (t & 15) * 4;
#pragma unroll
    for (int i = 0; i < 4; ++i) {
        int k = kt * 64 + i * 16 + tr;
        float4 v = *reinterpret_cast<const float4*>(src + (size_t)k * N + nt * 64 + tc);
        tileT[tc + 0][i * 16 + tr] = v.x;
        tileT[tc + 1][i * 16 + tr] = v.y;
        tileT[tc + 2][i * 16 + tr] = v.z;
        tileT[tc + 3][i * 16 + tr] = v.w;
    }
    __syncthreads();
    int wr = t >> 3;
    int wc = (t & 7) * 8;
#pragma unroll
    for (int i = 0; i < 2; ++i) {
        int n = wr + i * 32;
        bf16x8 o;
#pragma unroll
        for (int j = 0; j < 8; ++j) o[j] = (short)f2b(tileT[n][wc + j]);
        *reinterpret_cast<bf16x8*>(dst + (size_t)(nt * 64 + n) * K + kt * 64 + wc) = o;
    }
}

// ---------------- router v5: expert-vectorized, d-split across 4 waves ----------------
__global__ __launch_bounds__(256) void router_kernel(
    const float* __restrict__ x, const float* __restrict__ rw,
    const float* __restrict__ sgw,
    float* __restrict__ scores,
    int* __restrict__ topk_idx,
    float* __restrict__ topk_val,
    float* __restrict__ g_shared,
    ushort_t* __restrict__ x_bf)
{
    __shared__ float lds_acc[4][16][4][4];   // [wave][tok][e4][4]
    __shared__ float lds_g[4][16];           // [wave][tok]

    int tid = threadIdx.x;
    int w = tid >> 6;
    int lane = tid & 63;
    int tok0 = blockIdx.x * 16;

    // ---- pass 1: x_bf conversion + shared-gate partials (coalesced) ----
    {
        int dq = w * 256 + lane * 4;
        float4 gv = *reinterpret_cast<const float4*>(sgw + dq);
#pragma unroll 4
        for (int tt = 0; tt < 16; ++tt) {
            const float* xr = x + (size_t)(tok0 + tt) * DIM + dq;
            float4 xv = *reinterpret_cast<const float4*>(xr);
            ushort4 o;
            o.x = f2b(xv.x); o.y = f2b(xv.y); o.z = f2b(xv.z); o.w = f2b(xv.w);
            *reinterpret_cast<ushort4*>(x_bf + (size_t)(tok0 + tt) * DIM + dq) = o;
            float dg = xv.x * gv.x + xv.y * gv.y + xv.z * gv.z + xv.w * gv.w;
#pragma unroll
            for (int m = 1; m < 64; m <<= 1) dg += __shfl_xor(dg, m, 64);
            if (lane == 0) lds_g[w][tt] = dg;
        }
    }

    // ---- pass 2: logits (4 experts per lane, float4 rw loads) ----
    int tok = lane >> 2;
    int e4 = lane & 3;
    int token = tok0 + tok;
    {
        const float* xr = x + (size_t)token * DIM + w * 256;
        const float* rwb = rw + (size_t)(w * 256) * NEXP + e4 * 4;
        float4 a0 = {0,0,0,0}, a1 = {0,0,0,0}, a2 = {0,0,0,0}, a3 = {0,0,0,0};
#pragma unroll 4
        for (int i = 0; i < 64; ++i) {
            float4 xv = *reinterpret_cast<const float4*>(xr + i * 4);
            const float* rp = rwb + (size_t)i * 4 * NEXP;
            float4 w0 = *reinterpret_cast<const float4*>(rp);
            float4 w1 = *reinterpret_cast<const float4*>(rp + NEXP);
            float4 w2 = *reinterpret_cast<const float4*>(rp + 2 * NEXP);
            float4 w3 = *reinterpret_cast<const float4*>(rp + 3 * NEXP);
            a0.x += xv.x * w0.x; a0.y += xv.x * w0.y; a0.z += xv.x * w0.z; a0.w += xv.x * w0.w;
            a1.x += xv.y * w1.x; a1.y += xv.y * w1.y; a1.z += xv.y * w1.z; a1.w += xv.y * w1.w;
            a2.x += xv.z * w2.x; a2.y += xv.z * w2.y; a2.z += xv.z * w2.z; a2.w += xv.z * w2.w;
            a3.x += xv.w * w3.x; a3.y += xv.w * w3.y; a3.z += xv.w * w3.z; a3.w += xv.w * w3.w;
        }
        lds_acc[w][tok][e4][0] = (a0.x + a1.x) + (a2.x + a3.x);
        lds_acc[w][tok][e4][1] = (a0.y + a1.y) + (a2.y + a3.y);
        lds_acc[w][tok][e4][2] = (a0.z + a1.z) + (a2.z + a3.z);
        lds_acc[w][tok][e4][3] = (a0.w + a1.w) + (a2.w + a3.w);
    }
    __syncthreads();

    if (w != 0) return;

    float L0 = lds_acc[0][tok][e4][0] + lds_acc[1][tok][e4][0]
             + lds_acc[2][tok][e4][0] + lds_acc[3][tok][e4][0];
    float L1 = lds_acc[0][tok][e4][1] + lds_acc[1][tok][e4][1]
             + lds_acc[2][tok][e4][1] + lds_acc[3][tok][e4][1];
    float L2 = lds_acc[0][tok][e4][2] + lds_acc[1][tok][e4][2]
             + lds_acc[2][tok][e4][2] + lds_acc[3][tok][e4][2];
    float L3 = lds_acc[0][tok][e4][3] + lds_acc[1][tok][e4][3]
             + lds_acc[2][tok][e4][3] + lds_acc[3][tok][e4][3];

    float mx = fmaxf(fmaxf(L0, L1), fmaxf(L2, L3));
    mx = fmaxf(mx, __shfl_xor(mx, 1, 4));
    mx = fmaxf(mx, __shfl_xor(mx, 2, 4));
    float P0 = expf(L0 - mx), P1 = expf(L1 - mx);
    float P2 = expf(L2 - mx), P3 = expf(L3 - mx);
    float s = (P0 + P1) + (P2 + P3);
    s += __shfl_xor(s, 1, 4);
    s += __shfl_xor(s, 2, 4);
    float inv = 1.f / s;
    P0 *= inv; P1 *= inv; P2 *= inv; P3 *= inv;

    float4 Pv = {P0, P1, P2, P3};
    *reinterpret_cast<float4*>(scores + (size_t)token * NEXP + e4 * 4) = Pv;

    int base = e4 * 4;
    float v = P0; int idx = base;
    if (P1 > v) { v = P1; idx = base + 1; }
    if (P2 > v) { v = P2; idx = base + 2; }
    if (P3 > v) { v = P3; idx = base + 3; }
#pragma unroll
    for (int m = 1; m < 4; m <<= 1) {
        float vo = __shfl_xor(v, m, 4);
        int io = __shfl_xor(idx, m, 4);
        if (vo > v || (vo == v && io < idx)) { v = vo; idx = io; }
    }
    int i0 = idx; float v0 = v;
    float q0 = (base + 0 == i0) ? -1.f : P0;
    float q1 = (base + 1 == i0) ? -1.f : P1;
    float q2 = (base + 2 == i0) ? -1.f : P2;
    float q3 = (base + 3 == i0) ? -1.f : P3;
    v = q0; idx = base;
    if (q1 > v) { v = q1; idx = base + 1; }
    if (q2 > v) { v = q2; idx = base + 2; }
    if (q3 > v) { v = q3; idx = base + 3; }
#pragma unroll
    for (int m = 1; m < 4; m <<= 1) {
        float vo = __shfl_xor(v, m, 4);
        int io = __shfl_xor(idx, m, 4);
        if (vo > v || (vo == v && io < idx)) { v = vo; idx = io; }
    }
    if (e4 == 0) {
        topk_idx[2 * token] = i0; topk_idx[2 * token + 1] = idx;
        topk_val[2 * token] = v0; topk_val[2 * token + 1] = v;
        float ag = (lds_g[0][tok] + lds_g[1][tok]) + (lds_g[2][tok] + lds_g[3][tok]);
        g_shared[token] = 1.f / (1.f + expf(-ag));
    }
}

// ---------------- per-chunk expert histogram ----------------
__global__ __launch_bounds__(256) void hist_kernel(
    const int* __restrict__ topk_idx, int* __restrict__ chunk_hist)
{
    __shared__ int h[NEXP];
    int tid = threadIdx.x;
    if (tid < NEXP) h[tid] = 0;
    __syncthreads();
    int r = blockIdx.x * 256 + tid;
    atomicAdd(&h[topk_idx[r]], 1);
    __syncthreads();
    if (tid < NEXP) chunk_hist[blockIdx.x * NEXP + tid] = h[tid];
}

// ---------------- scan chunk histograms ----------------
__global__ __launch_bounds__(64) void scan_kernel(
    const int* __restrict__ chunk_hist, int* __restrict__ chunk_off,
    int* __restrict__ counts_cap, float* __restrict__ out_tail)
{
    int e = threadIdx.x;
    if (e >= NEXP) return;
    int run = 0;
    for (int b = 0; b < NCHUNK; ++b) {
        chunk_off[b * NEXP + e] = run;
        run += chunk_hist[b * NEXP + e];
    }
    counts_cap[e] = run < CAP ? run : CAP;
    out_tail[NEXP + e] = (float)((double)run / 16384.0);
}

// ---------------- deterministic slot assignment ----------------
__global__ __launch_bounds__(256) void assign_kernel(
    const int* __restrict__ topk_idx, const float* __restrict__ topk_val,
    const int* __restrict__ chunk_off,
    int* __restrict__ route_slot, int* __restrict__ slot_token)
{
    __shared__ int wave_cnt[4][NEXP];
    int tid = threadIdx.x;
    int lane = tid & 63;
    int w = tid >> 6;
    int r = blockIdx.x * 256 + tid;
    int e = topk_idx[r];
    float gate = topk_val[r];
    int rank_w = 0;
#pragma unroll
    for (int e16 = 0; e16 < NEXP; ++e16) {
        unsigned long long bal = __ballot(e == e16);
        if (e == e16) rank_w = __popcll(bal & ((1ull << lane) - 1ull));
        if (lane == 0) wave_cnt[w][e16] = __popcll(bal);
    }
    __syncthreads();
    int rank = rank_w;
#pragma unroll
    for (int w2 = 0; w2 < 3; ++w2)
        if (w2 < w) rank += wave_cnt[w2][e];
    int pos = chunk_off[blockIdx.x * NEXP + e] + rank;
    int slot = -1;
    if (pos < CAP && gate != 0.f) {
        slot = e * CAP + pos;
        slot_token[slot] = r >> 1;
    }
    route_slot[r] = slot;
}

// ---------------- importance reduction ----------------
__global__ __launch_bounds__(256) void importance_kernel(
    const float* __restrict__ scores, float* __restrict__ out_tail)
{
    __shared__ float red[256];
    int e = blockIdx.x;
    float s = 0.f;
    for (int t = threadIdx.x; t < N_TOK; t += 256) s += scores[t * NEXP + e];
    red[threadIdx.x] = s;
    __syncthreads();
    for (int st = 128; st > 0; st >>= 1) {
        if (threadIdx.x < st) red[threadIdx.x] += red[threadIdx.x + st];
        __syncthreads();
    }
    if (threadIdx.x == 0) out_tail[e] = red[0] / (float)N_TOK;
}

// ================= MFMA grouped GEMM 1: h = gelu(Xg @ W1) =================
// 256x256 tile, 8 waves (wave = 128x64 out), BK=32, 2-buffer LDS (64KB ->
// 2 blocks/CU for cross-block overlap), setprio, T1+T2.
// 32 MFMA + 12 ds_read_b128 per K-step; grid 224 (single generation).
#define G1_GX (NEXP * 5 + N_TOK / 256)      /* 112 */
#define G1_NWG (G1_GX * (FDIM / 256))       /* 224 */
__global__ __launch_bounds__(512) void gemm1_mfma(
    const ushort_t* __restrict__ xg,        // [ECAP][DIM] bf16 (expert rows)
    const ushort_t* __restrict__ x_bf,      // [N_TOK][DIM] bf16 (shared rows)
    const ushort_t* __restrict__ w1t,       // [16][FDIM][DIM] bf16 n-major
    const ushort_t* __restrict__ sw1t,      // [FDIM][DIM]
    const int* __restrict__ counts_cap,
    ushort_t* __restrict__ h_buf)           // [TOTROW][FDIM] bf16
{
    __shared__ ushort_t As[2][256 * 32];    // 16KB x2
    __shared__ ushort_t Bs[2][256 * 32];    // 16KB x2

    int flat = blockIdx.x;
    int wg = (flat & 7) * (G1_NWG / 8) + (flat >> 3);   // T1 (224 % 8 == 0)
    int by = wg & 1;
    int bxg = wg >> 1;

    int g, rb;
    if (bxg < NEXP * 5) { g = bxg / 5; rb = bxg % 5; }
    else { g = NEXP; rb = bxg - NEXP * 5; }
    int Mg = (g < NEXP) ? counts_cap[g] : N_TOK;
    int m0 = rb * 256;
    if (m0 >= Mg) return;
    const ushort_t* Arows = (g < NEXP) ? (xg + ((size_t)g * CAP + m0) * DIM)
                                       : (x_bf + (size_t)m0 * DIM);
    const ushort_t* Bt = (g < NEXP) ? (w1t + (size_t)g * DIM * FDIM) : sw1t;
    int n0 = by * 256;
    int t = threadIdx.x;

    const ushort_t* asrc[2];
    const ushort_t* bsrc[2];
#pragma unroll
    for (int i = 0; i < 2; ++i) {
        int s = t + i * 512;
        int lr = ((s >> 3) << 1) | ((s >> 2) & 1);
        int qq = (s & 3) ^ ((s >> 3) & 3);
        asrc[i] = Arows + (size_t)lr * DIM + qq * 8;
        bsrc[i] = Bt + (size_t)(n0 + lr) * DIM + qq * 8;
    }

    int lane = t & 63;
    int w = t >> 6;
    int wm = (w & 1) * 128, wn = (w >> 1) * 64;
    int l15 = lane & 15, q = lane >> 4;

    int aoff[8], boff[4];
#pragma unroll
    for (int m = 0; m < 8; ++m) aoff[m] = swz_addr16(wm + m * 16 + l15, q) << 3;
#pragma unroll
    for (int n = 0; n < 4; ++n) boff[n] = swz_addr16(wn + n * 16 + l15, q) << 3;

    f32x4 acc[8][4];
#pragma unroll
    for (int m = 0; m < 8; ++m)
#pragma unroll
        for (int n = 0; n < 4; ++n) acc[m][n] = (f32x4){0.f, 0.f, 0.f, 0.f};

    auto STAGE = [&](int buf, int koff) {
        gload16(asrc[0] + koff, &As[buf][t * 8]);
        gload16(asrc[1] + koff, &As[buf][t * 8 + 4096]);
        gload16(bsrc[0] + koff, &Bs[buf][t * 8]);
        gload16(bsrc[1] + koff, &Bs[buf][t * 8 + 4096]);
    };

    const int NSTEP = DIM / 32;   // 32
    STAGE(0, 0);
    __syncthreads();

    int cur = 0;
    for (int kt = 0; kt < NSTEP; ++kt) {
        if (kt + 1 < NSTEP) STAGE(cur ^ 1, (kt + 1) * 32);
        const ushort_t* asb = &As[cur][0];
        const ushort_t* bsb = &Bs[cur][0];
        bf16x8 bfr[4];
#pragma unroll
        for (int n = 0; n < 4; ++n)
            bfr[n] = *reinterpret_cast<const bf16x8*>(bsb + boff[n]);
        __builtin_amdgcn_s_setprio(1);
#pragma unroll
        for (int m = 0; m < 8; ++m) {
            bf16x8 af = *reinterpret_cast<const bf16x8*>(asb + aoff[m]);
#pragma unroll
            for (int n = 0; n < 4; ++n)
                acc[m][n] = __builtin_amdgcn_mfma_f32_16x16x32_bf16(
                    af, bfr[n], acc[m][n], 0, 0, 0);
        }
        __builtin_amdgcn_s_setprio(0);
        __syncthreads();
        cur ^= 1;
    }

    size_t obase = ((g < NEXP) ? (size_t)g * CAP : (size_t)ECAP) + m0;
#pragma unroll
    for (int m = 0; m < 8; ++m) {
#pragma unroll
        for (int r = 0; r < 4; ++r) {
            int grow = wm + m * 16 + q * 4 + r;
            ushort_t* orow = h_buf + (obase + grow) * FDIM + n0 + wn + l15;
#pragma unroll
            for (int n = 0; n < 4; ++n)
                orow[n * 16] = f2b(gelu_fast(acc[m][n][r]));
        }
    }
}

// ================= MFMA grouped GEMM 2: out = H @ W2 =================
// 256x256 tile, 8 waves, BK=32, 2-buffer (64KB -> 2 blocks/CU), setprio, T1+T2.
#define G2_NWG (G1_GX * (DIM / 256))        /* 448 */
__global__ __launch_bounds__(512) void gemm2_mfma(
    const ushort_t* __restrict__ h_buf,     // [TOTROW][FDIM] bf16
    const ushort_t* __restrict__ w2t,       // [16][DIM][FDIM] bf16 n-major
    const ushort_t* __restrict__ sw2t,      // [DIM][FDIM]
    const int* __restrict__ counts_cap,
    const float* __restrict__ g_shared,
    ushort_t* __restrict__ out_buf,         // [ECAP][DIM] bf16
    ushort_t* __restrict__ sh_out)          // [N_TOK][DIM] bf16 (x_bf reuse)
{
    __shared__ ushort_t As[2][256 * 32];
    __shared__ ushort_t Bs[2][256 * 32];

    int flat = blockIdx.x;
    int wg = (flat & 7) * (G2_NWG / 8) + (flat >> 3);   // 448 % 8 == 0
    int by = wg & 3;
    int bxg = wg >> 2;

    int g, rb;
    if (bxg < NEXP * 5) { g = bxg / 5; rb = bxg % 5; }
    else { g = NEXP; rb = bxg - NEXP * 5; }
    int Mg = (g < NEXP) ? counts_cap[g] : N_TOK;
    int m0 = rb * 256;
    if (m0 >= Mg) return;
    size_t abase = ((g < NEXP) ? (size_t)g * CAP : (size_t)ECAP) + m0;
    const ushort_t* Bt = (g < NEXP) ? (w2t + (size_t)g * FDIM * DIM) : sw2t;
    int n0 = by * 256;
    int t = threadIdx.x;

    const ushort_t* asrc[2];
    const ushort_t* bsrc[2];
#pragma unroll
    for (int i = 0; i < 2; ++i) {
        int s = t + i * 512;
        int lr = ((s >> 3) << 1) | ((s >> 2) & 1);
        int qq = (s & 3) ^ ((s >> 3) & 3);
        asrc[i] = h_buf + (abase + lr) * FDIM + qq * 8;
        bsrc[i] = Bt + (size_t)(n0 + lr) * FDIM + qq * 8;
    }

    int lane = t & 63;
    int w = t >> 6;
    int wm = (w & 1) * 128, wn = (w >> 1) * 64;
    int l15 = lane & 15, q = lane >> 4;

    int aoff[8], boff[4];
#pragma unroll
    for (int m = 0; m < 8; ++m) aoff[m] = swz_addr16(wm + m * 16 + l15, q) << 3;
#pragma unroll
    for (int n = 0; n < 4; ++n) boff[n] = swz_addr16(wn + n * 16 + l15, q) << 3;

    f32x4 acc[8][4];
#pragma unroll
    for (int m = 0; m < 8; ++m)
#pragma unroll
        for (int n = 0; n < 4; ++n) acc[m][n] = (f32x4){0.f, 0.f, 0.f, 0.f};

    auto STAGE = [&](int buf, int koff) {
        gload16(asrc[0] + koff, &As[buf][t * 8]);
        gload16(asrc[1] + koff, &As[buf][t * 8 + 4096]);
        gload16(bsrc[0] + koff, &Bs[buf][t * 8]);
        gload16(bsrc[1] + koff, &Bs[buf][t * 8 + 4096]);
    };

    const int NSTEP = FDIM / 32;  // 16
    STAGE(0, 0);
    __syncthreads();

    int cur = 0;
    for (int kt = 0; kt < NSTEP; ++kt) {
        if (kt + 1 < NSTEP) STAGE(cur ^ 1, (kt + 1) * 32);
        const ushort_t* asb = &As[cur][0];
        const ushort_t* bsb = &Bs[cur][0];
        bf16x8 bfr[4];
#pragma unroll
        for (int n = 0; n < 4; ++n)
            bfr[n] = *reinterpret_cast<const bf16x8*>(bsb + boff[n]);
        __builtin_amdgcn_s_setprio(1);
#pragma unroll
        for (int m = 0; m < 8; ++m) {
            bf16x8 af = *reinterpret_cast<const bf16x8*>(asb + aoff[m]);
#pragma unroll
            for (int n = 0; n < 4; ++n)
                acc[m][n] = __builtin_amdgcn_mfma_f32_16x16x32_bf16(
                    af, bfr[n], acc[m][n], 0, 0, 0);
        }
        __builtin_amdgcn_s_setprio(0);
        __syncthreads();
        cur ^= 1;
    }

    if (g < NEXP) {
#pragma unroll
        for (int m = 0; m < 8; ++m) {
#pragma unroll
            for (int r = 0; r < 4; ++r) {
                int grow = wm + m * 16 + q * 4 + r;
                ushort_t* orow = out_buf + (abase + grow) * DIM + n0 + wn + l15;
#pragma unroll
                for (int n = 0; n < 4; ++n)
                    orow[n * 16] = f2b(acc[m][n][r]);
            }
        }
    } else {
#pragma unroll
        for (int m = 0; m < 8; ++m) {
#pragma unroll
            for (int r = 0; r < 4; ++r) {
                int tok = m0 + wm + m * 16 + q * 4 + r;
                float gs = g_shared[tok];
                ushort_t* orow = sh_out + (size_t)tok * DIM + n0 + wn + l15;
#pragma unroll
                for (int n = 0; n < 4; ++n)
                    orow[n * 16] = f2b(gs * acc[m][n][r]);
            }
        }
    }
}

// ---------------- combine: y = sh_out + sum(gate * expert_out), write-only ----------------
__global__ __launch_bounds__(256) void combine_kernel(
    const ushort_t* __restrict__ out_buf, const ushort_t* __restrict__ sh_out,
    const int* __restrict__ route_slot, const float* __restrict__ topk_val,
    float* __restrict__ y)
{
    int token = blockIdx.x;
    int c = threadIdx.x * 4;
    ushort4 sv = *reinterpret_cast<const ushort4*>(sh_out + (size_t)token * DIM + c);
    float y0 = bf2f(sv.x), y1 = bf2f(sv.y), y2 = bf2f(sv.z), y3 = bf2f(sv.w);
#pragma unroll
    for (int k = 0; k < 2; ++k) {
        int s = route_slot[2 * token + k];
        if (s >= 0) {
            float gate = topk_val[2 * token + k];
            ushort4 rv = *reinterpret_cast<const ushort4*>(out_buf + (size_t)s * DIM + c);
            y0 += gate * bf2f(rv.x); y1 += gate * bf2f(rv.y);
            y2 += gate * bf2f(rv.z); y3 += gate * bf2f(rv.w);
        }
    }
    float4 o; o.x = y0; o.y = y1; o.z = y2; o.w = y3;
    *reinterpret_cast<float4*>(y + (size_t)token * DIM + c) = o;
}

extern "C" void kernel_launch(void* const* d_in, const int* in_sizes, int n_in,
                              void* d_out, int out_size, void* d_ws, size_t ws_size,
                              hipStream_t stream) {
    const float* x   = (const float*)d_in[0];
    const float* rw  = (const float*)d_in[1];
    const float* sgw = (const float*)d_in[2];
    const float* w1  = (const float*)d_in[3];
    const float* w2  = (const float*)d_in[4];
    const float* sw1 = (const float*)d_in[5];
    const float* sw2 = (const float*)d_in[6];
    float* y = (float*)d_out;
    float* out_tail = y + (size_t)N_TOK * DIM;

    size_t off = 0;
    char* wsb = (char*)d_ws;
    auto alloc = [&](size_t bytes) -> void* {
        void* p = wsb + off;
        off += (bytes + 255) & ~(size_t)255;
        return p;
    };
    float*    scores     = (float*)alloc((size_t)N_TOK * NEXP * 4);
    int*      topk_idx   = (int*)alloc((size_t)NROUTE * 4);
    float*    topk_val   = (float*)alloc((size_t)NROUTE * 4);
    float*    g_shared   = (float*)alloc((size_t)N_TOK * 4);
    int*      chunk_hist = (int*)alloc((size_t)NCHUNK * NEXP * 4);
    int*      chunk_off  = (int*)alloc((size_t)NCHUNK * NEXP * 4);
    int*      counts_cap = (int*)alloc((size_t)NEXP * 4);
    int*      route_slot = (int*)alloc((size_t)NROUTE * 4);
    int*      slot_token = (int*)alloc((size_t)ECAP * 4);
    // xg [ECAP][DIM] aliased with out_buf: xg dead after gemm1.
    char*     xg_union   = (char*)alloc((size_t)ECAP * DIM * 2);
    ushort_t* xg         = (ushort_t*)xg_union;
    ushort_t* out_buf    = (ushort_t*)xg_union;
    // x_bf [N_TOK][DIM] reused as sh_out after gemm1 (x_bf dead post-gemm1).
    ushort_t* x_bf       = (ushort_t*)alloc((size_t)N_TOK * DIM * 2);
    ushort_t* sh_out     = x_bf;
    ushort_t* w1t        = (ushort_t*)alloc((size_t)NEXP * DIM * FDIM * 2);
    ushort_t* w2t        = (ushort_t*)alloc((size_t)NEXP * DIM * FDIM * 2);
    ushort_t* sw1t       = (ushort_t*)alloc((size_t)DIM * FDIM * 2);
    ushort_t* sw2t       = (ushort_t*)alloc((size_t)DIM * FDIM * 2);
    ushort_t* h_buf      = (ushort_t*)alloc((size_t)TOTROW * FDIM * 2);
    (void)ws_size; (void)in_sizes; (void)n_in; (void)out_size;

    transpose_w_kernel<<<4352, 256, 0, stream>>>(w1, w2, sw1, sw2,
                                                 w1t, w2t, sw1t, sw2t);
    router_kernel<<<N_TOK / 16, 256, 0, stream>>>(x, rw, sgw, scores, topk_idx,
                                                  topk_val, g_shared, x_bf);
    hist_kernel<<<NCHUNK, 256, 0, stream>>>(topk_idx, chunk_hist);
    scan_kernel<<<1, 64, 0, stream>>>(chunk_hist, chunk_off, counts_cap, out_tail);
    assign_kernel<<<NCHUNK, 256, 0, stream>>>(topk_idx, topk_val, chunk_off, route_slot, slot_token);
    importance_kernel<<<NEXP, 256, 0, stream>>>(scores, out_tail);
    gather_x_kernel<<<ECAP, 256, 0, stream>>>(x_bf, slot_token, counts_cap, xg);

    gemm1_mfma<<<G1_NWG, 512, 0, stream>>>(xg, x_bf, w1t, sw1t, counts_cap, h_buf);
    gemm2_mfma<<<G2_NWG, 512, 0, stream>>>(h_buf, w2t, sw2t, counts_cap, g_shared, out_buf, sh_out);

    combine_kernel<<<N_TOK, 256, 0, stream>>>(out_buf, sh_out, route_slot, topk_val, y);
}

// Round 17
// 174.949 us; speedup vs baseline: 1.1516x; 1.1427x over previous
//
#include <hip/hip_runtime.h>
#include <hip/hip_bf16.h>
#include <math.h>

#define N_TOK 8192
#define DIM 1024
#define NEXP 16
#define CAP 1280
#define FDIM 512
#define NROUTE (N_TOK * 2)
#define NCHUNK 64
#define ECAP (NEXP * CAP)        /* 20480 */
#define TOTROW (ECAP + N_TOK)    /* 28672 */

typedef __hip_bfloat16 bf16;
typedef unsigned short ushort_t;
typedef __attribute__((ext_vector_type(8))) short bf16x8;
typedef __attribute__((ext_vector_type(4))) float f32x4;

// tanh-approx gelu via sigmoid; |err| vs erf-gelu ~1e-3 << tolerance.
__device__ __forceinline__ float gelu_fast(float x) {
    float u = 1.5957691216057308f * (x + 0.044715f * x * x * x);
    return x / (1.f + __expf(-u));
}

__device__ __forceinline__ float bf2f(unsigned short u) {
    union { float f; unsigned int i; } v; v.i = ((unsigned int)u) << 16; return v.f;
}

__device__ __forceinline__ unsigned short f2b(float f) {
    union { __hip_bfloat16 h; unsigned short u; } v;
    v.h = __float2bfloat16(f);
    return v.u;
}

__device__ __forceinline__ void gload16(const void* g, void* l) {
    __builtin_amdgcn_global_load_lds(
        (const __attribute__((address_space(1))) unsigned int*)g,
        (__attribute__((address_space(3))) unsigned int*)l,
        16, 0, 0);
}

// T2 both-sides swizzle (verified: SQ_LDS_BANK_CONFLICT -> 0, rounds 5-16)
__device__ __forceinline__ int swz_addr16(int r, int q) {
    return ((r >> 1) << 3) + ((r & 1) << 2) + (q ^ ((r >> 1) & 3));
}

// ---------------- gather expert rows from bf16 copy ----------------
__global__ __launch_bounds__(256) void gather_x_kernel(
    const ushort_t* __restrict__ x_bf, const int* __restrict__ slot_token,
    const int* __restrict__ counts_cap, ushort_t* __restrict__ xg)
{
    int row = blockIdx.x;            // [0, ECAP)
    int e = row / CAP;
    int pos = row - e * CAP;
    int tok = (pos < counts_cap[e]) ? slot_token[row] : 0;
    if ((unsigned)tok >= N_TOK) tok = 0;   // poison guard (gate==0 slots)
    int c = threadIdx.x * 4;
    ushort4 v = *reinterpret_cast<const ushort4*>(x_bf + (size_t)tok * DIM + c);
    *reinterpret_cast<ushort4*>(xg + (size_t)row * DIM + c) = v;
}

// ========== fused prep: router (blocks 0-511) + weight transpose (512-4863) ==========
// Router and transpose are data-independent; fusing lets latency-bound router
// waves hide under BW-bound transpose waves and saves one serialized launch.
#define PREP_RTR_BLOCKS 512
__global__ __launch_bounds__(256) void prep_kernel(
    const float* __restrict__ x, const float* __restrict__ rw,
    const float* __restrict__ sgw,
    const float* __restrict__ w1, const float* __restrict__ w2,
    const float* __restrict__ sw1, const float* __restrict__ sw2,
    float* __restrict__ scores,
    int* __restrict__ topk_idx,
    float* __restrict__ topk_val,
    float* __restrict__ g_shared,
    ushort_t* __restrict__ x_bf,
    ushort_t* __restrict__ w1t, ushort_t* __restrict__ w2t,
    ushort_t* __restrict__ sw1t, ushort_t* __restrict__ sw2t)
{
    __shared__ union {
        float tileT[64][65];                 // transpose part (16.6KB)
        struct {
            float acc[4][16][4][4];          // router part [wave][tok][e4][4]
            float g[4][16];
        } r;
    } sm;

    if (blockIdx.x < PREP_RTR_BLOCKS) {
        // ---------------- router v5 (round-14 proven) ----------------
        int tid = threadIdx.x;
        int w = tid >> 6;
        int lane = tid & 63;
        int tok0 = blockIdx.x * 16;

        // pass 1: x_bf conversion + shared-gate partials (coalesced)
        {
            int dq = w * 256 + lane * 4;
            float4 gv = *reinterpret_cast<const float4*>(sgw + dq);
#pragma unroll 4
            for (int tt = 0; tt < 16; ++tt) {
                const float* xr = x + (size_t)(tok0 + tt) * DIM + dq;
                float4 xv = *reinterpret_cast<const float4*>(xr);
                ushort4 o;
                o.x = f2b(xv.x); o.y = f2b(xv.y); o.z = f2b(xv.z); o.w = f2b(xv.w);
                *reinterpret_cast<ushort4*>(x_bf + (size_t)(tok0 + tt) * DIM + dq) = o;
                float dg = xv.x * gv.x + xv.y * gv.y + xv.z * gv.z + xv.w * gv.w;
#pragma unroll
                for (int m = 1; m < 64; m <<= 1) dg += __shfl_xor(dg, m, 64);
                if (lane == 0) sm.r.g[w][tt] = dg;
            }
        }

        // pass 2: logits (4 experts per lane, float4 rw loads)
        int tok = lane >> 2;
        int e4 = lane & 3;
        int token = tok0 + tok;
        {
            const float* xr = x + (size_t)token * DIM + w * 256;
            const float* rwb = rw + (size_t)(w * 256) * NEXP + e4 * 4;
            float4 a0 = {0,0,0,0}, a1 = {0,0,0,0}, a2 = {0,0,0,0}, a3 = {0,0,0,0};
#pragma unroll 4
            for (int i = 0; i < 64; ++i) {
                float4 xv = *reinterpret_cast<const float4*>(xr + i * 4);
                const float* rp = rwb + (size_t)i * 4 * NEXP;
                float4 w0 = *reinterpret_cast<const float4*>(rp);
                float4 w1v = *reinterpret_cast<const float4*>(rp + NEXP);
                float4 w2v = *reinterpret_cast<const float4*>(rp + 2 * NEXP);
                float4 w3v = *reinterpret_cast<const float4*>(rp + 3 * NEXP);
                a0.x += xv.x * w0.x;  a0.y += xv.x * w0.y;  a0.z += xv.x * w0.z;  a0.w += xv.x * w0.w;
                a1.x += xv.y * w1v.x; a1.y += xv.y * w1v.y; a1.z += xv.y * w1v.z; a1.w += xv.y * w1v.w;
                a2.x += xv.z * w2v.x; a2.y += xv.z * w2v.y; a2.z += xv.z * w2v.z; a2.w += xv.z * w2v.w;
                a3.x += xv.w * w3v.x; a3.y += xv.w * w3v.y; a3.z += xv.w * w3v.z; a3.w += xv.w * w3v.w;
            }
            sm.r.acc[w][tok][e4][0] = (a0.x + a1.x) + (a2.x + a3.x);
            sm.r.acc[w][tok][e4][1] = (a0.y + a1.y) + (a2.y + a3.y);
            sm.r.acc[w][tok][e4][2] = (a0.z + a1.z) + (a2.z + a3.z);
            sm.r.acc[w][tok][e4][3] = (a0.w + a1.w) + (a2.w + a3.w);
        }
        __syncthreads();

        if (w != 0) return;

        float L0 = sm.r.acc[0][tok][e4][0] + sm.r.acc[1][tok][e4][0]
                 + sm.r.acc[2][tok][e4][0] + sm.r.acc[3][tok][e4][0];
        float L1 = sm.r.acc[0][tok][e4][1] + sm.r.acc[1][tok][e4][1]
                 + sm.r.acc[2][tok][e4][1] + sm.r.acc[3][tok][e4][1];
        float L2 = sm.r.acc[0][tok][e4][2] + sm.r.acc[1][tok][e4][2]
                 + sm.r.acc[2][tok][e4][2] + sm.r.acc[3][tok][e4][2];
        float L3 = sm.r.acc[0][tok][e4][3] + sm.r.acc[1][tok][e4][3]
                 + sm.r.acc[2][tok][e4][3] + sm.r.acc[3][tok][e4][3];

        float mx = fmaxf(fmaxf(L0, L1), fmaxf(L2, L3));
        mx = fmaxf(mx, __shfl_xor(mx, 1, 4));
        mx = fmaxf(mx, __shfl_xor(mx, 2, 4));
        float P0 = expf(L0 - mx), P1 = expf(L1 - mx);
        float P2 = expf(L2 - mx), P3 = expf(L3 - mx);
        float s = (P0 + P1) + (P2 + P3);
        s += __shfl_xor(s, 1, 4);
        s += __shfl_xor(s, 2, 4);
        float inv = 1.f / s;
        P0 *= inv; P1 *= inv; P2 *= inv; P3 *= inv;

        float4 Pv = {P0, P1, P2, P3};
        *reinterpret_cast<float4*>(scores + (size_t)token * NEXP + e4 * 4) = Pv;

        int base = e4 * 4;
        float v = P0; int idx = base;
        if (P1 > v) { v = P1; idx = base + 1; }
        if (P2 > v) { v = P2; idx = base + 2; }
        if (P3 > v) { v = P3; idx = base + 3; }
#pragma unroll
        for (int m = 1; m < 4; m <<= 1) {
            float vo = __shfl_xor(v, m, 4);
            int io = __shfl_xor(idx, m, 4);
            if (vo > v || (vo == v && io < idx)) { v = vo; idx = io; }
        }
        int i0 = idx; float v0 = v;
        float q0 = (base + 0 == i0) ? -1.f : P0;
        float q1 = (base + 1 == i0) ? -1.f : P1;
        float q2 = (base + 2 == i0) ? -1.f : P2;
        float q3 = (base + 3 == i0) ? -1.f : P3;
        v = q0; idx = base;
        if (q1 > v) { v = q1; idx = base + 1; }
        if (q2 > v) { v = q2; idx = base + 2; }
        if (q3 > v) { v = q3; idx = base + 3; }
#pragma unroll
        for (int m = 1; m < 4; m <<= 1) {
            float vo = __shfl_xor(v, m, 4);
            int io = __shfl_xor(idx, m, 4);
            if (vo > v || (vo == v && io < idx)) { v = vo; idx = io; }
        }
        if (e4 == 0) {
            topk_idx[2 * token] = i0; topk_idx[2 * token + 1] = idx;
            topk_val[2 * token] = v0; topk_val[2 * token + 1] = v;
            float ag = (sm.r.g[0][tok] + sm.r.g[1][tok]) + (sm.r.g[2][tok] + sm.r.g[3][tok]);
            g_shared[token] = 1.f / (1.f + expf(-ag));
        }
        return;
    }

    // ---------------- weight transpose+convert: fp32 [K][N] -> bf16 [N][K] ----------------
    int bx = blockIdx.x - PREP_RTR_BLOCKS;
    const float* src; ushort_t* dst; int K, N, kt, nt;
    if (bx < 2048) {                      // w1: per-expert [1024][512]
        int e = bx >> 7, r = bx & 127;
        K = 1024; N = 512; kt = r >> 3; nt = r & 7;
        src = w1 + (size_t)e * K * N; dst = w1t + (size_t)e * K * N;
    } else if (bx < 4096) {               // w2: per-expert [512][1024]
        int b2 = bx - 2048, e = b2 >> 7, r = b2 & 127;
        K = 512; N = 1024; kt = r >> 4; nt = r & 15;
        src = w2 + (size_t)e * K * N; dst = w2t + (size_t)e * K * N;
    } else if (bx < 4224) {               // sw1 [1024][512]
        int r = bx - 4096;
        K = 1024; N = 512; kt = r >> 3; nt = r & 7;
        src = sw1; dst = sw1t;
    } else {                              // sw2 [512][1024]
        int r = bx - 4224;
        K = 512; N = 1024; kt = r >> 4; nt = r & 15;
        src = sw2; dst = sw2t;
    }
    int t = threadIdx.x;
    int tr = t >> 4;
    int tc = (t & 15) * 4;
#pragma unroll
    for (int i = 0; i < 4; ++i) {
        int k = kt * 64 + i * 16 + tr;
        float4 v = *reinterpret_cast<const float4*>(src + (size_t)k * N + nt * 64 + tc);
        sm.tileT[tc + 0][i * 16 + tr] = v.x;
        sm.tileT[tc + 1][i * 16 + tr] = v.y;
        sm.tileT[tc + 2][i * 16 + tr] = v.z;
        sm.tileT[tc + 3][i * 16 + tr] = v.w;
    }
    __syncthreads();
    int wr = t >> 3;
    int wc = (t & 7) * 8;
#pragma unroll
    for (int i = 0; i < 2; ++i) {
        int n = wr + i * 32;
        bf16x8 o;
#pragma unroll
        for (int j = 0; j < 8; ++j) o[j] = (short)f2b(sm.tileT[n][wc + j]);
        *reinterpret_cast<bf16x8*>(dst + (size_t)(nt * 64 + n) * K + kt * 64 + wc) = o;
    }
}

// ---------------- per-chunk expert histogram ----------------
__global__ __launch_bounds__(256) void hist_kernel(
    const int* __restrict__ topk_idx, int* __restrict__ chunk_hist)
{
    __shared__ int h[NEXP];
    int tid = threadIdx.x;
    if (tid < NEXP) h[tid] = 0;
    __syncthreads();
    int r = blockIdx.x * 256 + tid;
    atomicAdd(&h[topk_idx[r]], 1);
    __syncthreads();
    if (tid < NEXP) chunk_hist[blockIdx.x * NEXP + tid] = h[tid];
}

// ---------------- scan chunk histograms ----------------
__global__ __launch_bounds__(64) void scan_kernel(
    const int* __restrict__ chunk_hist, int* __restrict__ chunk_off,
    int* __restrict__ counts_cap, float* __restrict__ out_tail)
{
    int e = threadIdx.x;
    if (e >= NEXP) return;
    int run = 0;
    for (int b = 0; b < NCHUNK; ++b) {
        chunk_off[b * NEXP + e] = run;
        run += chunk_hist[b * NEXP + e];
    }
    counts_cap[e] = run < CAP ? run : CAP;
    out_tail[NEXP + e] = (float)((double)run / 16384.0);
}

// ---------------- deterministic slot assignment ----------------
__global__ __launch_bounds__(256) void assign_kernel(
    const int* __restrict__ topk_idx, const float* __restrict__ topk_val,
    const int* __restrict__ chunk_off,
    int* __restrict__ route_slot, int* __restrict__ slot_token)
{
    __shared__ int wave_cnt[4][NEXP];
    int tid = threadIdx.x;
    int lane = tid & 63;
    int w = tid >> 6;
    int r = blockIdx.x * 256 + tid;
    int e = topk_idx[r];
    float gate = topk_val[r];
    int rank_w = 0;
#pragma unroll
    for (int e16 = 0; e16 < NEXP; ++e16) {
        unsigned long long bal = __ballot(e == e16);
        if (e == e16) rank_w = __popcll(bal & ((1ull << lane) - 1ull));
        if (lane == 0) wave_cnt[w][e16] = __popcll(bal);
    }
    __syncthreads();
    int rank = rank_w;
#pragma unroll
    for (int w2 = 0; w2 < 3; ++w2)
        if (w2 < w) rank += wave_cnt[w2][e];
    int pos = chunk_off[blockIdx.x * NEXP + e] + rank;
    int slot = -1;
    if (pos < CAP && gate != 0.f) {
        slot = e * CAP + pos;
        slot_token[slot] = r >> 1;
    }
    route_slot[r] = slot;
}

// ---------------- importance reduction ----------------
__global__ __launch_bounds__(256) void importance_kernel(
    const float* __restrict__ scores, float* __restrict__ out_tail)
{
    __shared__ float red[256];
    int e = blockIdx.x;
    float s = 0.f;
    for (int t = threadIdx.x; t < N_TOK; t += 256) s += scores[t * NEXP + e];
    red[threadIdx.x] = s;
    __syncthreads();
    for (int st = 128; st > 0; st >>= 1) {
        if (threadIdx.x < st) red[threadIdx.x] += red[threadIdx.x + st];
        __syncthreads();
    }
    if (threadIdx.x == 0) out_tail[e] = red[0] / (float)N_TOK;
}

// ================= MFMA grouped GEMM 1: h = gelu(Xg @ W1) =================
// 256x128 tile, 8 waves, BK=32, 3-buffer LDS, counted vmcnt(3), setprio, T1+T2.
#define G1_GX (NEXP * 5 + N_TOK / 256)      /* 112 */
#define G1_NWG (G1_GX * (FDIM / 128))       /* 448 */
__global__ __launch_bounds__(512) void gemm1_mfma(
    const ushort_t* __restrict__ xg,        // [ECAP][DIM] bf16 (expert rows)
    const ushort_t* __restrict__ x_bf,      // [N_TOK][DIM] bf16 (shared rows)
    const ushort_t* __restrict__ w1t,       // [16][FDIM][DIM] bf16 n-major
    const ushort_t* __restrict__ sw1t,      // [FDIM][DIM]
    const int* __restrict__ counts_cap,
    ushort_t* __restrict__ h_buf)           // [TOTROW][FDIM] bf16
{
    __shared__ ushort_t As[3][256 * 32];
    __shared__ ushort_t Bs[3][128 * 32];

    int flat = blockIdx.x;
    int wg = (flat & 7) * (G1_NWG / 8) + (flat >> 3);   // T1 (448 % 8 == 0)
    int by = wg & 3;
    int bxg = wg >> 2;

    int g, rb;
    if (bxg < NEXP * 5) { g = bxg / 5; rb = bxg % 5; }
    else { g = NEXP; rb = bxg - NEXP * 5; }
    int Mg = (g < NEXP) ? counts_cap[g] : N_TOK;
    int m0 = rb * 256;
    if (m0 >= Mg) return;
    const ushort_t* Arows = (g < NEXP) ? (xg + ((size_t)g * CAP + m0) * DIM)
                                       : (x_bf + (size_t)m0 * DIM);
    const ushort_t* Bt = (g < NEXP) ? (w1t + (size_t)g * DIM * FDIM) : sw1t;
    int n0 = by * 128;
    int t = threadIdx.x;

    const ushort_t* asrc[2];
    const ushort_t* bsrc;
#pragma unroll
    for (int i = 0; i < 2; ++i) {
        int s = t + i * 512;
        int lr = ((s >> 3) << 1) | ((s >> 2) & 1);
        int qq = (s & 3) ^ ((s >> 3) & 3);
        asrc[i] = Arows + (size_t)lr * DIM + qq * 8;
    }
    {
        int s = t;
        int lr = ((s >> 3) << 1) | ((s >> 2) & 1);
        int qq = (s & 3) ^ ((s >> 3) & 3);
        bsrc = Bt + (size_t)(n0 + lr) * DIM + qq * 8;
    }

    int lane = t & 63;
    int w = t >> 6;
    int wm = (w & 3) * 64, wn = (w >> 2) * 64;
    int l15 = lane & 15, q = lane >> 4;

    int aoff[4], boff[4];
#pragma unroll
    for (int m = 0; m < 4; ++m) aoff[m] = swz_addr16(wm + m * 16 + l15, q) << 3;
#pragma unroll
    for (int n = 0; n < 4; ++n) boff[n] = swz_addr16(wn + n * 16 + l15, q) << 3;

    f32x4 acc[4][4];
#pragma unroll
    for (int m = 0; m < 4; ++m)
#pragma unroll
        for (int n = 0; n < 4; ++n) acc[m][n] = (f32x4){0.f, 0.f, 0.f, 0.f};

    auto STAGE = [&](int buf, int koff) {
        gload16(asrc[0] + koff, &As[buf][t * 8]);
        gload16(asrc[1] + koff, &As[buf][t * 8 + 4096]);
        gload16(bsrc + koff, &Bs[buf][t * 8]);
    };

    const int NSTEP = DIM / 32;   // 32
    STAGE(0, 0);
    STAGE(1, 32);
    asm volatile("s_waitcnt vmcnt(3)" ::: "memory");
    __builtin_amdgcn_s_barrier();
    asm volatile("" ::: "memory");

    int cur = 0, b2 = 2;
    for (int kt = 0; kt < NSTEP; ++kt) {
        if (kt + 2 < NSTEP) STAGE(b2, (kt + 2) * 32);
        const ushort_t* asb = &As[cur][0];
        const ushort_t* bsb = &Bs[cur][0];
        bf16x8 af[4], bfr[4];
#pragma unroll
        for (int m = 0; m < 4; ++m)
            af[m] = *reinterpret_cast<const bf16x8*>(asb + aoff[m]);
#pragma unroll
        for (int n = 0; n < 4; ++n)
            bfr[n] = *reinterpret_cast<const bf16x8*>(bsb + boff[n]);
        __builtin_amdgcn_s_setprio(1);
#pragma unroll
        for (int m = 0; m < 4; ++m)
#pragma unroll
            for (int n = 0; n < 4; ++n)
                acc[m][n] = __builtin_amdgcn_mfma_f32_16x16x32_bf16(
                    af[m], bfr[n], acc[m][n], 0, 0, 0);
        __builtin_amdgcn_s_setprio(0);
        if (kt + 1 < NSTEP) {
            if (kt + 2 < NSTEP) asm volatile("s_waitcnt vmcnt(3)" ::: "memory");
            else                asm volatile("s_waitcnt vmcnt(0)" ::: "memory");
            __builtin_amdgcn_s_barrier();
            asm volatile("" ::: "memory");
        }
        cur = (cur == 2) ? 0 : cur + 1;
        b2  = (b2 == 2) ? 0 : b2 + 1;
    }

    size_t obase = ((g < NEXP) ? (size_t)g * CAP : (size_t)ECAP) + m0;
#pragma unroll
    for (int m = 0; m < 4; ++m) {
#pragma unroll
        for (int r = 0; r < 4; ++r) {
            int grow = wm + m * 16 + q * 4 + r;
            ushort_t* orow = h_buf + (obase + grow) * FDIM + n0 + wn + l15;
#pragma unroll
            for (int n = 0; n < 4; ++n)
                orow[n * 16] = f2b(gelu_fast(acc[m][n][r]));
        }
    }
}

// ================= MFMA grouped GEMM 2: out = H @ W2 =================
// 256x128 tile, 8 waves, BK=32, 2-buffer (48KB, occupancy), setprio, T1+T2.
#define G2_NWG (G1_GX * (DIM / 128))        /* 896 */
__global__ __launch_bounds__(512) void gemm2_mfma(
    const ushort_t* __restrict__ h_buf,     // [TOTROW][FDIM] bf16
    const ushort_t* __restrict__ w2t,       // [16][DIM][FDIM] bf16 n-major
    const ushort_t* __restrict__ sw2t,      // [DIM][FDIM]
    const int* __restrict__ counts_cap,
    const float* __restrict__ g_shared,
    ushort_t* __restrict__ out_buf,         // [ECAP][DIM] bf16
    ushort_t* __restrict__ sh_out)          // [N_TOK][DIM] bf16 (x_bf reuse)
{
    __shared__ ushort_t As[2][256 * 32];
    __shared__ ushort_t Bs[2][128 * 32];

    int flat = blockIdx.x;
    int wg = (flat & 7) * (G2_NWG / 8) + (flat >> 3);
    int by = wg & 7;
    int bxg = wg >> 3;

    int g, rb;
    if (bxg < NEXP * 5) { g = bxg / 5; rb = bxg % 5; }
    else { g = NEXP; rb = bxg - NEXP * 5; }
    int Mg = (g < NEXP) ? counts_cap[g] : N_TOK;
    int m0 = rb * 256;
    if (m0 >= Mg) return;
    size_t abase = ((g < NEXP) ? (size_t)g * CAP : (size_t)ECAP) + m0;
    const ushort_t* Bt = (g < NEXP) ? (w2t + (size_t)g * FDIM * DIM) : sw2t;
    int n0 = by * 128;
    int t = threadIdx.x;

    const ushort_t* asrc[2];
    const ushort_t* bsrc;
#pragma unroll
    for (int i = 0; i < 2; ++i) {
        int s = t + i * 512;
        int lr = ((s >> 3) << 1) | ((s >> 2) & 1);
        int qq = (s & 3) ^ ((s >> 3) & 3);
        asrc[i] = h_buf + (abase + lr) * FDIM + qq * 8;
    }
    {
        int s = t;
        int lr = ((s >> 3) << 1) | ((s >> 2) & 1);
        int qq = (s & 3) ^ ((s >> 3) & 3);
        bsrc = Bt + (size_t)(n0 + lr) * FDIM + qq * 8;
    }

    int lane = t & 63;
    int w = t >> 6;
    int wm = (w & 3) * 64, wn = (w >> 2) * 64;
    int l15 = lane & 15, q = lane >> 4;

    int aoff[4], boff[4];
#pragma unroll
    for (int m = 0; m < 4; ++m) aoff[m] = swz_addr16(wm + m * 16 + l15, q) << 3;
#pragma unroll
    for (int n = 0; n < 4; ++n) boff[n] = swz_addr16(wn + n * 16 + l15, q) << 3;

    f32x4 acc[4][4];
#pragma unroll
    for (int m = 0; m < 4; ++m)
#pragma unroll
        for (int n = 0; n < 4; ++n) acc[m][n] = (f32x4){0.f, 0.f, 0.f, 0.f};

    auto STAGE = [&](int buf, int koff) {
        gload16(asrc[0] + koff, &As[buf][t * 8]);
        gload16(asrc[1] + koff, &As[buf][t * 8 + 4096]);
        gload16(bsrc + koff, &Bs[buf][t * 8]);
    };

    const int NSTEP = FDIM / 32;  // 16
    STAGE(0, 0);
    __syncthreads();

    int cur = 0;
    for (int kt = 0; kt < NSTEP; ++kt) {
        if (kt + 1 < NSTEP) STAGE(cur ^ 1, (kt + 1) * 32);
        const ushort_t* asb = &As[cur][0];
        const ushort_t* bsb = &Bs[cur][0];
        bf16x8 af[4], bfr[4];
#pragma unroll
        for (int m = 0; m < 4; ++m)
            af[m] = *reinterpret_cast<const bf16x8*>(asb + aoff[m]);
#pragma unroll
        for (int n = 0; n < 4; ++n)
            bfr[n] = *reinterpret_cast<const bf16x8*>(bsb + boff[n]);
        __builtin_amdgcn_s_setprio(1);
#pragma unroll
        for (int m = 0; m < 4; ++m)
#pragma unroll
            for (int n = 0; n < 4; ++n)
                acc[m][n] = __builtin_amdgcn_mfma_f32_16x16x32_bf16(
                    af[m], bfr[n], acc[m][n], 0, 0, 0);
        __builtin_amdgcn_s_setprio(0);
        __syncthreads();
        cur ^= 1;
    }

    if (g < NEXP) {
#pragma unroll
        for (int m = 0; m < 4; ++m) {
#pragma unroll
            for (int r = 0; r < 4; ++r) {
                int grow = wm + m * 16 + q * 4 + r;
                ushort_t* orow = out_buf + (abase + grow) * DIM + n0 + wn + l15;
#pragma unroll
                for (int n = 0; n < 4; ++n)
                    orow[n * 16] = f2b(acc[m][n][r]);
            }
        }
    } else {
#pragma unroll
        for (int m = 0; m < 4; ++m) {
#pragma unroll
            for (int r = 0; r < 4; ++r) {
                int tok = m0 + wm + m * 16 + q * 4 + r;
                float gs = g_shared[tok];
                ushort_t* orow = sh_out + (size_t)tok * DIM + n0 + wn + l15;
#pragma unroll
                for (int n = 0; n < 4; ++n)
                    orow[n * 16] = f2b(gs * acc[m][n][r]);
            }
        }
    }
}

// ---------------- combine: y = sh_out + sum(gate * expert_out), write-only ----------------
__global__ __launch_bounds__(256) void combine_kernel(
    const ushort_t* __restrict__ out_buf, const ushort_t* __restrict__ sh_out,
    const int* __restrict__ route_slot, const float* __restrict__ topk_val,
    float* __restrict__ y)
{
    int token = blockIdx.x;
    int c = threadIdx.x * 4;
    ushort4 sv = *reinterpret_cast<const ushort4*>(sh_out + (size_t)token * DIM + c);
    float y0 = bf2f(sv.x), y1 = bf2f(sv.y), y2 = bf2f(sv.z), y3 = bf2f(sv.w);
#pragma unroll
    for (int k = 0; k < 2; ++k) {
        int s = route_slot[2 * token + k];
        if (s >= 0) {
            float gate = topk_val[2 * token + k];
            ushort4 rv = *reinterpret_cast<const ushort4*>(out_buf + (size_t)s * DIM + c);
            y0 += gate * bf2f(rv.x); y1 += gate * bf2f(rv.y);
            y2 += gate * bf2f(rv.z); y3 += gate * bf2f(rv.w);
        }
    }
    float4 o; o.x = y0; o.y = y1; o.z = y2; o.w = y3;
    *reinterpret_cast<float4*>(y + (size_t)token * DIM + c) = o;
}

extern "C" void kernel_launch(void* const* d_in, const int* in_sizes, int n_in,
                              void* d_out, int out_size, void* d_ws, size_t ws_size,
                              hipStream_t stream) {
    const float* x   = (const float*)d_in[0];
    const float* rw  = (const float*)d_in[1];
    const float* sgw = (const float*)d_in[2];
    const float* w1  = (const float*)d_in[3];
    const float* w2  = (const float*)d_in[4];
    const float* sw1 = (const float*)d_in[5];
    const float* sw2 = (const float*)d_in[6];
    float* y = (float*)d_out;
    float* out_tail = y + (size_t)N_TOK * DIM;

    size_t off = 0;
    char* wsb = (char*)d_ws;
    auto alloc = [&](size_t bytes) -> void* {
        void* p = wsb + off;
        off += (bytes + 255) & ~(size_t)255;
        return p;
    };
    float*    scores     = (float*)alloc((size_t)N_TOK * NEXP * 4);
    int*      topk_idx   = (int*)alloc((size_t)NROUTE * 4);
    float*    topk_val   = (float*)alloc((size_t)NROUTE * 4);
    float*    g_shared   = (float*)alloc((size_t)N_TOK * 4);
    int*      chunk_hist = (int*)alloc((size_t)NCHUNK * NEXP * 4);
    int*      chunk_off  = (int*)alloc((size_t)NCHUNK * NEXP * 4);
    int*      counts_cap = (int*)alloc((size_t)NEXP * 4);
    int*      route_slot = (int*)alloc((size_t)NROUTE * 4);
    int*      slot_token = (int*)alloc((size_t)ECAP * 4);
    // xg [ECAP][DIM] aliased with out_buf: xg dead after gemm1.
    char*     xg_union   = (char*)alloc((size_t)ECAP * DIM * 2);
    ushort_t* xg         = (ushort_t*)xg_union;
    ushort_t* out_buf    = (ushort_t*)xg_union;
    // x_bf [N_TOK][DIM] reused as sh_out after gemm1 (x_bf dead post-gemm1).
    ushort_t* x_bf       = (ushort_t*)alloc((size_t)N_TOK * DIM * 2);
    ushort_t* sh_out     = x_bf;
    ushort_t* w1t        = (ushort_t*)alloc((size_t)NEXP * DIM * FDIM * 2);
    ushort_t* w2t        = (ushort_t*)alloc((size_t)NEXP * DIM * FDIM * 2);
    ushort_t* sw1t       = (ushort_t*)alloc((size_t)DIM * FDIM * 2);
    ushort_t* sw2t       = (ushort_t*)alloc((size_t)DIM * FDIM * 2);
    ushort_t* h_buf      = (ushort_t*)alloc((size_t)TOTROW * FDIM * 2);
    (void)ws_size; (void)in_sizes; (void)n_in; (void)out_size;

    prep_kernel<<<PREP_RTR_BLOCKS + 4352, 256, 0, stream>>>(
        x, rw, sgw, w1, w2, sw1, sw2,
        scores, topk_idx, topk_val, g_shared, x_bf, w1t, w2t, sw1t, sw2t);
    hist_kernel<<<NCHUNK, 256, 0, stream>>>(topk_idx, chunk_hist);
    scan_kernel<<<1, 64, 0, stream>>>(chunk_hist, chunk_off, counts_cap, out_tail);
    assign_kernel<<<NCHUNK, 256, 0, stream>>>(topk_idx, topk_val, chunk_off, route_slot, slot_token);
    importance_kernel<<<NEXP, 256, 0, stream>>>(scores, out_tail);
    gather_x_kernel<<<ECAP, 256, 0, stream>>>(x_bf, slot_token, counts_cap, xg);

    gemm1_mfma<<<G1_NWG, 512, 0, stream>>>(xg, x_bf, w1t, sw1t, counts_cap, h_buf);
    gemm2_mfma<<<G2_NWG, 512, 0, stream>>>(h_buf, w2t, sw2t, counts_cap, g_shared, out_buf, sh_out);

    combine_kernel<<<N_TOK, 256, 0, stream>>>(out_buf, sh_out, route_slot, topk_val, y);
}

// Round 18
// 174.174 us; speedup vs baseline: 1.1567x; 1.0044x over previous
//
#include <hip/hip_runtime.h>
#include <hip/hip_bf16.h>
#include <math.h>

#define N_TOK 8192
#define DIM 1024
#define NEXP 16
#define CAP 1280
#define FDIM 512
#define NROUTE (N_TOK * 2)
#define NCHUNK 64
#define ECAP (NEXP * CAP)        /* 20480 */
#define TOTROW (ECAP + N_TOK)    /* 28672 */

typedef __hip_bfloat16 bf16;
typedef unsigned short ushort_t;
typedef __attribute__((ext_vector_type(8))) short bf16x8;
typedef __attribute__((ext_vector_type(4))) float f32x4;

// tanh-approx gelu via sigmoid; |err| vs erf-gelu ~1e-3 << tolerance.
__device__ __forceinline__ float gelu_fast(float x) {
    float u = 1.5957691216057308f * (x + 0.044715f * x * x * x);
    return x / (1.f + __expf(-u));
}

__device__ __forceinline__ float bf2f(unsigned short u) {
    union { float f; unsigned int i; } v; v.i = ((unsigned int)u) << 16; return v.f;
}

__device__ __forceinline__ unsigned short f2b(float f) {
    union { __hip_bfloat16 h; unsigned short u; } v;
    v.h = __float2bfloat16(f);
    return v.u;
}

__device__ __forceinline__ void gload16(const void* g, void* l) {
    __builtin_amdgcn_global_load_lds(
        (const __attribute__((address_space(1))) unsigned int*)g,
        (__attribute__((address_space(3))) unsigned int*)l,
        16, 0, 0);
}

// T2 both-sides swizzle (verified: SQ_LDS_BANK_CONFLICT -> 0, rounds 5-17)
__device__ __forceinline__ int swz_addr16(int r, int q) {
    return ((r >> 1) << 3) + ((r & 1) << 2) + (q ^ ((r >> 1) & 3));
}

// ---------------- gather expert rows from bf16 copy ----------------
__global__ __launch_bounds__(256) void gather_x_kernel(
    const ushort_t* __restrict__ x_bf, const int* __restrict__ slot_token,
    const int* __restrict__ counts_cap, ushort_t* __restrict__ xg)
{
    int row = blockIdx.x;            // [0, ECAP)
    int e = row / CAP;
    int pos = row - e * CAP;
    int tok = (pos < counts_cap[e]) ? slot_token[row] : 0;
    if ((unsigned)tok >= N_TOK) tok = 0;   // poison guard (gate==0 slots)
    int c = threadIdx.x * 4;
    ushort4 v = *reinterpret_cast<const ushort4*>(x_bf + (size_t)tok * DIM + c);
    *reinterpret_cast<ushort4*>(xg + (size_t)row * DIM + c) = v;
}

// ========== fused prep: router (blocks 0-511) + weight transpose (512-1599) ==========
// Transpose uses 128x128 tiles: 512B-contiguous reads, 256B-contiguous writes
// (vs 256B/128B at 64x64) -> ~2x DRAM efficiency. bf16 LDS tile [128][130].
#define PREP_RTR_BLOCKS 512
#define PREP_NWG (PREP_RTR_BLOCKS + 1088)
__global__ __launch_bounds__(256) void prep_kernel(
    const float* __restrict__ x, const float* __restrict__ rw,
    const float* __restrict__ sgw,
    const float* __restrict__ w1, const float* __restrict__ w2,
    const float* __restrict__ sw1, const float* __restrict__ sw2,
    float* __restrict__ scores,
    int* __restrict__ topk_idx,
    float* __restrict__ topk_val,
    float* __restrict__ g_shared,
    ushort_t* __restrict__ x_bf,
    ushort_t* __restrict__ w1t, ushort_t* __restrict__ w2t,
    ushort_t* __restrict__ sw1t, ushort_t* __restrict__ sw2t)
{
    __shared__ union {
        ushort_t tileB[128][130];            // [n][k] bf16, pad->130 (32.5KB)
        struct {
            float acc[4][16][4][4];          // router [wave][tok][e4][4]
            float g[4][16];
        } r;
    } sm;

    if (blockIdx.x < PREP_RTR_BLOCKS) {
        // ---------------- router v5 (round-14 proven) ----------------
        int tid = threadIdx.x;
        int w = tid >> 6;
        int lane = tid & 63;
        int tok0 = blockIdx.x * 16;

        // pass 1: x_bf conversion + shared-gate partials (coalesced)
        {
            int dq = w * 256 + lane * 4;
            float4 gv = *reinterpret_cast<const float4*>(sgw + dq);
#pragma unroll 4
            for (int tt = 0; tt < 16; ++tt) {
                const float* xr = x + (size_t)(tok0 + tt) * DIM + dq;
                float4 xv = *reinterpret_cast<const float4*>(xr);
                ushort4 o;
                o.x = f2b(xv.x); o.y = f2b(xv.y); o.z = f2b(xv.z); o.w = f2b(xv.w);
                *reinterpret_cast<ushort4*>(x_bf + (size_t)(tok0 + tt) * DIM + dq) = o;
                float dg = xv.x * gv.x + xv.y * gv.y + xv.z * gv.z + xv.w * gv.w;
#pragma unroll
                for (int m = 1; m < 64; m <<= 1) dg += __shfl_xor(dg, m, 64);
                if (lane == 0) sm.r.g[w][tt] = dg;
            }
        }

        // pass 2: logits (4 experts per lane, float4 rw loads)
        int tok = lane >> 2;
        int e4 = lane & 3;
        int token = tok0 + tok;
        {
            const float* xr = x + (size_t)token * DIM + w * 256;
            const float* rwb = rw + (size_t)(w * 256) * NEXP + e4 * 4;
            float4 a0 = {0,0,0,0}, a1 = {0,0,0,0}, a2 = {0,0,0,0}, a3 = {0,0,0,0};
#pragma unroll 4
            for (int i = 0; i < 64; ++i) {
                float4 xv = *reinterpret_cast<const float4*>(xr + i * 4);
                const float* rp = rwb + (size_t)i * 4 * NEXP;
                float4 w0 = *reinterpret_cast<const float4*>(rp);
                float4 w1v = *reinterpret_cast<const float4*>(rp + NEXP);
                float4 w2v = *reinterpret_cast<const float4*>(rp + 2 * NEXP);
                float4 w3v = *reinterpret_cast<const float4*>(rp + 3 * NEXP);
                a0.x += xv.x * w0.x;  a0.y += xv.x * w0.y;  a0.z += xv.x * w0.z;  a0.w += xv.x * w0.w;
                a1.x += xv.y * w1v.x; a1.y += xv.y * w1v.y; a1.z += xv.y * w1v.z; a1.w += xv.y * w1v.w;
                a2.x += xv.z * w2v.x; a2.y += xv.z * w2v.y; a2.z += xv.z * w2v.z; a2.w += xv.z * w2v.w;
                a3.x += xv.w * w3v.x; a3.y += xv.w * w3v.y; a3.z += xv.w * w3v.z; a3.w += xv.w * w3v.w;
            }
            sm.r.acc[w][tok][e4][0] = (a0.x + a1.x) + (a2.x + a3.x);
            sm.r.acc[w][tok][e4][1] = (a0.y + a1.y) + (a2.y + a3.y);
            sm.r.acc[w][tok][e4][2] = (a0.z + a1.z) + (a2.z + a3.z);
            sm.r.acc[w][tok][e4][3] = (a0.w + a1.w) + (a2.w + a3.w);
        }
        __syncthreads();

        if (w != 0) return;

        float L0 = sm.r.acc[0][tok][e4][0] + sm.r.acc[1][tok][e4][0]
                 + sm.r.acc[2][tok][e4][0] + sm.r.acc[3][tok][e4][0];
        float L1 = sm.r.acc[0][tok][e4][1] + sm.r.acc[1][tok][e4][1]
                 + sm.r.acc[2][tok][e4][1] + sm.r.acc[3][tok][e4][1];
        float L2 = sm.r.acc[0][tok][e4][2] + sm.r.acc[1][tok][e4][2]
                 + sm.r.acc[2][tok][e4][2] + sm.r.acc[3][tok][e4][2];
        float L3 = sm.r.acc[0][tok][e4][3] + sm.r.acc[1][tok][e4][3]
                 + sm.r.acc[2][tok][e4][3] + sm.r.acc[3][tok][e4][3];

        float mx = fmaxf(fmaxf(L0, L1), fmaxf(L2, L3));
        mx = fmaxf(mx, __shfl_xor(mx, 1, 4));
        mx = fmaxf(mx, __shfl_xor(mx, 2, 4));
        float P0 = expf(L0 - mx), P1 = expf(L1 - mx);
        float P2 = expf(L2 - mx), P3 = expf(L3 - mx);
        float s = (P0 + P1) + (P2 + P3);
        s += __shfl_xor(s, 1, 4);
        s += __shfl_xor(s, 2, 4);
        float inv = 1.f / s;
        P0 *= inv; P1 *= inv; P2 *= inv; P3 *= inv;

        float4 Pv = {P0, P1, P2, P3};
        *reinterpret_cast<float4*>(scores + (size_t)token * NEXP + e4 * 4) = Pv;

        int base = e4 * 4;
        float v = P0; int idx = base;
        if (P1 > v) { v = P1; idx = base + 1; }
        if (P2 > v) { v = P2; idx = base + 2; }
        if (P3 > v) { v = P3; idx = base + 3; }
#pragma unroll
        for (int m = 1; m < 4; m <<= 1) {
            float vo = __shfl_xor(v, m, 4);
            int io = __shfl_xor(idx, m, 4);
            if (vo > v || (vo == v && io < idx)) { v = vo; idx = io; }
        }
        int i0 = idx; float v0 = v;
        float q0 = (base + 0 == i0) ? -1.f : P0;
        float q1 = (base + 1 == i0) ? -1.f : P1;
        float q2 = (base + 2 == i0) ? -1.f : P2;
        float q3 = (base + 3 == i0) ? -1.f : P3;
        v = q0; idx = base;
        if (q1 > v) { v = q1; idx = base + 1; }
        if (q2 > v) { v = q2; idx = base + 2; }
        if (q3 > v) { v = q3; idx = base + 3; }
#pragma unroll
        for (int m = 1; m < 4; m <<= 1) {
            float vo = __shfl_xor(v, m, 4);
            int io = __shfl_xor(idx, m, 4);
            if (vo > v || (vo == v && io < idx)) { v = vo; idx = io; }
        }
        if (e4 == 0) {
            topk_idx[2 * token] = i0; topk_idx[2 * token + 1] = idx;
            topk_val[2 * token] = v0; topk_val[2 * token + 1] = v;
            float ag = (sm.r.g[0][tok] + sm.r.g[1][tok]) + (sm.r.g[2][tok] + sm.r.g[3][tok]);
            g_shared[token] = 1.f / (1.f + expf(-ag));
        }
        return;
    }

    // ---------- weight transpose+convert, 128x128 tile: fp32 [K][N] -> bf16 [N][K] ----------
    int bx = blockIdx.x - PREP_RTR_BLOCKS;
    const float* src; ushort_t* dst; int K, N, kt, nt;
    if (bx < 512) {                       // w1: per-expert [1024][512], 32 tiles
        int e = bx >> 5, r = bx & 31;
        K = 1024; N = 512; kt = r >> 2; nt = r & 3;
        src = w1 + (size_t)e * K * N; dst = w1t + (size_t)e * K * N;
    } else if (bx < 1024) {               // w2: per-expert [512][1024], 32 tiles
        int b2 = bx - 512, e = b2 >> 5, r = b2 & 31;
        K = 512; N = 1024; kt = r >> 3; nt = r & 7;
        src = w2 + (size_t)e * K * N; dst = w2t + (size_t)e * K * N;
    } else if (bx < 1056) {               // sw1 [1024][512]
        int r = bx - 1024;
        K = 1024; N = 512; kt = r >> 2; nt = r & 3;
        src = sw1; dst = sw1t;
    } else {                              // sw2 [512][1024]
        int r = bx - 1056;
        K = 512; N = 1024; kt = r >> 3; nt = r & 7;
        src = sw2; dst = sw2t;
    }
    int t = threadIdx.x;
    // phase A: read 128 k-rows x 128 n-cols (512B contiguous per wave-row),
    // convert to bf16, store transposed into tileB[n][k].
#pragma unroll 4
    for (int i = 0; i < 16; ++i) {
        int u = t + 256 * i;
        int r = u >> 5;                 // k-local 0..127
        int c4 = (u & 31) * 4;          // n-local 0..124
        float4 v = *reinterpret_cast<const float4*>(
            src + (size_t)(kt * 128 + r) * N + nt * 128 + c4);
        sm.tileB[c4 + 0][r] = f2b(v.x);
        sm.tileB[c4 + 1][r] = f2b(v.y);
        sm.tileB[c4 + 2][r] = f2b(v.z);
        sm.tileB[c4 + 3][r] = f2b(v.w);
    }
    __syncthreads();
    // phase B: write 128 n-rows x 128 k (256B contiguous per wave-row).
#pragma unroll 4
    for (int i2 = 0; i2 < 8; ++i2) {
        int u = t + 256 * i2;
        int n = u >> 4;                 // n-local 0..127
        int kc = (u & 15) * 8;          // k-chunk 0..120
        bf16x8 o;
#pragma unroll
        for (int j = 0; j < 8; ++j) o[j] = (short)sm.tileB[n][kc + j];
        *reinterpret_cast<bf16x8*>(dst + (size_t)(nt * 128 + n) * K + kt * 128 + kc) = o;
    }
}

// ---------------- per-chunk expert histogram ----------------
__global__ __launch_bounds__(256) void hist_kernel(
    const int* __restrict__ topk_idx, int* __restrict__ chunk_hist)
{
    __shared__ int h[NEXP];
    int tid = threadIdx.x;
    if (tid < NEXP) h[tid] = 0;
    __syncthreads();
    int r = blockIdx.x * 256 + tid;
    atomicAdd(&h[topk_idx[r]], 1);
    __syncthreads();
    if (tid < NEXP) chunk_hist[blockIdx.x * NEXP + tid] = h[tid];
}

// ---------------- scan chunk histograms ----------------
__global__ __launch_bounds__(64) void scan_kernel(
    const int* __restrict__ chunk_hist, int* __restrict__ chunk_off,
    int* __restrict__ counts_cap, float* __restrict__ out_tail)
{
    int e = threadIdx.x;
    if (e >= NEXP) return;
    int run = 0;
    for (int b = 0; b < NCHUNK; ++b) {
        chunk_off[b * NEXP + e] = run;
        run += chunk_hist[b * NEXP + e];
    }
    counts_cap[e] = run < CAP ? run : CAP;
    out_tail[NEXP + e] = (float)((double)run / 16384.0);
}

// ---------------- deterministic slot assignment ----------------
__global__ __launch_bounds__(256) void assign_kernel(
    const int* __restrict__ topk_idx, const float* __restrict__ topk_val,
    const int* __restrict__ chunk_off,
    int* __restrict__ route_slot, int* __restrict__ slot_token)
{
    __shared__ int wave_cnt[4][NEXP];
    int tid = threadIdx.x;
    int lane = tid & 63;
    int w = tid >> 6;
    int r = blockIdx.x * 256 + tid;
    int e = topk_idx[r];
    float gate = topk_val[r];
    int rank_w = 0;
#pragma unroll
    for (int e16 = 0; e16 < NEXP; ++e16) {
        unsigned long long bal = __ballot(e == e16);
        if (e == e16) rank_w = __popcll(bal & ((1ull << lane) - 1ull));
        if (lane == 0) wave_cnt[w][e16] = __popcll(bal);
    }
    __syncthreads();
    int rank = rank_w;
#pragma unroll
    for (int w2 = 0; w2 < 3; ++w2)
        if (w2 < w) rank += wave_cnt[w2][e];
    int pos = chunk_off[blockIdx.x * NEXP + e] + rank;
    int slot = -1;
    if (pos < CAP && gate != 0.f) {
        slot = e * CAP + pos;
        slot_token[slot] = r >> 1;
    }
    route_slot[r] = slot;
}

// ---------------- importance reduction ----------------
__global__ __launch_bounds__(256) void importance_kernel(
    const float* __restrict__ scores, float* __restrict__ out_tail)
{
    __shared__ float red[256];
    int e = blockIdx.x;
    float s = 0.f;
    for (int t = threadIdx.x; t < N_TOK; t += 256) s += scores[t * NEXP + e];
    red[threadIdx.x] = s;
    __syncthreads();
    for (int st = 128; st > 0; st >>= 1) {
        if (threadIdx.x < st) red[threadIdx.x] += red[threadIdx.x + st];
        __syncthreads();
    }
    if (threadIdx.x == 0) out_tail[e] = red[0] / (float)N_TOK;
}

// ================= MFMA grouped GEMM 1: h = gelu(Xg @ W1) =================
// 256x128 tile, 8 waves, BK=32, 3-buffer LDS, counted vmcnt(3), setprio, T1+T2.
#define G1_GX (NEXP * 5 + N_TOK / 256)      /* 112 */
#define G1_NWG (G1_GX * (FDIM / 128))       /* 448 */
__global__ __launch_bounds__(512) void gemm1_mfma(
    const ushort_t* __restrict__ xg,        // [ECAP][DIM] bf16 (expert rows)
    const ushort_t* __restrict__ x_bf,      // [N_TOK][DIM] bf16 (shared rows)
    const ushort_t* __restrict__ w1t,       // [16][FDIM][DIM] bf16 n-major
    const ushort_t* __restrict__ sw1t,      // [FDIM][DIM]
    const int* __restrict__ counts_cap,
    ushort_t* __restrict__ h_buf)           // [TOTROW][FDIM] bf16
{
    __shared__ ushort_t As[3][256 * 32];
    __shared__ ushort_t Bs[3][128 * 32];

    int flat = blockIdx.x;
    int wg = (flat & 7) * (G1_NWG / 8) + (flat >> 3);   // T1 (448 % 8 == 0)
    int by = wg & 3;
    int bxg = wg >> 2;

    int g, rb;
    if (bxg < NEXP * 5) { g = bxg / 5; rb = bxg % 5; }
    else { g = NEXP; rb = bxg - NEXP * 5; }
    int Mg = (g < NEXP) ? counts_cap[g] : N_TOK;
    int m0 = rb * 256;
    if (m0 >= Mg) return;
    const ushort_t* Arows = (g < NEXP) ? (xg + ((size_t)g * CAP + m0) * DIM)
                                       : (x_bf + (size_t)m0 * DIM);
    const ushort_t* Bt = (g < NEXP) ? (w1t + (size_t)g * DIM * FDIM) : sw1t;
    int n0 = by * 128;
    int t = threadIdx.x;

    const ushort_t* asrc[2];
    const ushort_t* bsrc;
#pragma unroll
    for (int i = 0; i < 2; ++i) {
        int s = t + i * 512;
        int lr = ((s >> 3) << 1) | ((s >> 2) & 1);
        int qq = (s & 3) ^ ((s >> 3) & 3);
        asrc[i] = Arows + (size_t)lr * DIM + qq * 8;
    }
    {
        int s = t;
        int lr = ((s >> 3) << 1) | ((s >> 2) & 1);
        int qq = (s & 3) ^ ((s >> 3) & 3);
        bsrc = Bt + (size_t)(n0 + lr) * DIM + qq * 8;
    }

    int lane = t & 63;
    int w = t >> 6;
    int wm = (w & 3) * 64, wn = (w >> 2) * 64;
    int l15 = lane & 15, q = lane >> 4;

    int aoff[4], boff[4];
#pragma unroll
    for (int m = 0; m < 4; ++m) aoff[m] = swz_addr16(wm + m * 16 + l15, q) << 3;
#pragma unroll
    for (int n = 0; n < 4; ++n) boff[n] = swz_addr16(wn + n * 16 + l15, q) << 3;

    f32x4 acc[4][4];
#pragma unroll
    for (int m = 0; m < 4; ++m)
#pragma unroll
        for (int n = 0; n < 4; ++n) acc[m][n] = (f32x4){0.f, 0.f, 0.f, 0.f};

    auto STAGE = [&](int buf, int koff) {
        gload16(asrc[0] + koff, &As[buf][t * 8]);
        gload16(asrc[1] + koff, &As[buf][t * 8 + 4096]);
        gload16(bsrc + koff, &Bs[buf][t * 8]);
    };

    const int NSTEP = DIM / 32;   // 32
    STAGE(0, 0);
    STAGE(1, 32);
    asm volatile("s_waitcnt vmcnt(3)" ::: "memory");
    __builtin_amdgcn_s_barrier();
    asm volatile("" ::: "memory");

    int cur = 0, b2 = 2;
    for (int kt = 0; kt < NSTEP; ++kt) {
        if (kt + 2 < NSTEP) STAGE(b2, (kt + 2) * 32);
        const ushort_t* asb = &As[cur][0];
        const ushort_t* bsb = &Bs[cur][0];
        bf16x8 af[4], bfr[4];
#pragma unroll
        for (int m = 0; m < 4; ++m)
            af[m] = *reinterpret_cast<const bf16x8*>(asb + aoff[m]);
#pragma unroll
        for (int n = 0; n < 4; ++n)
            bfr[n] = *reinterpret_cast<const bf16x8*>(bsb + boff[n]);
        __builtin_amdgcn_s_setprio(1);
#pragma unroll
        for (int m = 0; m < 4; ++m)
#pragma unroll
            for (int n = 0; n < 4; ++n)
                acc[m][n] = __builtin_amdgcn_mfma_f32_16x16x32_bf16(
                    af[m], bfr[n], acc[m][n], 0, 0, 0);
        __builtin_amdgcn_s_setprio(0);
        if (kt + 1 < NSTEP) {
            if (kt + 2 < NSTEP) asm volatile("s_waitcnt vmcnt(3)" ::: "memory");
            else                asm volatile("s_waitcnt vmcnt(0)" ::: "memory");
            __builtin_amdgcn_s_barrier();
            asm volatile("" ::: "memory");
        }
        cur = (cur == 2) ? 0 : cur + 1;
        b2  = (b2 == 2) ? 0 : b2 + 1;
    }

    size_t obase = ((g < NEXP) ? (size_t)g * CAP : (size_t)ECAP) + m0;
#pragma unroll
    for (int m = 0; m < 4; ++m) {
#pragma unroll
        for (int r = 0; r < 4; ++r) {
            int grow = wm + m * 16 + q * 4 + r;
            ushort_t* orow = h_buf + (obase + grow) * FDIM + n0 + wn + l15;
#pragma unroll
            for (int n = 0; n < 4; ++n)
                orow[n * 16] = f2b(gelu_fast(acc[m][n][r]));
        }
    }
}

// ================= MFMA grouped GEMM 2: out = H @ W2 =================
// 256x128 tile, 8 waves, BK=32, 2-buffer (48KB, occupancy), setprio, T1+T2.
#define G2_NWG (G1_GX * (DIM / 128))        /* 896 */
__global__ __launch_bounds__(512) void gemm2_mfma(
    const ushort_t* __restrict__ h_buf,     // [TOTROW][FDIM] bf16
    const ushort_t* __restrict__ w2t,       // [16][DIM][FDIM] bf16 n-major
    const ushort_t* __restrict__ sw2t,      // [DIM][FDIM]
    const int* __restrict__ counts_cap,
    const float* __restrict__ g_shared,
    ushort_t* __restrict__ out_buf,         // [ECAP][DIM] bf16
    ushort_t* __restrict__ sh_out)          // [N_TOK][DIM] bf16 (x_bf reuse)
{
    __shared__ ushort_t As[2][256 * 32];
    __shared__ ushort_t Bs[2][128 * 32];

    int flat = blockIdx.x;
    int wg = (flat & 7) * (G2_NWG / 8) + (flat >> 3);
    int by = wg & 7;
    int bxg = wg >> 3;

    int g, rb;
    if (bxg < NEXP * 5) { g = bxg / 5; rb = bxg % 5; }
    else { g = NEXP; rb = bxg - NEXP * 5; }
    int Mg = (g < NEXP) ? counts_cap[g] : N_TOK;
    int m0 = rb * 256;
    if (m0 >= Mg) return;
    size_t abase = ((g < NEXP) ? (size_t)g * CAP : (size_t)ECAP) + m0;
    const ushort_t* Bt = (g < NEXP) ? (w2t + (size_t)g * FDIM * DIM) : sw2t;
    int n0 = by * 128;
    int t = threadIdx.x;

    const ushort_t* asrc[2];
    const ushort_t* bsrc;
#pragma unroll
    for (int i = 0; i < 2; ++i) {
        int s = t + i * 512;
        int lr = ((s >> 3) << 1) | ((s >> 2) & 1);
        int qq = (s & 3) ^ ((s >> 3) & 3);
        asrc[i] = h_buf + (abase + lr) * FDIM + qq * 8;
    }
    {
        int s = t;
        int lr = ((s >> 3) << 1) | ((s >> 2) & 1);
        int qq = (s & 3) ^ ((s >> 3) & 3);
        bsrc = Bt + (size_t)(n0 + lr) * FDIM + qq * 8;
    }

    int lane = t & 63;
    int w = t >> 6;
    int wm = (w & 3) * 64, wn = (w >> 2) * 64;
    int l15 = lane & 15, q = lane >> 4;

    int aoff[4], boff[4];
#pragma unroll
    for (int m = 0; m < 4; ++m) aoff[m] = swz_addr16(wm + m * 16 + l15, q) << 3;
#pragma unroll
    for (int n = 0; n < 4; ++n) boff[n] = swz_addr16(wn + n * 16 + l15, q) << 3;

    f32x4 acc[4][4];
#pragma unroll
    for (int m = 0; m < 4; ++m)
#pragma unroll
        for (int n = 0; n < 4; ++n) acc[m][n] = (f32x4){0.f, 0.f, 0.f, 0.f};

    auto STAGE = [&](int buf, int koff) {
        gload16(asrc[0] + koff, &As[buf][t * 8]);
        gload16(asrc[1] + koff, &As[buf][t * 8 + 4096]);
        gload16(bsrc + koff, &Bs[buf][t * 8]);
    };

    const int NSTEP = FDIM / 32;  // 16
    STAGE(0, 0);
    __syncthreads();

    int cur = 0;
    for (int kt = 0; kt < NSTEP; ++kt) {
        if (kt + 1 < NSTEP) STAGE(cur ^ 1, (kt + 1) * 32);
        const ushort_t* asb = &As[cur][0];
        const ushort_t* bsb = &Bs[cur][0];
        bf16x8 af[4], bfr[4];
#pragma unroll
        for (int m = 0; m < 4; ++m)
            af[m] = *reinterpret_cast<const bf16x8*>(asb + aoff[m]);
#pragma unroll
        for (int n = 0; n < 4; ++n)
            bfr[n] = *reinterpret_cast<const bf16x8*>(bsb + boff[n]);
        __builtin_amdgcn_s_setprio(1);
#pragma unroll
        for (int m = 0; m < 4; ++m)
#pragma unroll
            for (int n = 0; n < 4; ++n)
                acc[m][n] = __builtin_amdgcn_mfma_f32_16x16x32_bf16(
                    af[m], bfr[n], acc[m][n], 0, 0, 0);
        __builtin_amdgcn_s_setprio(0);
        __syncthreads();
        cur ^= 1;
    }

    if (g < NEXP) {
#pragma unroll
        for (int m = 0; m < 4; ++m) {
#pragma unroll
            for (int r = 0; r < 4; ++r) {
                int grow = wm + m * 16 + q * 4 + r;
                ushort_t* orow = out_buf + (abase + grow) * DIM + n0 + wn + l15;
#pragma unroll
                for (int n = 0; n < 4; ++n)
                    orow[n * 16] = f2b(acc[m][n][r]);
            }
        }
    } else {
#pragma unroll
        for (int m = 0; m < 4; ++m) {
#pragma unroll
            for (int r = 0; r < 4; ++r) {
                int tok = m0 + wm + m * 16 + q * 4 + r;
                float gs = g_shared[tok];
                ushort_t* orow = sh_out + (size_t)tok * DIM + n0 + wn + l15;
#pragma unroll
                for (int n = 0; n < 4; ++n)
                    orow[n * 16] = f2b(gs * acc[m][n][r]);
            }
        }
    }
}

// ---------------- combine: y = sh_out + sum(gate * expert_out), write-only ----------------
__global__ __launch_bounds__(256) void combine_kernel(
    const ushort_t* __restrict__ out_buf, const ushort_t* __restrict__ sh_out,
    const int* __restrict__ route_slot, const float* __restrict__ topk_val,
    float* __restrict__ y)
{
    int token = blockIdx.x;
    int c = threadIdx.x * 4;
    ushort4 sv = *reinterpret_cast<const ushort4*>(sh_out + (size_t)token * DIM + c);
    float y0 = bf2f(sv.x), y1 = bf2f(sv.y), y2 = bf2f(sv.z), y3 = bf2f(sv.w);
#pragma unroll
    for (int k = 0; k < 2; ++k) {
        int s = route_slot[2 * token + k];
        if (s >= 0) {
            float gate = topk_val[2 * token + k];
            ushort4 rv = *reinterpret_cast<const ushort4*>(out_buf + (size_t)s * DIM + c);
            y0 += gate * bf2f(rv.x); y1 += gate * bf2f(rv.y);
            y2 += gate * bf2f(rv.z); y3 += gate * bf2f(rv.w);
        }
    }
    float4 o; o.x = y0; o.y = y1; o.z = y2; o.w = y3;
    *reinterpret_cast<float4*>(y + (size_t)token * DIM + c) = o;
}

extern "C" void kernel_launch(void* const* d_in, const int* in_sizes, int n_in,
                              void* d_out, int out_size, void* d_ws, size_t ws_size,
                              hipStream_t stream) {
    const float* x   = (const float*)d_in[0];
    const float* rw  = (const float*)d_in[1];
    const float* sgw = (const float*)d_in[2];
    const float* w1  = (const float*)d_in[3];
    const float* w2  = (const float*)d_in[4];
    const float* sw1 = (const float*)d_in[5];
    const float* sw2 = (const float*)d_in[6];
    float* y = (float*)d_out;
    float* out_tail = y + (size_t)N_TOK * DIM;

    size_t off = 0;
    char* wsb = (char*)d_ws;
    auto alloc = [&](size_t bytes) -> void* {
        void* p = wsb + off;
        off += (bytes + 255) & ~(size_t)255;
        return p;
    };
    float*    scores     = (float*)alloc((size_t)N_TOK * NEXP * 4);
    int*      topk_idx   = (int*)alloc((size_t)NROUTE * 4);
    float*    topk_val   = (float*)alloc((size_t)NROUTE * 4);
    float*    g_shared   = (float*)alloc((size_t)N_TOK * 4);
    int*      chunk_hist = (int*)alloc((size_t)NCHUNK * NEXP * 4);
    int*      chunk_off  = (int*)alloc((size_t)NCHUNK * NEXP * 4);
    int*      counts_cap = (int*)alloc((size_t)NEXP * 4);
    int*      route_slot = (int*)alloc((size_t)NROUTE * 4);
    int*      slot_token = (int*)alloc((size_t)ECAP * 4);
    // xg [ECAP][DIM] aliased with out_buf: xg dead after gemm1.
    char*     xg_union   = (char*)alloc((size_t)ECAP * DIM * 2);
    ushort_t* xg         = (ushort_t*)xg_union;
    ushort_t* out_buf    = (ushort_t*)xg_union;
    // x_bf [N_TOK][DIM] reused as sh_out after gemm1 (x_bf dead post-gemm1).
    ushort_t* x_bf       = (ushort_t*)alloc((size_t)N_TOK * DIM * 2);
    ushort_t* sh_out     = x_bf;
    ushort_t* w1t        = (ushort_t*)alloc((size_t)NEXP * DIM * FDIM * 2);
    ushort_t* w2t        = (ushort_t*)alloc((size_t)NEXP * DIM * FDIM * 2);
    ushort_t* sw1t       = (ushort_t*)alloc((size_t)DIM * FDIM * 2);
    ushort_t* sw2t       = (ushort_t*)alloc((size_t)DIM * FDIM * 2);
    ushort_t* h_buf      = (ushort_t*)alloc((size_t)TOTROW * FDIM * 2);
    (void)ws_size; (void)in_sizes; (void)n_in; (void)out_size;

    prep_kernel<<<PREP_NWG, 256, 0, stream>>>(
        x, rw, sgw, w1, w2, sw1, sw2,
        scores, topk_idx, topk_val, g_shared, x_bf, w1t, w2t, sw1t, sw2t);
    hist_kernel<<<NCHUNK, 256, 0, stream>>>(topk_idx, chunk_hist);
    scan_kernel<<<1, 64, 0, stream>>>(chunk_hist, chunk_off, counts_cap, out_tail);
    assign_kernel<<<NCHUNK, 256, 0, stream>>>(topk_idx, topk_val, chunk_off, route_slot, slot_token);
    importance_kernel<<<NEXP, 256, 0, stream>>>(scores, out_tail);
    gather_x_kernel<<<ECAP, 256, 0, stream>>>(x_bf, slot_token, counts_cap, xg);

    gemm1_mfma<<<G1_NWG, 512, 0, stream>>>(xg, x_bf, w1t, sw1t, counts_cap, h_buf);
    gemm2_mfma<<<G2_NWG, 512, 0, stream>>>(h_buf, w2t, sw2t, counts_cap, g_shared, out_buf, sh_out);

    combine_kernel<<<N_TOK, 256, 0, stream>>>(out_buf, sh_out, route_slot, topk_val, y);
}

// Round 19
// 166.998 us; speedup vs baseline: 1.2064x; 1.0430x over previous
//
#include <hip/hip_runtime.h>
#include <hip/hip_bf16.h>
#include <math.h>

#define N_TOK 8192
#define DIM 1024
#define NEXP 16
#define CAP 1280
#define FDIM 512
#define NROUTE (N_TOK * 2)
#define NCHUNK 64
#define ECAP (NEXP * CAP)        /* 20480 */
#define TOTROW (ECAP + N_TOK)    /* 28672 */

typedef __hip_bfloat16 bf16;
typedef unsigned short ushort_t;
typedef __attribute__((ext_vector_type(8))) short bf16x8;
typedef __attribute__((ext_vector_type(4))) float f32x4;

// tanh-approx gelu via sigmoid; |err| vs erf-gelu ~1e-3 << tolerance.
__device__ __forceinline__ float gelu_fast(float x) {
    float u = 1.5957691216057308f * (x + 0.044715f * x * x * x);
    return x / (1.f + __expf(-u));
}

__device__ __forceinline__ float bf2f(unsigned short u) {
    union { float f; unsigned int i; } v; v.i = ((unsigned int)u) << 16; return v.f;
}

__device__ __forceinline__ unsigned short f2b(float f) {
    union { __hip_bfloat16 h; unsigned short u; } v;
    v.h = __float2bfloat16(f);
    return v.u;
}

__device__ __forceinline__ void gload16(const void* g, void* l) {
    __builtin_amdgcn_global_load_lds(
        (const __attribute__((address_space(1))) unsigned int*)g,
        (__attribute__((address_space(3))) unsigned int*)l,
        16, 0, 0);
}

// T2 both-sides swizzle (verified: SQ_LDS_BANK_CONFLICT -> 0, rounds 5-18)
__device__ __forceinline__ int swz_addr16(int r, int q) {
    return ((r >> 1) << 3) + ((r & 1) << 2) + (q ^ ((r >> 1) & 3));
}

// ---------------- gather expert rows from bf16 copy ----------------
__global__ __launch_bounds__(256) void gather_x_kernel(
    const ushort_t* __restrict__ x_bf, const int* __restrict__ slot_token,
    const int* __restrict__ counts_cap, ushort_t* __restrict__ xg)
{
    int row = blockIdx.x;            // [0, ECAP)
    int e = row / CAP;
    int pos = row - e * CAP;
    int tok = (pos < counts_cap[e]) ? slot_token[row] : 0;
    if ((unsigned)tok >= N_TOK) tok = 0;   // poison guard (gate==0 slots)
    int c = threadIdx.x * 4;
    ushort4 v = *reinterpret_cast<const ushort4*>(x_bf + (size_t)tok * DIM + c);
    *reinterpret_cast<ushort4*>(xg + (size_t)row * DIM + c) = v;
}

// ========== fused prep: router (blocks 0-1023, 8 tok/blk) + transpose (1024-2111) ==========
// Router v6: pass 1 stages x rows into fp32 LDS (coalesced) + fused bf16 emit +
// shared-gate; pass 2 dots from LDS (2-way bank = free) vs L1-hot rw -> no
// global x gathers. Transpose: 128x128 tiles (round-18 layout).
#define PREP_RTR_BLOCKS 1024
#define PREP_NWG (PREP_RTR_BLOCKS + 1088)
__global__ __launch_bounds__(256) void prep_kernel(
    const float* __restrict__ x, const float* __restrict__ rw,
    const float* __restrict__ sgw,
    const float* __restrict__ w1, const float* __restrict__ w2,
    const float* __restrict__ sw1, const float* __restrict__ sw2,
    float* __restrict__ scores,
    int* __restrict__ topk_idx,
    float* __restrict__ topk_val,
    float* __restrict__ g_shared,
    ushort_t* __restrict__ x_bf,
    ushort_t* __restrict__ w1t, ushort_t* __restrict__ w2t,
    ushort_t* __restrict__ sw1t, ushort_t* __restrict__ sw2t)
{
    __shared__ union {
        ushort_t tileB[128][130];            // transpose [n][k] bf16 (32.5KB)
        struct {
            float xl[8][1028];               // router x tile, pad 1028 (32.9KB)
            float racc[4][8][4][4];          // [wave][tok][e4][4]
            float g[4][8];
        } r;
    } sm;

    if (blockIdx.x < PREP_RTR_BLOCKS) {
        // ---------------- router v6 ----------------
        int tid = threadIdx.x;
        int w = tid >> 6;
        int lane = tid & 63;
        int tok0 = blockIdx.x * 8;

        // pass 1: stage x rows -> LDS + bf16 emit + shared-gate partials
        {
            int dq = w * 256 + lane * 4;
            float4 gv = *reinterpret_cast<const float4*>(sgw + dq);
#pragma unroll
            for (int tt = 0; tt < 8; ++tt) {
                const float* xr = x + (size_t)(tok0 + tt) * DIM + dq;
                float4 xv = *reinterpret_cast<const float4*>(xr);
                *reinterpret_cast<float4*>(&sm.r.xl[tt][dq]) = xv;
                ushort4 o;
                o.x = f2b(xv.x); o.y = f2b(xv.y); o.z = f2b(xv.z); o.w = f2b(xv.w);
                *reinterpret_cast<ushort4*>(x_bf + (size_t)(tok0 + tt) * DIM + dq) = o;
                float dg = xv.x * gv.x + xv.y * gv.y + xv.z * gv.z + xv.w * gv.w;
#pragma unroll
                for (int m = 1; m < 64; m <<= 1) dg += __shfl_xor(dg, m, 64);
                if (lane == 0) sm.r.g[w][tt] = dg;
            }
        }
        __syncthreads();

        // pass 2: logits from LDS. lane = (tok:3 | dup:1 | e4:2).
        int tok = lane >> 3;
        int dup = (lane >> 2) & 1;
        int e4 = lane & 3;
        {
            int base_d = w * 256 + dup * 128;
            const float* rwb = rw + (size_t)base_d * NEXP + e4 * 4;
            float4 a0 = {0,0,0,0}, a1 = {0,0,0,0}, a2 = {0,0,0,0}, a3 = {0,0,0,0};
#pragma unroll 4
            for (int i = 0; i < 32; ++i) {
                float4 xv = *reinterpret_cast<const float4*>(&sm.r.xl[tok][base_d + i * 4]);
                const float* rp = rwb + (size_t)i * 4 * NEXP;
                float4 w0 = *reinterpret_cast<const float4*>(rp);
                float4 w1v = *reinterpret_cast<const float4*>(rp + NEXP);
                float4 w2v = *reinterpret_cast<const float4*>(rp + 2 * NEXP);
                float4 w3v = *reinterpret_cast<const float4*>(rp + 3 * NEXP);
                a0.x += xv.x * w0.x;  a0.y += xv.x * w0.y;  a0.z += xv.x * w0.z;  a0.w += xv.x * w0.w;
                a1.x += xv.y * w1v.x; a1.y += xv.y * w1v.y; a1.z += xv.y * w1v.z; a1.w += xv.y * w1v.w;
                a2.x += xv.z * w2v.x; a2.y += xv.z * w2v.y; a2.z += xv.z * w2v.z; a2.w += xv.z * w2v.w;
                a3.x += xv.w * w3v.x; a3.y += xv.w * w3v.y; a3.z += xv.w * w3v.z; a3.w += xv.w * w3v.w;
            }
            float s0 = (a0.x + a1.x) + (a2.x + a3.x);
            float s1 = (a0.y + a1.y) + (a2.y + a3.y);
            float s2 = (a0.z + a1.z) + (a2.z + a3.z);
            float s3 = (a0.w + a1.w) + (a2.w + a3.w);
            // fold dup halves (xor bit 2)
            s0 += __shfl_xor(s0, 4, 64);
            s1 += __shfl_xor(s1, 4, 64);
            s2 += __shfl_xor(s2, 4, 64);
            s3 += __shfl_xor(s3, 4, 64);
            if (dup == 0) {
                sm.r.racc[w][tok][e4][0] = s0;
                sm.r.racc[w][tok][e4][1] = s1;
                sm.r.racc[w][tok][e4][2] = s2;
                sm.r.racc[w][tok][e4][3] = s3;
            }
        }
        __syncthreads();

        if (tid >= 32) return;
        // epilogue: 32 lanes = 8 tok x 4 e4
        int tk = tid >> 2;
        int eq = tid & 3;
        int token = tok0 + tk;
        float L0 = sm.r.racc[0][tk][eq][0] + sm.r.racc[1][tk][eq][0]
                 + sm.r.racc[2][tk][eq][0] + sm.r.racc[3][tk][eq][0];
        float L1 = sm.r.racc[0][tk][eq][1] + sm.r.racc[1][tk][eq][1]
                 + sm.r.racc[2][tk][eq][1] + sm.r.racc[3][tk][eq][1];
        float L2 = sm.r.racc[0][tk][eq][2] + sm.r.racc[1][tk][eq][2]
                 + sm.r.racc[2][tk][eq][2] + sm.r.racc[3][tk][eq][2];
        float L3 = sm.r.racc[0][tk][eq][3] + sm.r.racc[1][tk][eq][3]
                 + sm.r.racc[2][tk][eq][3] + sm.r.racc[3][tk][eq][3];

        float mx = fmaxf(fmaxf(L0, L1), fmaxf(L2, L3));
        mx = fmaxf(mx, __shfl_xor(mx, 1, 4));
        mx = fmaxf(mx, __shfl_xor(mx, 2, 4));
        float P0 = expf(L0 - mx), P1 = expf(L1 - mx);
        float P2 = expf(L2 - mx), P3 = expf(L3 - mx);
        float s = (P0 + P1) + (P2 + P3);
        s += __shfl_xor(s, 1, 4);
        s += __shfl_xor(s, 2, 4);
        float inv = 1.f / s;
        P0 *= inv; P1 *= inv; P2 *= inv; P3 *= inv;

        float4 Pv = {P0, P1, P2, P3};
        *reinterpret_cast<float4*>(scores + (size_t)token * NEXP + eq * 4) = Pv;

        int base = eq * 4;
        float v = P0; int idx = base;
        if (P1 > v) { v = P1; idx = base + 1; }
        if (P2 > v) { v = P2; idx = base + 2; }
        if (P3 > v) { v = P3; idx = base + 3; }
#pragma unroll
        for (int m = 1; m < 4; m <<= 1) {
            float vo = __shfl_xor(v, m, 4);
            int io = __shfl_xor(idx, m, 4);
            if (vo > v || (vo == v && io < idx)) { v = vo; idx = io; }
        }
        int i0 = idx; float v0 = v;
        float q0 = (base + 0 == i0) ? -1.f : P0;
        float q1 = (base + 1 == i0) ? -1.f : P1;
        float q2 = (base + 2 == i0) ? -1.f : P2;
        float q3 = (base + 3 == i0) ? -1.f : P3;
        v = q0; idx = base;
        if (q1 > v) { v = q1; idx = base + 1; }
        if (q2 > v) { v = q2; idx = base + 2; }
        if (q3 > v) { v = q3; idx = base + 3; }
#pragma unroll
        for (int m = 1; m < 4; m <<= 1) {
            float vo = __shfl_xor(v, m, 4);
            int io = __shfl_xor(idx, m, 4);
            if (vo > v || (vo == v && io < idx)) { v = vo; idx = io; }
        }
        if (eq == 0) {
            topk_idx[2 * token] = i0; topk_idx[2 * token + 1] = idx;
            topk_val[2 * token] = v0; topk_val[2 * token + 1] = v;
            float ag = (sm.r.g[0][tk] + sm.r.g[1][tk]) + (sm.r.g[2][tk] + sm.r.g[3][tk]);
            g_shared[token] = 1.f / (1.f + expf(-ag));
        }
        return;
    }

    // ---------- weight transpose+convert, 128x128 tile: fp32 [K][N] -> bf16 [N][K] ----------
    int bx = blockIdx.x - PREP_RTR_BLOCKS;
    const float* src; ushort_t* dst; int K, N, kt, nt;
    if (bx < 512) {                       // w1: per-expert [1024][512], 32 tiles
        int e = bx >> 5, r = bx & 31;
        K = 1024; N = 512; kt = r >> 2; nt = r & 3;
        src = w1 + (size_t)e * K * N; dst = w1t + (size_t)e * K * N;
    } else if (bx < 1024) {               // w2: per-expert [512][1024], 32 tiles
        int b2 = bx - 512, e = b2 >> 5, r = b2 & 31;
        K = 512; N = 1024; kt = r >> 3; nt = r & 7;
        src = w2 + (size_t)e * K * N; dst = w2t + (size_t)e * K * N;
    } else if (bx < 1056) {               // sw1 [1024][512]
        int r = bx - 1024;
        K = 1024; N = 512; kt = r >> 2; nt = r & 3;
        src = sw1; dst = sw1t;
    } else {                              // sw2 [512][1024]
        int r = bx - 1056;
        K = 512; N = 1024; kt = r >> 3; nt = r & 7;
        src = sw2; dst = sw2t;
    }
    int t = threadIdx.x;
#pragma unroll 4
    for (int i = 0; i < 16; ++i) {
        int u = t + 256 * i;
        int r = u >> 5;                 // k-local 0..127
        int c4 = (u & 31) * 4;          // n-local 0..124
        float4 v = *reinterpret_cast<const float4*>(
            src + (size_t)(kt * 128 + r) * N + nt * 128 + c4);
        sm.tileB[c4 + 0][r] = f2b(v.x);
        sm.tileB[c4 + 1][r] = f2b(v.y);
        sm.tileB[c4 + 2][r] = f2b(v.z);
        sm.tileB[c4 + 3][r] = f2b(v.w);
    }
    __syncthreads();
#pragma unroll 4
    for (int i2 = 0; i2 < 8; ++i2) {
        int u = t + 256 * i2;
        int n = u >> 4;                 // n-local 0..127
        int kc = (u & 15) * 8;          // k-chunk 0..120
        bf16x8 o;
#pragma unroll
        for (int j = 0; j < 8; ++j) o[j] = (short)sm.tileB[n][kc + j];
        *reinterpret_cast<bf16x8*>(dst + (size_t)(nt * 128 + n) * K + kt * 128 + kc) = o;
    }
}

// ---------------- per-chunk expert histogram ----------------
__global__ __launch_bounds__(256) void hist_kernel(
    const int* __restrict__ topk_idx, int* __restrict__ chunk_hist)
{
    __shared__ int h[NEXP];
    int tid = threadIdx.x;
    if (tid < NEXP) h[tid] = 0;
    __syncthreads();
    int r = blockIdx.x * 256 + tid;
    atomicAdd(&h[topk_idx[r]], 1);
    __syncthreads();
    if (tid < NEXP) chunk_hist[blockIdx.x * NEXP + tid] = h[tid];
}

// ---------------- scan chunk histograms ----------------
__global__ __launch_bounds__(64) void scan_kernel(
    const int* __restrict__ chunk_hist, int* __restrict__ chunk_off,
    int* __restrict__ counts_cap, float* __restrict__ out_tail)
{
    int e = threadIdx.x;
    if (e >= NEXP) return;
    int run = 0;
    for (int b = 0; b < NCHUNK; ++b) {
        chunk_off[b * NEXP + e] = run;
        run += chunk_hist[b * NEXP + e];
    }
    counts_cap[e] = run < CAP ? run : CAP;
    out_tail[NEXP + e] = (float)((double)run / 16384.0);
}

// ---------------- deterministic slot assignment ----------------
__global__ __launch_bounds__(256) void assign_kernel(
    const int* __restrict__ topk_idx, const float* __restrict__ topk_val,
    const int* __restrict__ chunk_off,
    int* __restrict__ route_slot, int* __restrict__ slot_token)
{
    __shared__ int wave_cnt[4][NEXP];
    int tid = threadIdx.x;
    int lane = tid & 63;
    int w = tid >> 6;
    int r = blockIdx.x * 256 + tid;
    int e = topk_idx[r];
    float gate = topk_val[r];
    int rank_w = 0;
#pragma unroll
    for (int e16 = 0; e16 < NEXP; ++e16) {
        unsigned long long bal = __ballot(e == e16);
        if (e == e16) rank_w = __popcll(bal & ((1ull << lane) - 1ull));
        if (lane == 0) wave_cnt[w][e16] = __popcll(bal);
    }
    __syncthreads();
    int rank = rank_w;
#pragma unroll
    for (int w2 = 0; w2 < 3; ++w2)
        if (w2 < w) rank += wave_cnt[w2][e];
    int pos = chunk_off[blockIdx.x * NEXP + e] + rank;
    int slot = -1;
    if (pos < CAP && gate != 0.f) {
        slot = e * CAP + pos;
        slot_token[slot] = r >> 1;
    }
    route_slot[r] = slot;
}

// ---------------- importance reduction ----------------
__global__ __launch_bounds__(256) void importance_kernel(
    const float* __restrict__ scores, float* __restrict__ out_tail)
{
    __shared__ float red[256];
    int e = blockIdx.x;
    float s = 0.f;
    for (int t = threadIdx.x; t < N_TOK; t += 256) s += scores[t * NEXP + e];
    red[threadIdx.x] = s;
    __syncthreads();
    for (int st = 128; st > 0; st >>= 1) {
        if (threadIdx.x < st) red[threadIdx.x] += red[threadIdx.x + st];
        __syncthreads();
    }
    if (threadIdx.x == 0) out_tail[e] = red[0] / (float)N_TOK;
}

// ================= MFMA grouped GEMM 1: h = gelu(Xg @ W1) =================
// 256x128 tile, 8 waves, BK=32, 3-buffer LDS, counted vmcnt(3), setprio, T1+T2.
#define G1_GX (NEXP * 5 + N_TOK / 256)      /* 112 */
#define G1_NWG (G1_GX * (FDIM / 128))       /* 448 */
__global__ __launch_bounds__(512) void gemm1_mfma(
    const ushort_t* __restrict__ xg,        // [ECAP][DIM] bf16 (expert rows)
    const ushort_t* __restrict__ x_bf,      // [N_TOK][DIM] bf16 (shared rows)
    const ushort_t* __restrict__ w1t,       // [16][FDIM][DIM] bf16 n-major
    const ushort_t* __restrict__ sw1t,      // [FDIM][DIM]
    const int* __restrict__ counts_cap,
    ushort_t* __restrict__ h_buf)           // [TOTROW][FDIM] bf16
{
    __shared__ ushort_t As[3][256 * 32];
    __shared__ ushort_t Bs[3][128 * 32];

    int flat = blockIdx.x;
    int wg = (flat & 7) * (G1_NWG / 8) + (flat >> 3);   // T1 (448 % 8 == 0)
    int by = wg & 3;
    int bxg = wg >> 2;

    int g, rb;
    if (bxg < NEXP * 5) { g = bxg / 5; rb = bxg % 5; }
    else { g = NEXP; rb = bxg - NEXP * 5; }
    int Mg = (g < NEXP) ? counts_cap[g] : N_TOK;
    int m0 = rb * 256;
    if (m0 >= Mg) return;
    const ushort_t* Arows = (g < NEXP) ? (xg + ((size_t)g * CAP + m0) * DIM)
                                       : (x_bf + (size_t)m0 * DIM);
    const ushort_t* Bt = (g < NEXP) ? (w1t + (size_t)g * DIM * FDIM) : sw1t;
    int n0 = by * 128;
    int t = threadIdx.x;

    const ushort_t* asrc[2];
    const ushort_t* bsrc;
#pragma unroll
    for (int i = 0; i < 2; ++i) {
        int s = t + i * 512;
        int lr = ((s >> 3) << 1) | ((s >> 2) & 1);
        int qq = (s & 3) ^ ((s >> 3) & 3);
        asrc[i] = Arows + (size_t)lr * DIM + qq * 8;
    }
    {
        int s = t;
        int lr = ((s >> 3) << 1) | ((s >> 2) & 1);
        int qq = (s & 3) ^ ((s >> 3) & 3);
        bsrc = Bt + (size_t)(n0 + lr) * DIM + qq * 8;
    }

    int lane = t & 63;
    int w = t >> 6;
    int wm = (w & 3) * 64, wn = (w >> 2) * 64;
    int l15 = lane & 15, q = lane >> 4;

    int aoff[4], boff[4];
#pragma unroll
    for (int m = 0; m < 4; ++m) aoff[m] = swz_addr16(wm + m * 16 + l15, q) << 3;
#pragma unroll
    for (int n = 0; n < 4; ++n) boff[n] = swz_addr16(wn + n * 16 + l15, q) << 3;

    f32x4 acc[4][4];
#pragma unroll
    for (int m = 0; m < 4; ++m)
#pragma unroll
        for (int n = 0; n < 4; ++n) acc[m][n] = (f32x4){0.f, 0.f, 0.f, 0.f};

    auto STAGE = [&](int buf, int koff) {
        gload16(asrc[0] + koff, &As[buf][t * 8]);
        gload16(asrc[1] + koff, &As[buf][t * 8 + 4096]);
        gload16(bsrc + koff, &Bs[buf][t * 8]);
    };

    const int NSTEP = DIM / 32;   // 32
    STAGE(0, 0);
    STAGE(1, 32);
    asm volatile("s_waitcnt vmcnt(3)" ::: "memory");
    __builtin_amdgcn_s_barrier();
    asm volatile("" ::: "memory");

    int cur = 0, b2 = 2;
    for (int kt = 0; kt < NSTEP; ++kt) {
        if (kt + 2 < NSTEP) STAGE(b2, (kt + 2) * 32);
        const ushort_t* asb = &As[cur][0];
        const ushort_t* bsb = &Bs[cur][0];
        bf16x8 af[4], bfr[4];
#pragma unroll
        for (int m = 0; m < 4; ++m)
            af[m] = *reinterpret_cast<const bf16x8*>(asb + aoff[m]);
#pragma unroll
        for (int n = 0; n < 4; ++n)
            bfr[n] = *reinterpret_cast<const bf16x8*>(bsb + boff[n]);
        __builtin_amdgcn_s_setprio(1);
#pragma unroll
        for (int m = 0; m < 4; ++m)
#pragma unroll
            for (int n = 0; n < 4; ++n)
                acc[m][n] = __builtin_amdgcn_mfma_f32_16x16x32_bf16(
                    af[m], bfr[n], acc[m][n], 0, 0, 0);
        __builtin_amdgcn_s_setprio(0);
        if (kt + 1 < NSTEP) {
            if (kt + 2 < NSTEP) asm volatile("s_waitcnt vmcnt(3)" ::: "memory");
            else                asm volatile("s_waitcnt vmcnt(0)" ::: "memory");
            __builtin_amdgcn_s_barrier();
            asm volatile("" ::: "memory");
        }
        cur = (cur == 2) ? 0 : cur + 1;
        b2  = (b2 == 2) ? 0 : b2 + 1;
    }

    size_t obase = ((g < NEXP) ? (size_t)g * CAP : (size_t)ECAP) + m0;
#pragma unroll
    for (int m = 0; m < 4; ++m) {
#pragma unroll
        for (int r = 0; r < 4; ++r) {
            int grow = wm + m * 16 + q * 4 + r;
            ushort_t* orow = h_buf + (obase + grow) * FDIM + n0 + wn + l15;
#pragma unroll
            for (int n = 0; n < 4; ++n)
                orow[n * 16] = f2b(gelu_fast(acc[m][n][r]));
        }
    }
}

// ================= MFMA grouped GEMM 2: out = H @ W2 =================
// 256x128 tile, 8 waves, BK=32, 2-buffer (48KB, occupancy), setprio, T1+T2.
#define G2_NWG (G1_GX * (DIM / 128))        /* 896 */
__global__ __launch_bounds__(512) void gemm2_mfma(
    const ushort_t* __restrict__ h_buf,     // [TOTROW][FDIM] bf16
    const ushort_t* __restrict__ w2t,       // [16][DIM][FDIM] bf16 n-major
    const ushort_t* __restrict__ sw2t,      // [DIM][FDIM]
    const int* __restrict__ counts_cap,
    const float* __restrict__ g_shared,
    ushort_t* __restrict__ out_buf,         // [ECAP][DIM] bf16
    ushort_t* __restrict__ sh_out)          // [N_TOK][DIM] bf16 (x_bf reuse)
{
    __shared__ ushort_t As[2][256 * 32];
    __shared__ ushort_t Bs[2][128 * 32];

    int flat = blockIdx.x;
    int wg = (flat & 7) * (G2_NWG / 8) + (flat >> 3);
    int by = wg & 7;
    int bxg = wg >> 3;

    int g, rb;
    if (bxg < NEXP * 5) { g = bxg / 5; rb = bxg % 5; }
    else { g = NEXP; rb = bxg - NEXP * 5; }
    int Mg = (g < NEXP) ? counts_cap[g] : N_TOK;
    int m0 = rb * 256;
    if (m0 >= Mg) return;
    size_t abase = ((g < NEXP) ? (size_t)g * CAP : (size_t)ECAP) + m0;
    const ushort_t* Bt = (g < NEXP) ? (w2t + (size_t)g * FDIM * DIM) : sw2t;
    int n0 = by * 128;
    int t = threadIdx.x;

    const ushort_t* asrc[2];
    const ushort_t* bsrc;
#pragma unroll
    for (int i = 0; i < 2; ++i) {
        int s = t + i * 512;
        int lr = ((s >> 3) << 1) | ((s >> 2) & 1);
        int qq = (s & 3) ^ ((s >> 3) & 3);
        asrc[i] = h_buf + (abase + lr) * FDIM + qq * 8;
    }
    {
        int s = t;
        int lr = ((s >> 3) << 1) | ((s >> 2) & 1);
        int qq = (s & 3) ^ ((s >> 3) & 3);
        bsrc = Bt + (size_t)(n0 + lr) * FDIM + qq * 8;
    }

    int lane = t & 63;
    int w = t >> 6;
    int wm = (w & 3) * 64, wn = (w >> 2) * 64;
    int l15 = lane & 15, q = lane >> 4;

    int aoff[4], boff[4];
#pragma unroll
    for (int m = 0; m < 4; ++m) aoff[m] = swz_addr16(wm + m * 16 + l15, q) << 3;
#pragma unroll
    for (int n = 0; n < 4; ++n) boff[n] = swz_addr16(wn + n * 16 + l15, q) << 3;

    f32x4 acc[4][4];
#pragma unroll
    for (int m = 0; m < 4; ++m)
#pragma unroll
        for (int n = 0; n < 4; ++n) acc[m][n] = (f32x4){0.f, 0.f, 0.f, 0.f};

    auto STAGE = [&](int buf, int koff) {
        gload16(asrc[0] + koff, &As[buf][t * 8]);
        gload16(asrc[1] + koff, &As[buf][t * 8 + 4096]);
        gload16(bsrc + koff, &Bs[buf][t * 8]);
    };

    const int NSTEP = FDIM / 32;  // 16
    STAGE(0, 0);
    __syncthreads();

    int cur = 0;
    for (int kt = 0; kt < NSTEP; ++kt) {
        if (kt + 1 < NSTEP) STAGE(cur ^ 1, (kt + 1) * 32);
        const ushort_t* asb = &As[cur][0];
        const ushort_t* bsb = &Bs[cur][0];
        bf16x8 af[4], bfr[4];
#pragma unroll
        for (int m = 0; m < 4; ++m)
            af[m] = *reinterpret_cast<const bf16x8*>(asb + aoff[m]);
#pragma unroll
        for (int n = 0; n < 4; ++n)
            bfr[n] = *reinterpret_cast<const bf16x8*>(bsb + boff[n]);
        __builtin_amdgcn_s_setprio(1);
#pragma unroll
        for (int m = 0; m < 4; ++m)
#pragma unroll
            for (int n = 0; n < 4; ++n)
                acc[m][n] = __builtin_amdgcn_mfma_f32_16x16x32_bf16(
                    af[m], bfr[n], acc[m][n], 0, 0, 0);
        __builtin_amdgcn_s_setprio(0);
        __syncthreads();
        cur ^= 1;
    }

    if (g < NEXP) {
#pragma unroll
        for (int m = 0; m < 4; ++m) {
#pragma unroll
            for (int r = 0; r < 4; ++r) {
                int grow = wm + m * 16 + q * 4 + r;
                ushort_t* orow = out_buf + (abase + grow) * DIM + n0 + wn + l15;
#pragma unroll
                for (int n = 0; n < 4; ++n)
                    orow[n * 16] = f2b(acc[m][n][r]);
            }
        }
    } else {
#pragma unroll
        for (int m = 0; m < 4; ++m) {
#pragma unroll
            for (int r = 0; r < 4; ++r) {
                int tok = m0 + wm + m * 16 + q * 4 + r;
                float gs = g_shared[tok];
                ushort_t* orow = sh_out + (size_t)tok * DIM + n0 + wn + l15;
#pragma unroll
                for (int n = 0; n < 4; ++n)
                    orow[n * 16] = f2b(gs * acc[m][n][r]);
            }
        }
    }
}

// ---------------- combine: y = sh_out + sum(gate * expert_out), write-only ----------------
__global__ __launch_bounds__(256) void combine_kernel(
    const ushort_t* __restrict__ out_buf, const ushort_t* __restrict__ sh_out,
    const int* __restrict__ route_slot, const float* __restrict__ topk_val,
    float* __restrict__ y)
{
    int token = blockIdx.x;
    int c = threadIdx.x * 4;
    ushort4 sv = *reinterpret_cast<const ushort4*>(sh_out + (size_t)token * DIM + c);
    float y0 = bf2f(sv.x), y1 = bf2f(sv.y), y2 = bf2f(sv.z), y3 = bf2f(sv.w);
#pragma unroll
    for (int k = 0; k < 2; ++k) {
        int s = route_slot[2 * token + k];
        if (s >= 0) {
            float gate = topk_val[2 * token + k];
            ushort4 rv = *reinterpret_cast<const ushort4*>(out_buf + (size_t)s * DIM + c);
            y0 += gate * bf2f(rv.x); y1 += gate * bf2f(rv.y);
            y2 += gate * bf2f(rv.z); y3 += gate * bf2f(rv.w);
        }
    }
    float4 o; o.x = y0; o.y = y1; o.z = y2; o.w = y3;
    *reinterpret_cast<float4*>(y + (size_t)token * DIM + c) = o;
}

extern "C" void kernel_launch(void* const* d_in, const int* in_sizes, int n_in,
                              void* d_out, int out_size, void* d_ws, size_t ws_size,
                              hipStream_t stream) {
    const float* x   = (const float*)d_in[0];
    const float* rw  = (const float*)d_in[1];
    const float* sgw = (const float*)d_in[2];
    const float* w1  = (const float*)d_in[3];
    const float* w2  = (const float*)d_in[4];
    const float* sw1 = (const float*)d_in[5];
    const float* sw2 = (const float*)d_in[6];
    float* y = (float*)d_out;
    float* out_tail = y + (size_t)N_TOK * DIM;

    size_t off = 0;
    char* wsb = (char*)d_ws;
    auto alloc = [&](size_t bytes) -> void* {
        void* p = wsb + off;
        off += (bytes + 255) & ~(size_t)255;
        return p;
    };
    float*    scores     = (float*)alloc((size_t)N_TOK * NEXP * 4);
    int*      topk_idx   = (int*)alloc((size_t)NROUTE * 4);
    float*    topk_val   = (float*)alloc((size_t)NROUTE * 4);
    float*    g_shared   = (float*)alloc((size_t)N_TOK * 4);
    int*      chunk_hist = (int*)alloc((size_t)NCHUNK * NEXP * 4);
    int*      chunk_off  = (int*)alloc((size_t)NCHUNK * NEXP * 4);
    int*      counts_cap = (int*)alloc((size_t)NEXP * 4);
    int*      route_slot = (int*)alloc((size_t)NROUTE * 4);
    int*      slot_token = (int*)alloc((size_t)ECAP * 4);
    // xg [ECAP][DIM] aliased with out_buf: xg dead after gemm1.
    char*     xg_union   = (char*)alloc((size_t)ECAP * DIM * 2);
    ushort_t* xg         = (ushort_t*)xg_union;
    ushort_t* out_buf    = (ushort_t*)xg_union;
    // x_bf [N_TOK][DIM] reused as sh_out after gemm1 (x_bf dead post-gemm1).
    ushort_t* x_bf       = (ushort_t*)alloc((size_t)N_TOK * DIM * 2);
    ushort_t* sh_out     = x_bf;
    ushort_t* w1t        = (ushort_t*)alloc((size_t)NEXP * DIM * FDIM * 2);
    ushort_t* w2t        = (ushort_t*)alloc((size_t)NEXP * DIM * FDIM * 2);
    ushort_t* sw1t       = (ushort_t*)alloc((size_t)DIM * FDIM * 2);
    ushort_t* sw2t       = (ushort_t*)alloc((size_t)DIM * FDIM * 2);
    ushort_t* h_buf      = (ushort_t*)alloc((size_t)TOTROW * FDIM * 2);
    (void)ws_size; (void)in_sizes; (void)n_in; (void)out_size;

    prep_kernel<<<PREP_NWG, 256, 0, stream>>>(
        x, rw, sgw, w1, w2, sw1, sw2,
        scores, topk_idx, topk_val, g_shared, x_bf, w1t, w2t, sw1t, sw2t);
    hist_kernel<<<NCHUNK, 256, 0, stream>>>(topk_idx, chunk_hist);
    scan_kernel<<<1, 64, 0, stream>>>(chunk_hist, chunk_off, counts_cap, out_tail);
    assign_kernel<<<NCHUNK, 256, 0, stream>>>(topk_idx, topk_val, chunk_off, route_slot, slot_token);
    importance_kernel<<<NEXP, 256, 0, stream>>>(scores, out_tail);
    gather_x_kernel<<<ECAP, 256, 0, stream>>>(x_bf, slot_token, counts_cap, xg);

    gemm1_mfma<<<G1_NWG, 512, 0, stream>>>(xg, x_bf, w1t, sw1t, counts_cap, h_buf);
    gemm2_mfma<<<G2_NWG, 512, 0, stream>>>(h_buf, w2t, sw2t, counts_cap, g_shared, out_buf, sh_out);

    combine_kernel<<<N_TOK, 256, 0, stream>>>(out_buf, sh_out, route_slot, topk_val, y);
}

// Round 20
// 153.226 us; speedup vs baseline: 1.3149x; 1.0899x over previous
//
#include <hip/hip_runtime.h>
#include <hip/hip_bf16.h>
#include <math.h>

#define N_TOK 8192
#define DIM 1024
#define NEXP 16
#define CAP 1280
#define FDIM 512
#define NROUTE (N_TOK * 2)
#define NCHUNK 64
#define ECAP (NEXP * CAP)        /* 20480 */
#define TOTROW (ECAP + N_TOK)    /* 28672 */

typedef __hip_bfloat16 bf16;
typedef unsigned short ushort_t;
typedef __attribute__((ext_vector_type(8))) short bf16x8;
typedef __attribute__((ext_vector_type(4))) float f32x4;

// tanh-approx gelu via sigmoid; |err| vs erf-gelu ~1e-3 << tolerance.
__device__ __forceinline__ float gelu_fast(float x) {
    float u = 1.5957691216057308f * (x + 0.044715f * x * x * x);
    return x / (1.f + __expf(-u));
}

__device__ __forceinline__ float bf2f(unsigned short u) {
    union { float f; unsigned int i; } v; v.i = ((unsigned int)u) << 16; return v.f;
}

__device__ __forceinline__ unsigned short f2b(float f) {
    union { __hip_bfloat16 h; unsigned short u; } v;
    v.h = __float2bfloat16(f);
    return v.u;
}

__device__ __forceinline__ void gload16(const void* g, void* l) {
    __builtin_amdgcn_global_load_lds(
        (const __attribute__((address_space(1))) unsigned int*)g,
        (__attribute__((address_space(3))) unsigned int*)l,
        16, 0, 0);
}

// T2 both-sides swizzle (verified: SQ_LDS_BANK_CONFLICT -> 0 in GEMMs, rounds 5-19)
__device__ __forceinline__ int swz_addr16(int r, int q) {
    return ((r >> 1) << 3) + ((r & 1) << 2) + (q ^ ((r >> 1) & 3));
}

// ========== fused prep: router (blocks 0-1023, 8 tok/blk) + transpose (1024-2111) ==========
// Router v6 (round-19 proven). Transpose: 128x128 tiles, LDS pad 129 (odd
// halfword stride -> phase-A scalar-store conflicts 4-way -> 2-way = free).
#define PREP_RTR_BLOCKS 1024
#define PREP_NWG (PREP_RTR_BLOCKS + 1088)
__global__ __launch_bounds__(256) void prep_kernel(
    const float* __restrict__ x, const float* __restrict__ rw,
    const float* __restrict__ sgw,
    const float* __restrict__ w1, const float* __restrict__ w2,
    const float* __restrict__ sw1, const float* __restrict__ sw2,
    float* __restrict__ scores,
    int* __restrict__ topk_idx,
    float* __restrict__ topk_val,
    float* __restrict__ g_shared,
    ushort_t* __restrict__ x_bf,
    ushort_t* __restrict__ w1t, ushort_t* __restrict__ w2t,
    ushort_t* __restrict__ sw1t, ushort_t* __restrict__ sw2t)
{
    __shared__ union {
        ushort_t tileB[128][129];            // transpose [n][k] bf16, pad 129 (33KB)
        struct {
            float xl[8][1028];               // router x tile (32.9KB)
            float racc[4][8][4][4];          // [wave][tok][e4][4]
            float g[4][8];
        } r;
    } sm;

    if (blockIdx.x < PREP_RTR_BLOCKS) {
        // ---------------- router v6 ----------------
        int tid = threadIdx.x;
        int w = tid >> 6;
        int lane = tid & 63;
        int tok0 = blockIdx.x * 8;

        // pass 1: stage x rows -> LDS + bf16 emit + shared-gate partials
        {
            int dq = w * 256 + lane * 4;
            float4 gv = *reinterpret_cast<const float4*>(sgw + dq);
#pragma unroll
            for (int tt = 0; tt < 8; ++tt) {
                const float* xr = x + (size_t)(tok0 + tt) * DIM + dq;
                float4 xv = *reinterpret_cast<const float4*>(xr);
                *reinterpret_cast<float4*>(&sm.r.xl[tt][dq]) = xv;
                ushort4 o;
                o.x = f2b(xv.x); o.y = f2b(xv.y); o.z = f2b(xv.z); o.w = f2b(xv.w);
                *reinterpret_cast<ushort4*>(x_bf + (size_t)(tok0 + tt) * DIM + dq) = o;
                float dg = xv.x * gv.x + xv.y * gv.y + xv.z * gv.z + xv.w * gv.w;
#pragma unroll
                for (int m = 1; m < 64; m <<= 1) dg += __shfl_xor(dg, m, 64);
                if (lane == 0) sm.r.g[w][tt] = dg;
            }
        }
        __syncthreads();

        // pass 2: logits from LDS. lane = (tok:3 | dup:1 | e4:2).
        int tok = lane >> 3;
        int dup = (lane >> 2) & 1;
        int e4 = lane & 3;
        {
            int base_d = w * 256 + dup * 128;
            const float* rwb = rw + (size_t)base_d * NEXP + e4 * 4;
            float4 a0 = {0,0,0,0}, a1 = {0,0,0,0}, a2 = {0,0,0,0}, a3 = {0,0,0,0};
#pragma unroll 4
            for (int i = 0; i < 32; ++i) {
                float4 xv = *reinterpret_cast<const float4*>(&sm.r.xl[tok][base_d + i * 4]);
                const float* rp = rwb + (size_t)i * 4 * NEXP;
                float4 w0 = *reinterpret_cast<const float4*>(rp);
                float4 w1v = *reinterpret_cast<const float4*>(rp + NEXP);
                float4 w2v = *reinterpret_cast<const float4*>(rp + 2 * NEXP);
                float4 w3v = *reinterpret_cast<const float4*>(rp + 3 * NEXP);
                a0.x += xv.x * w0.x;  a0.y += xv.x * w0.y;  a0.z += xv.x * w0.z;  a0.w += xv.x * w0.w;
                a1.x += xv.y * w1v.x; a1.y += xv.y * w1v.y; a1.z += xv.y * w1v.z; a1.w += xv.y * w1v.w;
                a2.x += xv.z * w2v.x; a2.y += xv.z * w2v.y; a2.z += xv.z * w2v.z; a2.w += xv.z * w2v.w;
                a3.x += xv.w * w3v.x; a3.y += xv.w * w3v.y; a3.z += xv.w * w3v.z; a3.w += xv.w * w3v.w;
            }
            float s0 = (a0.x + a1.x) + (a2.x + a3.x);
            float s1 = (a0.y + a1.y) + (a2.y + a3.y);
            float s2 = (a0.z + a1.z) + (a2.z + a3.z);
            float s3 = (a0.w + a1.w) + (a2.w + a3.w);
            s0 += __shfl_xor(s0, 4, 64);
            s1 += __shfl_xor(s1, 4, 64);
            s2 += __shfl_xor(s2, 4, 64);
            s3 += __shfl_xor(s3, 4, 64);
            if (dup == 0) {
                sm.r.racc[w][tok][e4][0] = s0;
                sm.r.racc[w][tok][e4][1] = s1;
                sm.r.racc[w][tok][e4][2] = s2;
                sm.r.racc[w][tok][e4][3] = s3;
            }
        }
        __syncthreads();

        if (tid >= 32) return;
        int tk = tid >> 2;
        int eq = tid & 3;
        int token = tok0 + tk;
        float L0 = sm.r.racc[0][tk][eq][0] + sm.r.racc[1][tk][eq][0]
                 + sm.r.racc[2][tk][eq][0] + sm.r.racc[3][tk][eq][0];
        float L1 = sm.r.racc[0][tk][eq][1] + sm.r.racc[1][tk][eq][1]
                 + sm.r.racc[2][tk][eq][1] + sm.r.racc[3][tk][eq][1];
        float L2 = sm.r.racc[0][tk][eq][2] + sm.r.racc[1][tk][eq][2]
                 + sm.r.racc[2][tk][eq][2] + sm.r.racc[3][tk][eq][2];
        float L3 = sm.r.racc[0][tk][eq][3] + sm.r.racc[1][tk][eq][3]
                 + sm.r.racc[2][tk][eq][3] + sm.r.racc[3][tk][eq][3];

        float mx = fmaxf(fmaxf(L0, L1), fmaxf(L2, L3));
        mx = fmaxf(mx, __shfl_xor(mx, 1, 4));
        mx = fmaxf(mx, __shfl_xor(mx, 2, 4));
        float P0 = expf(L0 - mx), P1 = expf(L1 - mx);
        float P2 = expf(L2 - mx), P3 = expf(L3 - mx);
        float s = (P0 + P1) + (P2 + P3);
        s += __shfl_xor(s, 1, 4);
        s += __shfl_xor(s, 2, 4);
        float inv = 1.f / s;
        P0 *= inv; P1 *= inv; P2 *= inv; P3 *= inv;

        float4 Pv = {P0, P1, P2, P3};
        *reinterpret_cast<float4*>(scores + (size_t)token * NEXP + eq * 4) = Pv;

        int base = eq * 4;
        float v = P0; int idx = base;
        if (P1 > v) { v = P1; idx = base + 1; }
        if (P2 > v) { v = P2; idx = base + 2; }
        if (P3 > v) { v = P3; idx = base + 3; }
#pragma unroll
        for (int m = 1; m < 4; m <<= 1) {
            float vo = __shfl_xor(v, m, 4);
            int io = __shfl_xor(idx, m, 4);
            if (vo > v || (vo == v && io < idx)) { v = vo; idx = io; }
        }
        int i0 = idx; float v0 = v;
        float q0 = (base + 0 == i0) ? -1.f : P0;
        float q1 = (base + 1 == i0) ? -1.f : P1;
        float q2 = (base + 2 == i0) ? -1.f : P2;
        float q3 = (base + 3 == i0) ? -1.f : P3;
        v = q0; idx = base;
        if (q1 > v) { v = q1; idx = base + 1; }
        if (q2 > v) { v = q2; idx = base + 2; }
        if (q3 > v) { v = q3; idx = base + 3; }
#pragma unroll
        for (int m = 1; m < 4; m <<= 1) {
            float vo = __shfl_xor(v, m, 4);
            int io = __shfl_xor(idx, m, 4);
            if (vo > v || (vo == v && io < idx)) { v = vo; idx = io; }
        }
        if (eq == 0) {
            topk_idx[2 * token] = i0; topk_idx[2 * token + 1] = idx;
            topk_val[2 * token] = v0; topk_val[2 * token + 1] = v;
            float ag = (sm.r.g[0][tk] + sm.r.g[1][tk]) + (sm.r.g[2][tk] + sm.r.g[3][tk]);
            g_shared[token] = 1.f / (1.f + expf(-ag));
        }
        return;
    }

    // ---------- weight transpose+convert, 128x128 tile: fp32 [K][N] -> bf16 [N][K] ----------
    int bx = blockIdx.x - PREP_RTR_BLOCKS;
    const float* src; ushort_t* dst; int K, N, kt, nt;
    if (bx < 512) {                       // w1: per-expert [1024][512], 32 tiles
        int e = bx >> 5, r = bx & 31;
        K = 1024; N = 512; kt = r >> 2; nt = r & 3;
        src = w1 + (size_t)e * K * N; dst = w1t + (size_t)e * K * N;
    } else if (bx < 1024) {               // w2: per-expert [512][1024], 32 tiles
        int b2 = bx - 512, e = b2 >> 5, r = b2 & 31;
        K = 512; N = 1024; kt = r >> 3; nt = r & 7;
        src = w2 + (size_t)e * K * N; dst = w2t + (size_t)e * K * N;
    } else if (bx < 1056) {               // sw1 [1024][512]
        int r = bx - 1024;
        K = 1024; N = 512; kt = r >> 2; nt = r & 3;
        src = sw1; dst = sw1t;
    } else {                              // sw2 [512][1024]
        int r = bx - 1056;
        K = 512; N = 1024; kt = r >> 3; nt = r & 7;
        src = sw2; dst = sw2t;
    }
    int t = threadIdx.x;
#pragma unroll 4
    for (int i = 0; i < 16; ++i) {
        int u = t + 256 * i;
        int r = u >> 5;                 // k-local 0..127
        int c4 = (u & 31) * 4;          // n-local 0..124
        float4 v = *reinterpret_cast<const float4*>(
            src + (size_t)(kt * 128 + r) * N + nt * 128 + c4);
        sm.tileB[c4 + 0][r] = f2b(v.x);
        sm.tileB[c4 + 1][r] = f2b(v.y);
        sm.tileB[c4 + 2][r] = f2b(v.z);
        sm.tileB[c4 + 3][r] = f2b(v.w);
    }
    __syncthreads();
#pragma unroll 4
    for (int i2 = 0; i2 < 8; ++i2) {
        int u = t + 256 * i2;
        int n = u >> 4;                 // n-local 0..127
        int kc = (u & 15) * 8;          // k-chunk 0..120
        bf16x8 o;
#pragma unroll
        for (int j = 0; j < 8; ++j) o[j] = (short)sm.tileB[n][kc + j];
        *reinterpret_cast<bf16x8*>(dst + (size_t)(nt * 128 + n) * K + kt * 128 + kc) = o;
    }
}

// ---------------- per-chunk expert histogram ----------------
__global__ __launch_bounds__(256) void hist_kernel(
    const int* __restrict__ topk_idx, int* __restrict__ chunk_hist)
{
    __shared__ int h[NEXP];
    int tid = threadIdx.x;
    if (tid < NEXP) h[tid] = 0;
    __syncthreads();
    int r = blockIdx.x * 256 + tid;
    atomicAdd(&h[topk_idx[r]], 1);
    __syncthreads();
    if (tid < NEXP) chunk_hist[blockIdx.x * NEXP + tid] = h[tid];
}

// ---------------- scan chunk histograms ----------------
__global__ __launch_bounds__(64) void scan_kernel(
    const int* __restrict__ chunk_hist, int* __restrict__ chunk_off,
    int* __restrict__ counts_cap, float* __restrict__ out_tail)
{
    int e = threadIdx.x;
    if (e >= NEXP) return;
    int run = 0;
    for (int b = 0; b < NCHUNK; ++b) {
        chunk_off[b * NEXP + e] = run;
        run += chunk_hist[b * NEXP + e];
    }
    counts_cap[e] = run < CAP ? run : CAP;
    out_tail[NEXP + e] = (float)((double)run / 16384.0);
}

// ---------------- deterministic slot assignment ----------------
__global__ __launch_bounds__(256) void assign_kernel(
    const int* __restrict__ topk_idx, const float* __restrict__ topk_val,
    const int* __restrict__ chunk_off,
    int* __restrict__ route_slot, int* __restrict__ slot_token)
{
    __shared__ int wave_cnt[4][NEXP];
    int tid = threadIdx.x;
    int lane = tid & 63;
    int w = tid >> 6;
    int r = blockIdx.x * 256 + tid;
    int e = topk_idx[r];
    float gate = topk_val[r];
    int rank_w = 0;
#pragma unroll
    for (int e16 = 0; e16 < NEXP; ++e16) {
        unsigned long long bal = __ballot(e == e16);
        if (e == e16) rank_w = __popcll(bal & ((1ull << lane) - 1ull));
        if (lane == 0) wave_cnt[w][e16] = __popcll(bal);
    }
    __syncthreads();
    int rank = rank_w;
#pragma unroll
    for (int w2 = 0; w2 < 3; ++w2)
        if (w2 < w) rank += wave_cnt[w2][e];
    int pos = chunk_off[blockIdx.x * NEXP + e] + rank;
    int slot = -1;
    if (pos < CAP && gate != 0.f) {
        slot = e * CAP + pos;
        slot_token[slot] = r >> 1;
    }
    route_slot[r] = slot;
}

// ---------------- importance reduction ----------------
__global__ __launch_bounds__(256) void importance_kernel(
    const float* __restrict__ scores, float* __restrict__ out_tail)
{
    __shared__ float red[256];
    int e = blockIdx.x;
    float s = 0.f;
    for (int t = threadIdx.x; t < N_TOK; t += 256) s += scores[t * NEXP + e];
    red[threadIdx.x] = s;
    __syncthreads();
    for (int st = 128; st > 0; st >>= 1) {
        if (threadIdx.x < st) red[threadIdx.x] += red[threadIdx.x + st];
        __syncthreads();
    }
    if (threadIdx.x == 0) out_tail[e] = red[0] / (float)N_TOK;
}

// ================= MFMA grouped GEMM 1: h = gelu(gather(X) @ W1) =================
// 256x128 tile, 8 waves, BK=32, 3-buffer LDS, counted vmcnt(3), setprio, T1+T2.
// A-staging gathers expert rows directly via slot_token (per-lane global src).
#define G1_GX (NEXP * 5 + N_TOK / 256)      /* 112 */
#define G1_NWG (G1_GX * (FDIM / 128))       /* 448 */
__global__ __launch_bounds__(512) void gemm1_mfma(
    const ushort_t* __restrict__ x_bf,      // [N_TOK][DIM] bf16
    const ushort_t* __restrict__ w1t,       // [16][FDIM][DIM] bf16 n-major
    const ushort_t* __restrict__ sw1t,      // [FDIM][DIM]
    const int* __restrict__ slot_token,     // [ECAP]
    const int* __restrict__ counts_cap,
    ushort_t* __restrict__ h_buf)           // [TOTROW][FDIM] bf16
{
    __shared__ ushort_t As[3][256 * 32];
    __shared__ ushort_t Bs[3][128 * 32];

    int flat = blockIdx.x;
    int wg = (flat & 7) * (G1_NWG / 8) + (flat >> 3);   // T1 (448 % 8 == 0)
    int by = wg & 3;
    int bxg = wg >> 2;

    int g, rb;
    if (bxg < NEXP * 5) { g = bxg / 5; rb = bxg % 5; }
    else { g = NEXP; rb = bxg - NEXP * 5; }
    int Mg = (g < NEXP) ? counts_cap[g] : N_TOK;
    int m0 = rb * 256;
    if (m0 >= Mg) return;
    const ushort_t* Bt = (g < NEXP) ? (w1t + (size_t)g * DIM * FDIM) : sw1t;
    int n0 = by * 128;
    int t = threadIdx.x;

    const ushort_t* asrc[2];
    const ushort_t* bsrc;
#pragma unroll
    for (int i = 0; i < 2; ++i) {
        int s = t + i * 512;
        int lr = ((s >> 3) << 1) | ((s >> 2) & 1);
        int qq = (s & 3) ^ ((s >> 3) & 3);
        int row = m0 + lr;
        const ushort_t* base;
        if (g < NEXP) {
            int tok = (row < Mg) ? slot_token[g * CAP + row] : 0;
            if ((unsigned)tok >= N_TOK) tok = 0;   // poison guard
            base = x_bf + (size_t)tok * DIM;
        } else {
            base = x_bf + (size_t)row * DIM;
        }
        asrc[i] = base + qq * 8;
    }
    {
        int s = t;
        int lr = ((s >> 3) << 1) | ((s >> 2) & 1);
        int qq = (s & 3) ^ ((s >> 3) & 3);
        bsrc = Bt + (size_t)(n0 + lr) * DIM + qq * 8;
    }

    int lane = t & 63;
    int w = t >> 6;
    int wm = (w & 3) * 64, wn = (w >> 2) * 64;
    int l15 = lane & 15, q = lane >> 4;

    int aoff[4], boff[4];
#pragma unroll
    for (int m = 0; m < 4; ++m) aoff[m] = swz_addr16(wm + m * 16 + l15, q) << 3;
#pragma unroll
    for (int n = 0; n < 4; ++n) boff[n] = swz_addr16(wn + n * 16 + l15, q) << 3;

    f32x4 acc[4][4];
#pragma unroll
    for (int m = 0; m < 4; ++m)
#pragma unroll
        for (int n = 0; n < 4; ++n) acc[m][n] = (f32x4){0.f, 0.f, 0.f, 0.f};

    auto STAGE = [&](int buf, int koff) {
        gload16(asrc[0] + koff, &As[buf][t * 8]);
        gload16(asrc[1] + koff, &As[buf][t * 8 + 4096]);
        gload16(bsrc + koff, &Bs[buf][t * 8]);
    };

    const int NSTEP = DIM / 32;   // 32
    STAGE(0, 0);
    STAGE(1, 32);
    asm volatile("s_waitcnt vmcnt(3)" ::: "memory");
    __builtin_amdgcn_s_barrier();
    asm volatile("" ::: "memory");

    int cur = 0, b2 = 2;
    for (int kt = 0; kt < NSTEP; ++kt) {
        if (kt + 2 < NSTEP) STAGE(b2, (kt + 2) * 32);
        const ushort_t* asb = &As[cur][0];
        const ushort_t* bsb = &Bs[cur][0];
        bf16x8 af[4], bfr[4];
#pragma unroll
        for (int m = 0; m < 4; ++m)
            af[m] = *reinterpret_cast<const bf16x8*>(asb + aoff[m]);
#pragma unroll
        for (int n = 0; n < 4; ++n)
            bfr[n] = *reinterpret_cast<const bf16x8*>(bsb + boff[n]);
        __builtin_amdgcn_s_setprio(1);
#pragma unroll
        for (int m = 0; m < 4; ++m)
#pragma unroll
            for (int n = 0; n < 4; ++n)
                acc[m][n] = __builtin_amdgcn_mfma_f32_16x16x32_bf16(
                    af[m], bfr[n], acc[m][n], 0, 0, 0);
        __builtin_amdgcn_s_setprio(0);
        if (kt + 1 < NSTEP) {
            if (kt + 2 < NSTEP) asm volatile("s_waitcnt vmcnt(3)" ::: "memory");
            else                asm volatile("s_waitcnt vmcnt(0)" ::: "memory");
            __builtin_amdgcn_s_barrier();
            asm volatile("" ::: "memory");
        }
        cur = (cur == 2) ? 0 : cur + 1;
        b2  = (b2 == 2) ? 0 : b2 + 1;
    }

    size_t obase = ((g < NEXP) ? (size_t)g * CAP : (size_t)ECAP) + m0;
#pragma unroll
    for (int m = 0; m < 4; ++m) {
#pragma unroll
        for (int r = 0; r < 4; ++r) {
            int grow = wm + m * 16 + q * 4 + r;
            ushort_t* orow = h_buf + (obase + grow) * FDIM + n0 + wn + l15;
#pragma unroll
            for (int n = 0; n < 4; ++n)
                orow[n * 16] = f2b(gelu_fast(acc[m][n][r]));
        }
    }
}

// ================= MFMA grouped GEMM 2: out = H @ W2 =================
// 256x128 tile, 8 waves, BK=32, 2-buffer (48KB, occupancy), setprio, T1+T2.
#define G2_NWG (G1_GX * (DIM / 128))        /* 896 */
__global__ __launch_bounds__(512) void gemm2_mfma(
    const ushort_t* __restrict__ h_buf,     // [TOTROW][FDIM] bf16
    const ushort_t* __restrict__ w2t,       // [16][DIM][FDIM] bf16 n-major
    const ushort_t* __restrict__ sw2t,      // [DIM][FDIM]
    const int* __restrict__ counts_cap,
    const float* __restrict__ g_shared,
    ushort_t* __restrict__ out_buf,         // [ECAP][DIM] bf16
    ushort_t* __restrict__ sh_out)          // [N_TOK][DIM] bf16 (x_bf reuse)
{
    __shared__ ushort_t As[2][256 * 32];
    __shared__ ushort_t Bs[2][128 * 32];

    int flat = blockIdx.x;
    int wg = (flat & 7) * (G2_NWG / 8) + (flat >> 3);
    int by = wg & 7;
    int bxg = wg >> 3;

    int g, rb;
    if (bxg < NEXP * 5) { g = bxg / 5; rb = bxg % 5; }
    else { g = NEXP; rb = bxg - NEXP * 5; }
    int Mg = (g < NEXP) ? counts_cap[g] : N_TOK;
    int m0 = rb * 256;
    if (m0 >= Mg) return;
    size_t abase = ((g < NEXP) ? (size_t)g * CAP : (size_t)ECAP) + m0;
    const ushort_t* Bt = (g < NEXP) ? (w2t + (size_t)g * FDIM * DIM) : sw2t;
    int n0 = by * 128;
    int t = threadIdx.x;

    const ushort_t* asrc[2];
    const ushort_t* bsrc;
#pragma unroll
    for (int i = 0; i < 2; ++i) {
        int s = t + i * 512;
        int lr = ((s >> 3) << 1) | ((s >> 2) & 1);
        int qq = (s & 3) ^ ((s >> 3) & 3);
        asrc[i] = h_buf + (abase + lr) * FDIM + qq * 8;
    }
    {
        int s = t;
        int lr = ((s >> 3) << 1) | ((s >> 2) & 1);
        int qq = (s & 3) ^ ((s >> 3) & 3);
        bsrc = Bt + (size_t)(n0 + lr) * FDIM + qq * 8;
    }

    int lane = t & 63;
    int w = t >> 6;
    int wm = (w & 3) * 64, wn = (w >> 2) * 64;
    int l15 = lane & 15, q = lane >> 4;

    int aoff[4], boff[4];
#pragma unroll
    for (int m = 0; m < 4; ++m) aoff[m] = swz_addr16(wm + m * 16 + l15, q) << 3;
#pragma unroll
    for (int n = 0; n < 4; ++n) boff[n] = swz_addr16(wn + n * 16 + l15, q) << 3;

    f32x4 acc[4][4];
#pragma unroll
    for (int m = 0; m < 4; ++m)
#pragma unroll
        for (int n = 0; n < 4; ++n) acc[m][n] = (f32x4){0.f, 0.f, 0.f, 0.f};

    auto STAGE = [&](int buf, int koff) {
        gload16(asrc[0] + koff, &As[buf][t * 8]);
        gload16(asrc[1] + koff, &As[buf][t * 8 + 4096]);
        gload16(bsrc + koff, &Bs[buf][t * 8]);
    };

    const int NSTEP = FDIM / 32;  // 16
    STAGE(0, 0);
    __syncthreads();

    int cur = 0;
    for (int kt = 0; kt < NSTEP; ++kt) {
        if (kt + 1 < NSTEP) STAGE(cur ^ 1, (kt + 1) * 32);
        const ushort_t* asb = &As[cur][0];
        const ushort_t* bsb = &Bs[cur][0];
        bf16x8 af[4], bfr[4];
#pragma unroll
        for (int m = 0; m < 4; ++m)
            af[m] = *reinterpret_cast<const bf16x8*>(asb + aoff[m]);
#pragma unroll
        for (int n = 0; n < 4; ++n)
            bfr[n] = *reinterpret_cast<const bf16x8*>(bsb + boff[n]);
        __builtin_amdgcn_s_setprio(1);
#pragma unroll
        for (int m = 0; m < 4; ++m)
#pragma unroll
            for (int n = 0; n < 4; ++n)
                acc[m][n] = __builtin_amdgcn_mfma_f32_16x16x32_bf16(
                    af[m], bfr[n], acc[m][n], 0, 0, 0);
        __builtin_amdgcn_s_setprio(0);
        __syncthreads();
        cur ^= 1;
    }

    if (g < NEXP) {
#pragma unroll
        for (int m = 0; m < 4; ++m) {
#pragma unroll
            for (int r = 0; r < 4; ++r) {
                int grow = wm + m * 16 + q * 4 + r;
                ushort_t* orow = out_buf + (abase + grow) * DIM + n0 + wn + l15;
#pragma unroll
                for (int n = 0; n < 4; ++n)
                    orow[n * 16] = f2b(acc[m][n][r]);
            }
        }
    } else {
#pragma unroll
        for (int m = 0; m < 4; ++m) {
#pragma unroll
            for (int r = 0; r < 4; ++r) {
                int tok = m0 + wm + m * 16 + q * 4 + r;
                float gs = g_shared[tok];
                ushort_t* orow = sh_out + (size_t)tok * DIM + n0 + wn + l15;
#pragma unroll
                for (int n = 0; n < 4; ++n)
                    orow[n * 16] = f2b(gs * acc[m][n][r]);
            }
        }
    }
}

// ---------------- combine: y = sh_out + sum(gate * expert_out), write-only ----------------
__global__ __launch_bounds__(256) void combine_kernel(
    const ushort_t* __restrict__ out_buf, const ushort_t* __restrict__ sh_out,
    const int* __restrict__ route_slot, const float* __restrict__ topk_val,
    float* __restrict__ y)
{
    int token = blockIdx.x;
    int c = threadIdx.x * 4;
    ushort4 sv = *reinterpret_cast<const ushort4*>(sh_out + (size_t)token * DIM + c);
    float y0 = bf2f(sv.x), y1 = bf2f(sv.y), y2 = bf2f(sv.z), y3 = bf2f(sv.w);
#pragma unroll
    for (int k = 0; k < 2; ++k) {
        int s = route_slot[2 * token + k];
        if (s >= 0) {
            float gate = topk_val[2 * token + k];
            ushort4 rv = *reinterpret_cast<const ushort4*>(out_buf + (size_t)s * DIM + c);
            y0 += gate * bf2f(rv.x); y1 += gate * bf2f(rv.y);
            y2 += gate * bf2f(rv.z); y3 += gate * bf2f(rv.w);
        }
    }
    float4 o; o.x = y0; o.y = y1; o.z = y2; o.w = y3;
    *reinterpret_cast<float4*>(y + (size_t)token * DIM + c) = o;
}

extern "C" void kernel_launch(void* const* d_in, const int* in_sizes, int n_in,
                              void* d_out, int out_size, void* d_ws, size_t ws_size,
                              hipStream_t stream) {
    const float* x   = (const float*)d_in[0];
    const float* rw  = (const float*)d_in[1];
    const float* sgw = (const float*)d_in[2];
    const float* w1  = (const float*)d_in[3];
    const float* w2  = (const float*)d_in[4];
    const float* sw1 = (const float*)d_in[5];
    const float* sw2 = (const float*)d_in[6];
    float* y = (float*)d_out;
    float* out_tail = y + (size_t)N_TOK * DIM;

    size_t off = 0;
    char* wsb = (char*)d_ws;
    auto alloc = [&](size_t bytes) -> void* {
        void* p = wsb + off;
        off += (bytes + 255) & ~(size_t)255;
        return p;
    };
    float*    scores     = (float*)alloc((size_t)N_TOK * NEXP * 4);
    int*      topk_idx   = (int*)alloc((size_t)NROUTE * 4);
    float*    topk_val   = (float*)alloc((size_t)NROUTE * 4);
    float*    g_shared   = (float*)alloc((size_t)N_TOK * 4);
    int*      chunk_hist = (int*)alloc((size_t)NCHUNK * NEXP * 4);
    int*      chunk_off  = (int*)alloc((size_t)NCHUNK * NEXP * 4);
    int*      counts_cap = (int*)alloc((size_t)NEXP * 4);
    int*      route_slot = (int*)alloc((size_t)NROUTE * 4);
    int*      slot_token = (int*)alloc((size_t)ECAP * 4);
    ushort_t* out_buf    = (ushort_t*)alloc((size_t)ECAP * DIM * 2);
    // x_bf [N_TOK][DIM] reused as sh_out after gemm1 (x_bf dead post-gemm1).
    ushort_t* x_bf       = (ushort_t*)alloc((size_t)N_TOK * DIM * 2);
    ushort_t* sh_out     = x_bf;
    ushort_t* w1t        = (ushort_t*)alloc((size_t)NEXP * DIM * FDIM * 2);
    ushort_t* w2t        = (ushort_t*)alloc((size_t)NEXP * DIM * FDIM * 2);
    ushort_t* sw1t       = (ushort_t*)alloc((size_t)DIM * FDIM * 2);
    ushort_t* sw2t       = (ushort_t*)alloc((size_t)DIM * FDIM * 2);
    ushort_t* h_buf      = (ushort_t*)alloc((size_t)TOTROW * FDIM * 2);
    (void)ws_size; (void)in_sizes; (void)n_in; (void)out_size;

    prep_kernel<<<PREP_NWG, 256, 0, stream>>>(
        x, rw, sgw, w1, w2, sw1, sw2,
        scores, topk_idx, topk_val, g_shared, x_bf, w1t, w2t, sw1t, sw2t);
    hist_kernel<<<NCHUNK, 256, 0, stream>>>(topk_idx, chunk_hist);
    scan_kernel<<<1, 64, 0, stream>>>(chunk_hist, chunk_off, counts_cap, out_tail);
    assign_kernel<<<NCHUNK, 256, 0, stream>>>(topk_idx, topk_val, chunk_off, route_slot, slot_token);
    importance_kernel<<<NEXP, 256, 0, stream>>>(scores, out_tail);

    gemm1_mfma<<<G1_NWG, 512, 0, stream>>>(x_bf, w1t, sw1t, slot_token, counts_cap, h_buf);
    gemm2_mfma<<<G2_NWG, 512, 0, stream>>>(h_buf, w2t, sw2t, counts_cap, g_shared, out_buf, sh_out);

    combine_kernel<<<N_TOK, 256, 0, stream>>>(out_buf, sh_out, route_slot, topk_val, y);
}

// Round 21
// 150.896 us; speedup vs baseline: 1.3352x; 1.0154x over previous
//
#include <hip/hip_runtime.h>
#include <hip/hip_bf16.h>
#include <math.h>

#define N_TOK 8192
#define DIM 1024
#define NEXP 16
#define CAP 1280
#define FDIM 512
#define NROUTE (N_TOK * 2)
#define NCHUNK 64
#define ECAP (NEXP * CAP)        /* 20480 */
#define TOTROW (ECAP + N_TOK)    /* 28672 */

typedef __hip_bfloat16 bf16;
typedef unsigned short ushort_t;
typedef __attribute__((ext_vector_type(8))) short bf16x8;
typedef __attribute__((ext_vector_type(4))) float f32x4;

// tanh-approx gelu via sigmoid; |err| vs erf-gelu ~1e-3 << tolerance.
__device__ __forceinline__ float gelu_fast(float x) {
    float u = 1.5957691216057308f * (x + 0.044715f * x * x * x);
    return x / (1.f + __expf(-u));
}

__device__ __forceinline__ float bf2f(unsigned short u) {
    union { float f; unsigned int i; } v; v.i = ((unsigned int)u) << 16; return v.f;
}

__device__ __forceinline__ unsigned short f2b(float f) {
    union { __hip_bfloat16 h; unsigned short u; } v;
    v.h = __float2bfloat16(f);
    return v.u;
}

__device__ __forceinline__ void gload16(const void* g, void* l) {
    __builtin_amdgcn_global_load_lds(
        (const __attribute__((address_space(1))) unsigned int*)g,
        (__attribute__((address_space(3))) unsigned int*)l,
        16, 0, 0);
}

// T2 both-sides swizzle (verified: SQ_LDS_BANK_CONFLICT -> 0 in GEMMs, rounds 5-20)
__device__ __forceinline__ int swz_addr16(int r, int q) {
    return ((r >> 1) << 3) + ((r & 1) << 2) + (q ^ ((r >> 1) & 3));
}

// ========== fused prep: router (blocks 0-2047, 4 tok/blk) + transpose (2048-4223) ==========
// Small-LDS variant: union = max(16.5KB transpose tile, 17.5KB router) -> 9 blocks/CU
// (was 4 at 33KB). Transpose tile 64n x 128k keeps 256B-granular reads+writes.
#define PREP_RTR_BLOCKS 2048
#define PREP_NWG (PREP_RTR_BLOCKS + 2176)
__global__ __launch_bounds__(256) void prep_kernel(
    const float* __restrict__ x, const float* __restrict__ rw,
    const float* __restrict__ sgw,
    const float* __restrict__ w1, const float* __restrict__ w2,
    const float* __restrict__ sw1, const float* __restrict__ sw2,
    float* __restrict__ scores,
    int* __restrict__ topk_idx,
    float* __restrict__ topk_val,
    float* __restrict__ g_shared,
    ushort_t* __restrict__ x_bf,
    ushort_t* __restrict__ w1t, ushort_t* __restrict__ w2t,
    ushort_t* __restrict__ sw1t, ushort_t* __restrict__ sw2t)
{
    __shared__ union {
        ushort_t tileB[64][129];             // transpose [n][k] bf16 (16.5KB)
        struct {
            float xl[4][1028];               // router x tile (16.4KB)
            float racc[4][4][4][4];          // [wave][tok][e4][4]
            float g[4][4];
        } r;
    } sm;

    if (blockIdx.x < PREP_RTR_BLOCKS) {
        // ---------------- router v7: 4 tokens/block ----------------
        int tid = threadIdx.x;
        int w = tid >> 6;
        int lane = tid & 63;
        int tok0 = blockIdx.x * 4;

        // pass 1: stage x rows -> LDS + bf16 emit + shared-gate partials
        {
            int dq = w * 256 + lane * 4;
            float4 gv = *reinterpret_cast<const float4*>(sgw + dq);
#pragma unroll
            for (int tt = 0; tt < 4; ++tt) {
                const float* xr = x + (size_t)(tok0 + tt) * DIM + dq;
                float4 xv = *reinterpret_cast<const float4*>(xr);
                *reinterpret_cast<float4*>(&sm.r.xl[tt][dq]) = xv;
                ushort4 o;
                o.x = f2b(xv.x); o.y = f2b(xv.y); o.z = f2b(xv.z); o.w = f2b(xv.w);
                *reinterpret_cast<ushort4*>(x_bf + (size_t)(tok0 + tt) * DIM + dq) = o;
                float dg = xv.x * gv.x + xv.y * gv.y + xv.z * gv.z + xv.w * gv.w;
#pragma unroll
                for (int m = 1; m < 64; m <<= 1) dg += __shfl_xor(dg, m, 64);
                if (lane == 0) sm.r.g[w][tt] = dg;
            }
        }
        __syncthreads();

        // pass 2: logits from LDS. lane = (tok:2 | dup:2 | e4:2), dup covers 64 d.
        int tok = lane >> 4;
        int dup = (lane >> 2) & 3;
        int e4 = lane & 3;
        {
            int base_d = w * 256 + dup * 64;
            const float* rwb = rw + (size_t)base_d * NEXP + e4 * 4;
            float4 a0 = {0,0,0,0}, a1 = {0,0,0,0}, a2 = {0,0,0,0}, a3 = {0,0,0,0};
#pragma unroll 4
            for (int i = 0; i < 16; ++i) {
                float4 xv = *reinterpret_cast<const float4*>(&sm.r.xl[tok][base_d + i * 4]);
                const float* rp = rwb + (size_t)i * 4 * NEXP;
                float4 w0 = *reinterpret_cast<const float4*>(rp);
                float4 w1v = *reinterpret_cast<const float4*>(rp + NEXP);
                float4 w2v = *reinterpret_cast<const float4*>(rp + 2 * NEXP);
                float4 w3v = *reinterpret_cast<const float4*>(rp + 3 * NEXP);
                a0.x += xv.x * w0.x;  a0.y += xv.x * w0.y;  a0.z += xv.x * w0.z;  a0.w += xv.x * w0.w;
                a1.x += xv.y * w1v.x; a1.y += xv.y * w1v.y; a1.z += xv.y * w1v.z; a1.w += xv.y * w1v.w;
                a2.x += xv.z * w2v.x; a2.y += xv.z * w2v.y; a2.z += xv.z * w2v.z; a2.w += xv.z * w2v.w;
                a3.x += xv.w * w3v.x; a3.y += xv.w * w3v.y; a3.z += xv.w * w3v.z; a3.w += xv.w * w3v.w;
            }
            float s0 = (a0.x + a1.x) + (a2.x + a3.x);
            float s1 = (a0.y + a1.y) + (a2.y + a3.y);
            float s2 = (a0.z + a1.z) + (a2.z + a3.z);
            float s3 = (a0.w + a1.w) + (a2.w + a3.w);
            // fold 4 dup groups (lane bits 2-3)
            s0 += __shfl_xor(s0, 4, 64);  s0 += __shfl_xor(s0, 8, 64);
            s1 += __shfl_xor(s1, 4, 64);  s1 += __shfl_xor(s1, 8, 64);
            s2 += __shfl_xor(s2, 4, 64);  s2 += __shfl_xor(s2, 8, 64);
            s3 += __shfl_xor(s3, 4, 64);  s3 += __shfl_xor(s3, 8, 64);
            if (dup == 0) {
                sm.r.racc[w][tok][e4][0] = s0;
                sm.r.racc[w][tok][e4][1] = s1;
                sm.r.racc[w][tok][e4][2] = s2;
                sm.r.racc[w][tok][e4][3] = s3;
            }
        }
        __syncthreads();

        if (tid >= 16) return;
        // epilogue: 16 lanes = 4 tok x 4 e4
        int tk = tid >> 2;
        int eq = tid & 3;
        int token = tok0 + tk;
        float L0 = sm.r.racc[0][tk][eq][0] + sm.r.racc[1][tk][eq][0]
                 + sm.r.racc[2][tk][eq][0] + sm.r.racc[3][tk][eq][0];
        float L1 = sm.r.racc[0][tk][eq][1] + sm.r.racc[1][tk][eq][1]
                 + sm.r.racc[2][tk][eq][1] + sm.r.racc[3][tk][eq][1];
        float L2 = sm.r.racc[0][tk][eq][2] + sm.r.racc[1][tk][eq][2]
                 + sm.r.racc[2][tk][eq][2] + sm.r.racc[3][tk][eq][2];
        float L3 = sm.r.racc[0][tk][eq][3] + sm.r.racc[1][tk][eq][3]
                 + sm.r.racc[2][tk][eq][3] + sm.r.racc[3][tk][eq][3];

        float mx = fmaxf(fmaxf(L0, L1), fmaxf(L2, L3));
        mx = fmaxf(mx, __shfl_xor(mx, 1, 4));
        mx = fmaxf(mx, __shfl_xor(mx, 2, 4));
        float P0 = expf(L0 - mx), P1 = expf(L1 - mx);
        float P2 = expf(L2 - mx), P3 = expf(L3 - mx);
        float s = (P0 + P1) + (P2 + P3);
        s += __shfl_xor(s, 1, 4);
        s += __shfl_xor(s, 2, 4);
        float inv = 1.f / s;
        P0 *= inv; P1 *= inv; P2 *= inv; P3 *= inv;

        float4 Pv = {P0, P1, P2, P3};
        *reinterpret_cast<float4*>(scores + (size_t)token * NEXP + eq * 4) = Pv;

        int base = eq * 4;
        float v = P0; int idx = base;
        if (P1 > v) { v = P1; idx = base + 1; }
        if (P2 > v) { v = P2; idx = base + 2; }
        if (P3 > v) { v = P3; idx = base + 3; }
#pragma unroll
        for (int m = 1; m < 4; m <<= 1) {
            float vo = __shfl_xor(v, m, 4);
            int io = __shfl_xor(idx, m, 4);
            if (vo > v || (vo == v && io < idx)) { v = vo; idx = io; }
        }
        int i0 = idx; float v0 = v;
        float q0 = (base + 0 == i0) ? -1.f : P0;
        float q1 = (base + 1 == i0) ? -1.f : P1;
        float q2 = (base + 2 == i0) ? -1.f : P2;
        float q3 = (base + 3 == i0) ? -1.f : P3;
        v = q0; idx = base;
        if (q1 > v) { v = q1; idx = base + 1; }
        if (q2 > v) { v = q2; idx = base + 2; }
        if (q3 > v) { v = q3; idx = base + 3; }
#pragma unroll
        for (int m = 1; m < 4; m <<= 1) {
            float vo = __shfl_xor(v, m, 4);
            int io = __shfl_xor(idx, m, 4);
            if (vo > v || (vo == v && io < idx)) { v = vo; idx = io; }
        }
        if (eq == 0) {
            topk_idx[2 * token] = i0; topk_idx[2 * token + 1] = idx;
            topk_val[2 * token] = v0; topk_val[2 * token + 1] = v;
            float ag = (sm.r.g[0][tk] + sm.r.g[1][tk]) + (sm.r.g[2][tk] + sm.r.g[3][tk]);
            g_shared[token] = 1.f / (1.f + expf(-ag));
        }
        return;
    }

    // ---------- weight transpose+convert, 64n x 128k tile: fp32 [K][N] -> bf16 [N][K] ----------
    int bx = blockIdx.x - PREP_RTR_BLOCKS;
    const float* src; ushort_t* dst; int K, N, kt, nt;
    if (bx < 1024) {                      // w1: per-expert [1024][512], 64 tiles
        int e = bx >> 6, r = bx & 63;
        K = 1024; N = 512; kt = r >> 3; nt = r & 7;
        src = w1 + (size_t)e * K * N; dst = w1t + (size_t)e * K * N;
    } else if (bx < 2048) {               // w2: per-expert [512][1024], 64 tiles
        int b2 = bx - 1024, e = b2 >> 6, r = b2 & 63;
        K = 512; N = 1024; kt = r >> 4; nt = r & 15;
        src = w2 + (size_t)e * K * N; dst = w2t + (size_t)e * K * N;
    } else if (bx < 2112) {               // sw1 [1024][512], 64 tiles
        int r = bx - 2048;
        K = 1024; N = 512; kt = r >> 3; nt = r & 7;
        src = sw1; dst = sw1t;
    } else {                              // sw2 [512][1024], 64 tiles
        int r = bx - 2112;
        K = 512; N = 1024; kt = r >> 4; nt = r & 15;
        src = sw2; dst = sw2t;
    }
    int t = threadIdx.x;
    // phase A: read 128 k-rows x 64 n-cols (256B contiguous per 16-lane group),
    // convert to bf16, store transposed into tileB[n][k].
#pragma unroll 4
    for (int i = 0; i < 8; ++i) {
        int u = t + 256 * i;
        int r = u >> 4;                 // k-local 0..127
        int c4 = (u & 15) * 4;          // n-local 0..60
        float4 v = *reinterpret_cast<const float4*>(
            src + (size_t)(kt * 128 + r) * N + nt * 64 + c4);
        sm.tileB[c4 + 0][r] = f2b(v.x);
        sm.tileB[c4 + 1][r] = f2b(v.y);
        sm.tileB[c4 + 2][r] = f2b(v.z);
        sm.tileB[c4 + 3][r] = f2b(v.w);
    }
    __syncthreads();
    // phase B: write 64 n-rows x 128 k (256B contiguous per 16-lane group).
#pragma unroll 4
    for (int i2 = 0; i2 < 4; ++i2) {
        int u = t + 256 * i2;
        int n = u >> 4;                 // n-local 0..63
        int kc = (u & 15) * 8;          // k-chunk 0..120
        bf16x8 o;
#pragma unroll
        for (int j = 0; j < 8; ++j) o[j] = (short)sm.tileB[n][kc + j];
        *reinterpret_cast<bf16x8*>(dst + (size_t)(nt * 64 + n) * K + kt * 128 + kc) = o;
    }
}

// ---------------- per-chunk expert histogram ----------------
__global__ __launch_bounds__(256) void hist_kernel(
    const int* __restrict__ topk_idx, int* __restrict__ chunk_hist)
{
    __shared__ int h[NEXP];
    int tid = threadIdx.x;
    if (tid < NEXP) h[tid] = 0;
    __syncthreads();
    int r = blockIdx.x * 256 + tid;
    atomicAdd(&h[topk_idx[r]], 1);
    __syncthreads();
    if (tid < NEXP) chunk_hist[blockIdx.x * NEXP + tid] = h[tid];
}

// ---------------- scan chunk histograms ----------------
__global__ __launch_bounds__(64) void scan_kernel(
    const int* __restrict__ chunk_hist, int* __restrict__ chunk_off,
    int* __restrict__ counts_cap, float* __restrict__ out_tail)
{
    int e = threadIdx.x;
    if (e >= NEXP) return;
    int run = 0;
    for (int b = 0; b < NCHUNK; ++b) {
        chunk_off[b * NEXP + e] = run;
        run += chunk_hist[b * NEXP + e];
    }
    counts_cap[e] = run < CAP ? run : CAP;
    out_tail[NEXP + e] = (float)((double)run / 16384.0);
}

// ---------------- deterministic slot assignment ----------------
__global__ __launch_bounds__(256) void assign_kernel(
    const int* __restrict__ topk_idx, const float* __restrict__ topk_val,
    const int* __restrict__ chunk_off,
    int* __restrict__ route_slot, int* __restrict__ slot_token)
{
    __shared__ int wave_cnt[4][NEXP];
    int tid = threadIdx.x;
    int lane = tid & 63;
    int w = tid >> 6;
    int r = blockIdx.x * 256 + tid;
    int e = topk_idx[r];
    float gate = topk_val[r];
    int rank_w = 0;
#pragma unroll
    for (int e16 = 0; e16 < NEXP; ++e16) {
        unsigned long long bal = __ballot(e == e16);
        if (e == e16) rank_w = __popcll(bal & ((1ull << lane) - 1ull));
        if (lane == 0) wave_cnt[w][e16] = __popcll(bal);
    }
    __syncthreads();
    int rank = rank_w;
#pragma unroll
    for (int w2 = 0; w2 < 3; ++w2)
        if (w2 < w) rank += wave_cnt[w2][e];
    int pos = chunk_off[blockIdx.x * NEXP + e] + rank;
    int slot = -1;
    if (pos < CAP && gate != 0.f) {
        slot = e * CAP + pos;
        slot_token[slot] = r >> 1;
    }
    route_slot[r] = slot;
}

// ---------------- importance reduction ----------------
__global__ __launch_bounds__(256) void importance_kernel(
    const float* __restrict__ scores, float* __restrict__ out_tail)
{
    __shared__ float red[256];
    int e = blockIdx.x;
    float s = 0.f;
    for (int t = threadIdx.x; t < N_TOK; t += 256) s += scores[t * NEXP + e];
    red[threadIdx.x] = s;
    __syncthreads();
    for (int st = 128; st > 0; st >>= 1) {
        if (threadIdx.x < st) red[threadIdx.x] += red[threadIdx.x + st];
        __syncthreads();
    }
    if (threadIdx.x == 0) out_tail[e] = red[0] / (float)N_TOK;
}

// ================= MFMA grouped GEMM 1: h = gelu(gather(X) @ W1) =================
// 256x128 tile, 8 waves, BK=32, 3-buffer LDS, counted vmcnt(3), setprio, T1+T2.
// A-staging gathers expert rows directly via slot_token (per-lane global src).
#define G1_GX (NEXP * 5 + N_TOK / 256)      /* 112 */
#define G1_NWG (G1_GX * (FDIM / 128))       /* 448 */
__global__ __launch_bounds__(512) void gemm1_mfma(
    const ushort_t* __restrict__ x_bf,      // [N_TOK][DIM] bf16
    const ushort_t* __restrict__ w1t,       // [16][FDIM][DIM] bf16 n-major
    const ushort_t* __restrict__ sw1t,      // [FDIM][DIM]
    const int* __restrict__ slot_token,     // [ECAP]
    const int* __restrict__ counts_cap,
    ushort_t* __restrict__ h_buf)           // [TOTROW][FDIM] bf16
{
    __shared__ ushort_t As[3][256 * 32];
    __shared__ ushort_t Bs[3][128 * 32];

    int flat = blockIdx.x;
    int wg = (flat & 7) * (G1_NWG / 8) + (flat >> 3);   // T1 (448 % 8 == 0)
    int by = wg & 3;
    int bxg = wg >> 2;

    int g, rb;
    if (bxg < NEXP * 5) { g = bxg / 5; rb = bxg % 5; }
    else { g = NEXP; rb = bxg - NEXP * 5; }
    int Mg = (g < NEXP) ? counts_cap[g] : N_TOK;
    int m0 = rb * 256;
    if (m0 >= Mg) return;
    const ushort_t* Bt = (g < NEXP) ? (w1t + (size_t)g * DIM * FDIM) : sw1t;
    int n0 = by * 128;
    int t = threadIdx.x;

    const ushort_t* asrc[2];
    const ushort_t* bsrc;
#pragma unroll
    for (int i = 0; i < 2; ++i) {
        int s = t + i * 512;
        int lr = ((s >> 3) << 1) | ((s >> 2) & 1);
        int qq = (s & 3) ^ ((s >> 3) & 3);
        int row = m0 + lr;
        const ushort_t* base;
        if (g < NEXP) {
            int tok = (row < Mg) ? slot_token[g * CAP + row] : 0;
            if ((unsigned)tok >= N_TOK) tok = 0;   // poison guard
            base = x_bf + (size_t)tok * DIM;
        } else {
            base = x_bf + (size_t)row * DIM;
        }
        asrc[i] = base + qq * 8;
    }
    {
        int s = t;
        int lr = ((s >> 3) << 1) | ((s >> 2) & 1);
        int qq = (s & 3) ^ ((s >> 3) & 3);
        bsrc = Bt + (size_t)(n0 + lr) * DIM + qq * 8;
    }

    int lane = t & 63;
    int w = t >> 6;
    int wm = (w & 3) * 64, wn = (w >> 2) * 64;
    int l15 = lane & 15, q = lane >> 4;

    int aoff[4], boff[4];
#pragma unroll
    for (int m = 0; m < 4; ++m) aoff[m] = swz_addr16(wm + m * 16 + l15, q) << 3;
#pragma unroll
    for (int n = 0; n < 4; ++n) boff[n] = swz_addr16(wn + n * 16 + l15, q) << 3;

    f32x4 acc[4][4];
#pragma unroll
    for (int m = 0; m < 4; ++m)
#pragma unroll
        for (int n = 0; n < 4; ++n) acc[m][n] = (f32x4){0.f, 0.f, 0.f, 0.f};

    auto STAGE = [&](int buf, int koff) {
        gload16(asrc[0] + koff, &As[buf][t * 8]);
        gload16(asrc[1] + koff, &As[buf][t * 8 + 4096]);
        gload16(bsrc + koff, &Bs[buf][t * 8]);
    };

    const int NSTEP = DIM / 32;   // 32
    STAGE(0, 0);
    STAGE(1, 32);
    asm volatile("s_waitcnt vmcnt(3)" ::: "memory");
    __builtin_amdgcn_s_barrier();
    asm volatile("" ::: "memory");

    int cur = 0, b2 = 2;
    for (int kt = 0; kt < NSTEP; ++kt) {
        if (kt + 2 < NSTEP) STAGE(b2, (kt + 2) * 32);
        const ushort_t* asb = &As[cur][0];
        const ushort_t* bsb = &Bs[cur][0];
        bf16x8 af[4], bfr[4];
#pragma unroll
        for (int m = 0; m < 4; ++m)
            af[m] = *reinterpret_cast<const bf16x8*>(asb + aoff[m]);
#pragma unroll
        for (int n = 0; n < 4; ++n)
            bfr[n] = *reinterpret_cast<const bf16x8*>(bsb + boff[n]);
        __builtin_amdgcn_s_setprio(1);
#pragma unroll
        for (int m = 0; m < 4; ++m)
#pragma unroll
            for (int n = 0; n < 4; ++n)
                acc[m][n] = __builtin_amdgcn_mfma_f32_16x16x32_bf16(
                    af[m], bfr[n], acc[m][n], 0, 0, 0);
        __builtin_amdgcn_s_setprio(0);
        if (kt + 1 < NSTEP) {
            if (kt + 2 < NSTEP) asm volatile("s_waitcnt vmcnt(3)" ::: "memory");
            else                asm volatile("s_waitcnt vmcnt(0)" ::: "memory");
            __builtin_amdgcn_s_barrier();
            asm volatile("" ::: "memory");
        }
        cur = (cur == 2) ? 0 : cur + 1;
        b2  = (b2 == 2) ? 0 : b2 + 1;
    }

    size_t obase = ((g < NEXP) ? (size_t)g * CAP : (size_t)ECAP) + m0;
#pragma unroll
    for (int m = 0; m < 4; ++m) {
#pragma unroll
        for (int r = 0; r < 4; ++r) {
            int grow = wm + m * 16 + q * 4 + r;
            ushort_t* orow = h_buf + (obase + grow) * FDIM + n0 + wn + l15;
#pragma unroll
            for (int n = 0; n < 4; ++n)
                orow[n * 16] = f2b(gelu_fast(acc[m][n][r]));
        }
    }
}

// ================= MFMA grouped GEMM 2: out = H @ W2 =================
// 256x128 tile, 8 waves, BK=32, 2-buffer (48KB, occupancy), setprio, T1+T2.
#define G2_NWG (G1_GX * (DIM / 128))        /* 896 */
__global__ __launch_bounds__(512) void gemm2_mfma(
    const ushort_t* __restrict__ h_buf,     // [TOTROW][FDIM] bf16
    const ushort_t* __restrict__ w2t,       // [16][DIM][FDIM] bf16 n-major
    const ushort_t* __restrict__ sw2t,      // [DIM][FDIM]
    const int* __restrict__ counts_cap,
    const float* __restrict__ g_shared,
    ushort_t* __restrict__ out_buf,         // [ECAP][DIM] bf16
    ushort_t* __restrict__ sh_out)          // [N_TOK][DIM] bf16 (x_bf reuse)
{
    __shared__ ushort_t As[2][256 * 32];
    __shared__ ushort_t Bs[2][128 * 32];

    int flat = blockIdx.x;
    int wg = (flat & 7) * (G2_NWG / 8) + (flat >> 3);
    int by = wg & 7;
    int bxg = wg >> 3;

    int g, rb;
    if (bxg < NEXP * 5) { g = bxg / 5; rb = bxg % 5; }
    else { g = NEXP; rb = bxg - NEXP * 5; }
    int Mg = (g < NEXP) ? counts_cap[g] : N_TOK;
    int m0 = rb * 256;
    if (m0 >= Mg) return;
    size_t abase = ((g < NEXP) ? (size_t)g * CAP : (size_t)ECAP) + m0;
    const ushort_t* Bt = (g < NEXP) ? (w2t + (size_t)g * FDIM * DIM) : sw2t;
    int n0 = by * 128;
    int t = threadIdx.x;

    const ushort_t* asrc[2];
    const ushort_t* bsrc;
#pragma unroll
    for (int i = 0; i < 2; ++i) {
        int s = t + i * 512;
        int lr = ((s >> 3) << 1) | ((s >> 2) & 1);
        int qq = (s & 3) ^ ((s >> 3) & 3);
        asrc[i] = h_buf + (abase + lr) * FDIM + qq * 8;
    }
    {
        int s = t;
        int lr = ((s >> 3) << 1) | ((s >> 2) & 1);
        int qq = (s & 3) ^ ((s >> 3) & 3);
        bsrc = Bt + (size_t)(n0 + lr) * FDIM + qq * 8;
    }

    int lane = t & 63;
    int w = t >> 6;
    int wm = (w & 3) * 64, wn = (w >> 2) * 64;
    int l15 = lane & 15, q = lane >> 4;

    int aoff[4], boff[4];
#pragma unroll
    for (int m = 0; m < 4; ++m) aoff[m] = swz_addr16(wm + m * 16 + l15, q) << 3;
#pragma unroll
    for (int n = 0; n < 4; ++n) boff[n] = swz_addr16(wn + n * 16 + l15, q) << 3;

    f32x4 acc[4][4];
#pragma unroll
    for (int m = 0; m < 4; ++m)
#pragma unroll
        for (int n = 0; n < 4; ++n) acc[m][n] = (f32x4){0.f, 0.f, 0.f, 0.f};

    auto STAGE = [&](int buf, int koff) {
        gload16(asrc[0] + koff, &As[buf][t * 8]);
        gload16(asrc[1] + koff, &As[buf][t * 8 + 4096]);
        gload16(bsrc + koff, &Bs[buf][t * 8]);
    };

    const int NSTEP = FDIM / 32;  // 16
    STAGE(0, 0);
    __syncthreads();

    int cur = 0;
    for (int kt = 0; kt < NSTEP; ++kt) {
        if (kt + 1 < NSTEP) STAGE(cur ^ 1, (kt + 1) * 32);
        const ushort_t* asb = &As[cur][0];
        const ushort_t* bsb = &Bs[cur][0];
        bf16x8 af[4], bfr[4];
#pragma unroll
        for (int m = 0; m < 4; ++m)
            af[m] = *reinterpret_cast<const bf16x8*>(asb + aoff[m]);
#pragma unroll
        for (int n = 0; n < 4; ++n)
            bfr[n] = *reinterpret_cast<const bf16x8*>(bsb + boff[n]);
        __builtin_amdgcn_s_setprio(1);
#pragma unroll
        for (int m = 0; m < 4; ++m)
#pragma unroll
            for (int n = 0; n < 4; ++n)
                acc[m][n] = __builtin_amdgcn_mfma_f32_16x16x32_bf16(
                    af[m], bfr[n], acc[m][n], 0, 0, 0);
        __builtin_amdgcn_s_setprio(0);
        __syncthreads();
        cur ^= 1;
    }

    if (g < NEXP) {
#pragma unroll
        for (int m = 0; m < 4; ++m) {
#pragma unroll
            for (int r = 0; r < 4; ++r) {
                int grow = wm + m * 16 + q * 4 + r;
                ushort_t* orow = out_buf + (abase + grow) * DIM + n0 + wn + l15;
#pragma unroll
                for (int n = 0; n < 4; ++n)
                    orow[n * 16] = f2b(acc[m][n][r]);
            }
        }
    } else {
#pragma unroll
        for (int m = 0; m < 4; ++m) {
#pragma unroll
            for (int r = 0; r < 4; ++r) {
                int tok = m0 + wm + m * 16 + q * 4 + r;
                float gs = g_shared[tok];
                ushort_t* orow = sh_out + (size_t)tok * DIM + n0 + wn + l15;
#pragma unroll
                for (int n = 0; n < 4; ++n)
                    orow[n * 16] = f2b(gs * acc[m][n][r]);
            }
        }
    }
}

// ---------------- combine: y = sh_out + sum(gate * expert_out), write-only ----------------
__global__ __launch_bounds__(256) void combine_kernel(
    const ushort_t* __restrict__ out_buf, const ushort_t* __restrict__ sh_out,
    const int* __restrict__ route_slot, const float* __restrict__ topk_val,
    float* __restrict__ y)
{
    int token = blockIdx.x;
    int c = threadIdx.x * 4;
    ushort4 sv = *reinterpret_cast<const ushort4*>(sh_out + (size_t)token * DIM + c);
    float y0 = bf2f(sv.x), y1 = bf2f(sv.y), y2 = bf2f(sv.z), y3 = bf2f(sv.w);
#pragma unroll
    for (int k = 0; k < 2; ++k) {
        int s = route_slot[2 * token + k];
        if (s >= 0) {
            float gate = topk_val[2 * token + k];
            ushort4 rv = *reinterpret_cast<const ushort4*>(out_buf + (size_t)s * DIM + c);
            y0 += gate * bf2f(rv.x); y1 += gate * bf2f(rv.y);
            y2 += gate * bf2f(rv.z); y3 += gate * bf2f(rv.w);
        }
    }
    float4 o; o.x = y0; o.y = y1; o.z = y2; o.w = y3;
    *reinterpret_cast<float4*>(y + (size_t)token * DIM + c) = o;
}

extern "C" void kernel_launch(void* const* d_in, const int* in_sizes, int n_in,
                              void* d_out, int out_size, void* d_ws, size_t ws_size,
                              hipStream_t stream) {
    const float* x   = (const float*)d_in[0];
    const float* rw  = (const float*)d_in[1];
    const float* sgw = (const float*)d_in[2];
    const float* w1  = (const float*)d_in[3];
    const float* w2  = (const float*)d_in[4];
    const float* sw1 = (const float*)d_in[5];
    const float* sw2 = (const float*)d_in[6];
    float* y = (float*)d_out;
    float* out_tail = y + (size_t)N_TOK * DIM;

    size_t off = 0;
    char* wsb = (char*)d_ws;
    auto alloc = [&](size_t bytes) -> void* {
        void* p = wsb + off;
        off += (bytes + 255) & ~(size_t)255;
        return p;
    };
    float*    scores     = (float*)alloc((size_t)N_TOK * NEXP * 4);
    int*      topk_idx   = (int*)alloc((size_t)NROUTE * 4);
    float*    topk_val   = (float*)alloc((size_t)NROUTE * 4);
    float*    g_shared   = (float*)alloc((size_t)N_TOK * 4);
    int*      chunk_hist = (int*)alloc((size_t)NCHUNK * NEXP * 4);
    int*      chunk_off  = (int*)alloc((size_t)NCHUNK * NEXP * 4);
    int*      counts_cap = (int*)alloc((size_t)NEXP * 4);
    int*      route_slot = (int*)alloc((size_t)NROUTE * 4);
    int*      slot_token = (int*)alloc((size_t)ECAP * 4);
    ushort_t* out_buf    = (ushort_t*)alloc((size_t)ECAP * DIM * 2);
    // x_bf [N_TOK][DIM] reused as sh_out after gemm1 (x_bf dead post-gemm1).
    ushort_t* x_bf       = (ushort_t*)alloc((size_t)N_TOK * DIM * 2);
    ushort_t* sh_out     = x_bf;
    ushort_t* w1t        = (ushort_t*)alloc((size_t)NEXP * DIM * FDIM * 2);
    ushort_t* w2t        = (ushort_t*)alloc((size_t)NEXP * DIM * FDIM * 2);
    ushort_t* sw1t       = (ushort_t*)alloc((size_t)DIM * FDIM * 2);
    ushort_t* sw2t       = (ushort_t*)alloc((size_t)DIM * FDIM * 2);
    ushort_t* h_buf      = (ushort_t*)alloc((size_t)TOTROW * FDIM * 2);
    (void)ws_size; (void)in_sizes; (void)n_in; (void)out_size;

    prep_kernel<<<PREP_NWG, 256, 0, stream>>>(
        x, rw, sgw, w1, w2, sw1, sw2,
        scores, topk_idx, topk_val, g_shared, x_bf, w1t, w2t, sw1t, sw2t);
    hist_kernel<<<NCHUNK, 256, 0, stream>>>(topk_idx, chunk_hist);
    scan_kernel<<<1, 64, 0, stream>>>(chunk_hist, chunk_off, counts_cap, out_tail);
    assign_kernel<<<NCHUNK, 256, 0, stream>>>(topk_idx, topk_val, chunk_off, route_slot, slot_token);
    importance_kernel<<<NEXP, 256, 0, stream>>>(scores, out_tail);

    gemm1_mfma<<<G1_NWG, 512, 0, stream>>>(x_bf, w1t, sw1t, slot_token, counts_cap, h_buf);
    gemm2_mfma<<<G2_NWG, 512, 0, stream>>>(h_buf, w2t, sw2t, counts_cap, g_shared, out_buf, sh_out);

    combine_kernel<<<N_TOK, 256, 0, stream>>>(out_buf, sh_out, route_slot, topk_val, y);
}

// Round 22
// 146.678 us; speedup vs baseline: 1.3736x; 1.0288x over previous
//
#include <hip/hip_runtime.h>
#include <hip/hip_bf16.h>
#include <math.h>

#define N_TOK 8192
#define DIM 1024
#define NEXP 16
#define CAP 1280
#define FDIM 512
#define NROUTE (N_TOK * 2)
#define NCHUNK 64
#define ECAP (NEXP * CAP)        /* 20480 */
#define TOTROW (ECAP + N_TOK)    /* 28672 */

typedef __hip_bfloat16 bf16;
typedef unsigned short ushort_t;
typedef __attribute__((ext_vector_type(8))) short bf16x8;
typedef __attribute__((ext_vector_type(4))) float f32x4;

// xl layout constants (anti-bank-conflict, 2-way uniform):
// flat = tok*1104 + chunk*68 + (d&63), chunk = d>>6 (16 chunks of 64 floats)
#define XL_CH 68
#define XL_TOK 1104

// tanh-approx gelu via sigmoid; |err| vs erf-gelu ~1e-3 << tolerance.
__device__ __forceinline__ float gelu_fast(float x) {
    float u = 1.5957691216057308f * (x + 0.044715f * x * x * x);
    return x / (1.f + __expf(-u));
}

__device__ __forceinline__ float bf2f(unsigned short u) {
    union { float f; unsigned int i; } v; v.i = ((unsigned int)u) << 16; return v.f;
}

__device__ __forceinline__ unsigned short f2b(float f) {
    union { __hip_bfloat16 h; unsigned short u; } v;
    v.h = __float2bfloat16(f);
    return v.u;
}

__device__ __forceinline__ void gload16(const void* g, void* l) {
    __builtin_amdgcn_global_load_lds(
        (const __attribute__((address_space(1))) unsigned int*)g,
        (__attribute__((address_space(3))) unsigned int*)l,
        16, 0, 0);
}

// T2 both-sides swizzle (verified: SQ_LDS_BANK_CONFLICT -> 0 in GEMMs, rounds 5-21)
__device__ __forceinline__ int swz_addr16(int r, int q) {
    return ((r >> 1) << 3) + ((r & 1) << 2) + (q ^ ((r >> 1) & 3));
}

// ========== prep: router (blocks 0-2047) + w1/sw1 transpose (2048-3135) ==========
// w2/sw2 transpose moved into gemm1x's grid (hidden under gemm1's memory slack).
#define PREP_RTR_BLOCKS 2048
#define PREP_NWG (PREP_RTR_BLOCKS + 1088)
__global__ __launch_bounds__(256) void prep_kernel(
    const float* __restrict__ x, const float* __restrict__ rw,
    const float* __restrict__ sgw,
    const float* __restrict__ w1, const float* __restrict__ sw1,
    float* __restrict__ scores,
    int* __restrict__ topk_idx,
    float* __restrict__ topk_val,
    float* __restrict__ g_shared,
    ushort_t* __restrict__ x_bf,
    ushort_t* __restrict__ w1t, ushort_t* __restrict__ sw1t)
{
    __shared__ union {
        ushort_t tileB[64][129];             // transpose [n][k] bf16 (16.5KB)
        struct {
            float xl[4 * XL_TOK];            // router x tile, chunked (17.7KB)
            float racc[4][4][4][4];          // [wave][tok][e4][4]
            float g[4][4];
        } r;
    } sm;

    if (blockIdx.x < PREP_RTR_BLOCKS) {
        // ---------------- router v7 (4 tokens/block, chunked xl) ----------------
        int tid = threadIdx.x;
        int w = tid >> 6;
        int lane = tid & 63;
        int tok0 = blockIdx.x * 4;

        // pass 1: stage x rows -> LDS + bf16 emit + shared-gate partials
        {
            int dq = w * 256 + lane * 4;
            int xoff = (dq >> 6) * XL_CH + (dq & 63);
            float4 gv = *reinterpret_cast<const float4*>(sgw + dq);
#pragma unroll
            for (int tt = 0; tt < 4; ++tt) {
                const float* xr = x + (size_t)(tok0 + tt) * DIM + dq;
                float4 xv = *reinterpret_cast<const float4*>(xr);
                *reinterpret_cast<float4*>(&sm.r.xl[tt * XL_TOK + xoff]) = xv;
                ushort4 o;
                o.x = f2b(xv.x); o.y = f2b(xv.y); o.z = f2b(xv.z); o.w = f2b(xv.w);
                *reinterpret_cast<ushort4*>(x_bf + (size_t)(tok0 + tt) * DIM + dq) = o;
                float dg = xv.x * gv.x + xv.y * gv.y + xv.z * gv.z + xv.w * gv.w;
#pragma unroll
                for (int m = 1; m < 64; m <<= 1) dg += __shfl_xor(dg, m, 64);
                if (lane == 0) sm.r.g[w][tt] = dg;
            }
        }
        __syncthreads();

        // pass 2: logits from LDS. lane = (tok:2 | dup:2 | e4:2), dup covers 64 d.
        int tok = lane >> 4;
        int dup = (lane >> 2) & 3;
        int e4 = lane & 3;
        {
            int base_d = w * 256 + dup * 64;
            const float* xc = &sm.r.xl[tok * XL_TOK + (base_d >> 6) * XL_CH];
            const float* rwb = rw + (size_t)base_d * NEXP + e4 * 4;
            float4 a0 = {0,0,0,0}, a1 = {0,0,0,0}, a2 = {0,0,0,0}, a3 = {0,0,0,0};
#pragma unroll 4
            for (int i = 0; i < 16; ++i) {
                float4 xv = *reinterpret_cast<const float4*>(xc + i * 4);
                const float* rp = rwb + (size_t)i * 4 * NEXP;
                float4 w0 = *reinterpret_cast<const float4*>(rp);
                float4 w1v = *reinterpret_cast<const float4*>(rp + NEXP);
                float4 w2v = *reinterpret_cast<const float4*>(rp + 2 * NEXP);
                float4 w3v = *reinterpret_cast<const float4*>(rp + 3 * NEXP);
                a0.x += xv.x * w0.x;  a0.y += xv.x * w0.y;  a0.z += xv.x * w0.z;  a0.w += xv.x * w0.w;
                a1.x += xv.y * w1v.x; a1.y += xv.y * w1v.y; a1.z += xv.y * w1v.z; a1.w += xv.y * w1v.w;
                a2.x += xv.z * w2v.x; a2.y += xv.z * w2v.y; a2.z += xv.z * w2v.z; a2.w += xv.z * w2v.w;
                a3.x += xv.w * w3v.x; a3.y += xv.w * w3v.y; a3.z += xv.w * w3v.z; a3.w += xv.w * w3v.w;
            }
            float s0 = (a0.x + a1.x) + (a2.x + a3.x);
            float s1 = (a0.y + a1.y) + (a2.y + a3.y);
            float s2 = (a0.z + a1.z) + (a2.z + a3.z);
            float s3 = (a0.w + a1.w) + (a2.w + a3.w);
            s0 += __shfl_xor(s0, 4, 64);  s0 += __shfl_xor(s0, 8, 64);
            s1 += __shfl_xor(s1, 4, 64);  s1 += __shfl_xor(s1, 8, 64);
            s2 += __shfl_xor(s2, 4, 64);  s2 += __shfl_xor(s2, 8, 64);
            s3 += __shfl_xor(s3, 4, 64);  s3 += __shfl_xor(s3, 8, 64);
            if (dup == 0) {
                sm.r.racc[w][tok][e4][0] = s0;
                sm.r.racc[w][tok][e4][1] = s1;
                sm.r.racc[w][tok][e4][2] = s2;
                sm.r.racc[w][tok][e4][3] = s3;
            }
        }
        __syncthreads();

        if (tid >= 16) return;
        int tk = tid >> 2;
        int eq = tid & 3;
        int token = tok0 + tk;
        float L0 = sm.r.racc[0][tk][eq][0] + sm.r.racc[1][tk][eq][0]
                 + sm.r.racc[2][tk][eq][0] + sm.r.racc[3][tk][eq][0];
        float L1 = sm.r.racc[0][tk][eq][1] + sm.r.racc[1][tk][eq][1]
                 + sm.r.racc[2][tk][eq][1] + sm.r.racc[3][tk][eq][1];
        float L2 = sm.r.racc[0][tk][eq][2] + sm.r.racc[1][tk][eq][2]
                 + sm.r.racc[2][tk][eq][2] + sm.r.racc[3][tk][eq][2];
        float L3 = sm.r.racc[0][tk][eq][3] + sm.r.racc[1][tk][eq][3]
                 + sm.r.racc[2][tk][eq][3] + sm.r.racc[3][tk][eq][3];

        float mx = fmaxf(fmaxf(L0, L1), fmaxf(L2, L3));
        mx = fmaxf(mx, __shfl_xor(mx, 1, 4));
        mx = fmaxf(mx, __shfl_xor(mx, 2, 4));
        float P0 = expf(L0 - mx), P1 = expf(L1 - mx);
        float P2 = expf(L2 - mx), P3 = expf(L3 - mx);
        float s = (P0 + P1) + (P2 + P3);
        s += __shfl_xor(s, 1, 4);
        s += __shfl_xor(s, 2, 4);
        float inv = 1.f / s;
        P0 *= inv; P1 *= inv; P2 *= inv; P3 *= inv;

        float4 Pv = {P0, P1, P2, P3};
        *reinterpret_cast<float4*>(scores + (size_t)token * NEXP + eq * 4) = Pv;

        int base = eq * 4;
        float v = P0; int idx = base;
        if (P1 > v) { v = P1; idx = base + 1; }
        if (P2 > v) { v = P2; idx = base + 2; }
        if (P3 > v) { v = P3; idx = base + 3; }
#pragma unroll
        for (int m = 1; m < 4; m <<= 1) {
            float vo = __shfl_xor(v, m, 4);
            int io = __shfl_xor(idx, m, 4);
            if (vo > v || (vo == v && io < idx)) { v = vo; idx = io; }
        }
        int i0 = idx; float v0 = v;
        float q0 = (base + 0 == i0) ? -1.f : P0;
        float q1 = (base + 1 == i0) ? -1.f : P1;
        float q2 = (base + 2 == i0) ? -1.f : P2;
        float q3 = (base + 3 == i0) ? -1.f : P3;
        v = q0; idx = base;
        if (q1 > v) { v = q1; idx = base + 1; }
        if (q2 > v) { v = q2; idx = base + 2; }
        if (q3 > v) { v = q3; idx = base + 3; }
#pragma unroll
        for (int m = 1; m < 4; m <<= 1) {
            float vo = __shfl_xor(v, m, 4);
            int io = __shfl_xor(idx, m, 4);
            if (vo > v || (vo == v && io < idx)) { v = vo; idx = io; }
        }
        if (eq == 0) {
            topk_idx[2 * token] = i0; topk_idx[2 * token + 1] = idx;
            topk_val[2 * token] = v0; topk_val[2 * token + 1] = v;
            float ag = (sm.r.g[0][tk] + sm.r.g[1][tk]) + (sm.r.g[2][tk] + sm.r.g[3][tk]);
            g_shared[token] = 1.f / (1.f + expf(-ag));
        }
        return;
    }

    // ---------- w1/sw1 transpose, 64n x 128k tile: fp32 [K][N] -> bf16 [N][K] ----------
    int bx = blockIdx.x - PREP_RTR_BLOCKS;
    const float* src; ushort_t* dst; int K, N, kt, nt;
    if (bx < 1024) {                      // w1: per-expert [1024][512], 64 tiles
        int e = bx >> 6, r = bx & 63;
        K = 1024; N = 512; kt = r >> 3; nt = r & 7;
        src = w1 + (size_t)e * K * N; dst = w1t + (size_t)e * K * N;
    } else {                              // sw1 [1024][512], 64 tiles
        int r = bx - 1024;
        K = 1024; N = 512; kt = r >> 3; nt = r & 7;
        src = sw1; dst = sw1t;
    }
    int t = threadIdx.x;
#pragma unroll 4
    for (int i = 0; i < 8; ++i) {
        int u = t + 256 * i;
        int r = u >> 4;                 // k-local 0..127
        int c4 = (u & 15) * 4;          // n-local 0..60
        float4 v = *reinterpret_cast<const float4*>(
            src + (size_t)(kt * 128 + r) * N + nt * 64 + c4);
        sm.tileB[c4 + 0][r] = f2b(v.x);
        sm.tileB[c4 + 1][r] = f2b(v.y);
        sm.tileB[c4 + 2][r] = f2b(v.z);
        sm.tileB[c4 + 3][r] = f2b(v.w);
    }
    __syncthreads();
#pragma unroll 4
    for (int i2 = 0; i2 < 4; ++i2) {
        int u = t + 256 * i2;
        int n = u >> 4;                 // n-local 0..63
        int kc = (u & 15) * 8;          // k-chunk 0..120
        bf16x8 o;
#pragma unroll
        for (int j = 0; j < 8; ++j) o[j] = (short)sm.tileB[n][kc + j];
        *reinterpret_cast<bf16x8*>(dst + (size_t)(nt * 64 + n) * K + kt * 128 + kc) = o;
    }
}

// ---------------- per-chunk expert histogram ----------------
__global__ __launch_bounds__(256) void hist_kernel(
    const int* __restrict__ topk_idx, int* __restrict__ chunk_hist)
{
    __shared__ int h[NEXP];
    int tid = threadIdx.x;
    if (tid < NEXP) h[tid] = 0;
    __syncthreads();
    int r = blockIdx.x * 256 + tid;
    atomicAdd(&h[topk_idx[r]], 1);
    __syncthreads();
    if (tid < NEXP) chunk_hist[blockIdx.x * NEXP + tid] = h[tid];
}

// ---------------- scan chunk histograms ----------------
__global__ __launch_bounds__(64) void scan_kernel(
    const int* __restrict__ chunk_hist, int* __restrict__ chunk_off,
    int* __restrict__ counts_cap, float* __restrict__ out_tail)
{
    int e = threadIdx.x;
    if (e >= NEXP) return;
    int run = 0;
    for (int b = 0; b < NCHUNK; ++b) {
        chunk_off[b * NEXP + e] = run;
        run += chunk_hist[b * NEXP + e];
    }
    counts_cap[e] = run < CAP ? run : CAP;
    out_tail[NEXP + e] = (float)((double)run / 16384.0);
}

// ---------------- deterministic slot assignment ----------------
__global__ __launch_bounds__(256) void assign_kernel(
    const int* __restrict__ topk_idx, const float* __restrict__ topk_val,
    const int* __restrict__ chunk_off,
    int* __restrict__ route_slot, int* __restrict__ slot_token)
{
    __shared__ int wave_cnt[4][NEXP];
    int tid = threadIdx.x;
    int lane = tid & 63;
    int w = tid >> 6;
    int r = blockIdx.x * 256 + tid;
    int e = topk_idx[r];
    float gate = topk_val[r];
    int rank_w = 0;
#pragma unroll
    for (int e16 = 0; e16 < NEXP; ++e16) {
        unsigned long long bal = __ballot(e == e16);
        if (e == e16) rank_w = __popcll(bal & ((1ull << lane) - 1ull));
        if (lane == 0) wave_cnt[w][e16] = __popcll(bal);
    }
    __syncthreads();
    int rank = rank_w;
#pragma unroll
    for (int w2 = 0; w2 < 3; ++w2)
        if (w2 < w) rank += wave_cnt[w2][e];
    int pos = chunk_off[blockIdx.x * NEXP + e] + rank;
    int slot = -1;
    if (pos < CAP && gate != 0.f) {
        slot = e * CAP + pos;
        slot_token[slot] = r >> 1;
    }
    route_slot[r] = slot;
}

// ---------------- importance reduction ----------------
__global__ __launch_bounds__(256) void importance_kernel(
    const float* __restrict__ scores, float* __restrict__ out_tail)
{
    __shared__ float red[256];
    int e = blockIdx.x;
    float s = 0.f;
    for (int t = threadIdx.x; t < N_TOK; t += 256) s += scores[t * NEXP + e];
    red[threadIdx.x] = s;
    __syncthreads();
    for (int st = 128; st > 0; st >>= 1) {
        if (threadIdx.x < st) red[threadIdx.x] += red[threadIdx.x + st];
        __syncthreads();
    }
    if (threadIdx.x == 0) out_tail[e] = red[0] / (float)N_TOK;
}

// ============ gemm1x: gemm1 (blocks 0-447) + w2/sw2 transpose (448-1535) ============
// gemm1: 256x128 tile, 8 waves, BK=32, 3-buffer, counted vmcnt(3), setprio, T1+T2,
// fused slot_token gather in A-staging. Transpose blocks (512 thr) fill gemm1's
// memory slack; same-launch ordering guarantees w2t ready before gemm2.
#define G1_GX (NEXP * 5 + N_TOK / 256)      /* 112 */
#define G1_NWG (G1_GX * (FDIM / 128))       /* 448 */
#define G1X_NWG (G1_NWG + 1088)
__global__ __launch_bounds__(512) void gemm1x_kernel(
    const ushort_t* __restrict__ x_bf,      // [N_TOK][DIM] bf16
    const ushort_t* __restrict__ w1t,       // [16][FDIM][DIM] bf16 n-major
    const ushort_t* __restrict__ sw1t,      // [FDIM][DIM]
    const int* __restrict__ slot_token,     // [ECAP]
    const int* __restrict__ counts_cap,
    ushort_t* __restrict__ h_buf,           // [TOTROW][FDIM] bf16
    const float* __restrict__ w2, const float* __restrict__ sw2,
    ushort_t* __restrict__ w2t, ushort_t* __restrict__ sw2t)
{
    __shared__ union {
        struct {
            ushort_t As[3][256 * 32];
            ushort_t Bs[3][128 * 32];
        } g;
        ushort_t tileB[64][129];
    } sm;

    int t = threadIdx.x;

    if (blockIdx.x >= G1_NWG) {
        // ---------- w2/sw2 transpose, 64n x 128k tile, 512 threads ----------
        int bx = blockIdx.x - G1_NWG;
        const float* src; ushort_t* dst; int K, N, kt, nt;
        if (bx < 1024) {                  // w2: per-expert [512][1024], 64 tiles
            int e = bx >> 6, r = bx & 63;
            K = 512; N = 1024; kt = r >> 4; nt = r & 15;
            src = w2 + (size_t)e * K * N; dst = w2t + (size_t)e * K * N;
        } else {                          // sw2 [512][1024], 64 tiles
            int r = bx - 1024;
            K = 512; N = 1024; kt = r >> 4; nt = r & 15;
            src = sw2; dst = sw2t;
        }
#pragma unroll 4
        for (int i = 0; i < 4; ++i) {
            int u = t + 512 * i;
            int r = u >> 4;               // k-local 0..127
            int c4 = (u & 15) * 4;        // n-local 0..60
            float4 v = *reinterpret_cast<const float4*>(
                src + (size_t)(kt * 128 + r) * N + nt * 64 + c4);
            sm.tileB[c4 + 0][r] = f2b(v.x);
            sm.tileB[c4 + 1][r] = f2b(v.y);
            sm.tileB[c4 + 2][r] = f2b(v.z);
            sm.tileB[c4 + 3][r] = f2b(v.w);
        }
        __syncthreads();
#pragma unroll 2
        for (int i2 = 0; i2 < 2; ++i2) {
            int u = t + 512 * i2;
            int n = u >> 4;               // n-local 0..63
            int kc = (u & 15) * 8;        // k-chunk 0..120
            bf16x8 o;
#pragma unroll
            for (int j = 0; j < 8; ++j) o[j] = (short)sm.tileB[n][kc + j];
            *reinterpret_cast<bf16x8*>(dst + (size_t)(nt * 64 + n) * K + kt * 128 + kc) = o;
        }
        return;
    }

    // ---------------- gemm1 ----------------
    int flat = blockIdx.x;
    int wg = (flat & 7) * (G1_NWG / 8) + (flat >> 3);   // T1 (448 % 8 == 0)
    int by = wg & 3;
    int bxg = wg >> 2;

    int g, rb;
    if (bxg < NEXP * 5) { g = bxg / 5; rb = bxg % 5; }
    else { g = NEXP; rb = bxg - NEXP * 5; }
    int Mg = (g < NEXP) ? counts_cap[g] : N_TOK;
    int m0 = rb * 256;
    if (m0 >= Mg) return;
    const ushort_t* Bt = (g < NEXP) ? (w1t + (size_t)g * DIM * FDIM) : sw1t;
    int n0 = by * 128;

    const ushort_t* asrc[2];
    const ushort_t* bsrc;
#pragma unroll
    for (int i = 0; i < 2; ++i) {
        int s = t + i * 512;
        int lr = ((s >> 3) << 1) | ((s >> 2) & 1);
        int qq = (s & 3) ^ ((s >> 3) & 3);
        int row = m0 + lr;
        const ushort_t* base;
        if (g < NEXP) {
            int tok = (row < Mg) ? slot_token[g * CAP + row] : 0;
            if ((unsigned)tok >= N_TOK) tok = 0;   // poison guard
            base = x_bf + (size_t)tok * DIM;
        } else {
            base = x_bf + (size_t)row * DIM;
        }
        asrc[i] = base + qq * 8;
    }
    {
        int s = t;
        int lr = ((s >> 3) << 1) | ((s >> 2) & 1);
        int qq = (s & 3) ^ ((s >> 3) & 3);
        bsrc = Bt + (size_t)(n0 + lr) * DIM + qq * 8;
    }

    int lane = t & 63;
    int w = t >> 6;
    int wm = (w & 3) * 64, wn = (w >> 2) * 64;
    int l15 = lane & 15, q = lane >> 4;

    int aoff[4], boff[4];
#pragma unroll
    for (int m = 0; m < 4; ++m) aoff[m] = swz_addr16(wm + m * 16 + l15, q) << 3;
#pragma unroll
    for (int n = 0; n < 4; ++n) boff[n] = swz_addr16(wn + n * 16 + l15, q) << 3;

    f32x4 acc[4][4];
#pragma unroll
    for (int m = 0; m < 4; ++m)
#pragma unroll
        for (int n = 0; n < 4; ++n) acc[m][n] = (f32x4){0.f, 0.f, 0.f, 0.f};

    auto STAGE = [&](int buf, int koff) {
        gload16(asrc[0] + koff, &sm.g.As[buf][t * 8]);
        gload16(asrc[1] + koff, &sm.g.As[buf][t * 8 + 4096]);
        gload16(bsrc + koff, &sm.g.Bs[buf][t * 8]);
    };

    const int NSTEP = DIM / 32;   // 32
    STAGE(0, 0);
    STAGE(1, 32);
    asm volatile("s_waitcnt vmcnt(3)" ::: "memory");
    __builtin_amdgcn_s_barrier();
    asm volatile("" ::: "memory");

    int cur = 0, b2 = 2;
    for (int kt = 0; kt < NSTEP; ++kt) {
        if (kt + 2 < NSTEP) STAGE(b2, (kt + 2) * 32);
        const ushort_t* asb = &sm.g.As[cur][0];
        const ushort_t* bsb = &sm.g.Bs[cur][0];
        bf16x8 af[4], bfr[4];
#pragma unroll
        for (int m = 0; m < 4; ++m)
            af[m] = *reinterpret_cast<const bf16x8*>(asb + aoff[m]);
#pragma unroll
        for (int n = 0; n < 4; ++n)
            bfr[n] = *reinterpret_cast<const bf16x8*>(bsb + boff[n]);
        __builtin_amdgcn_s_setprio(1);
#pragma unroll
        for (int m = 0; m < 4; ++m)
#pragma unroll
            for (int n = 0; n < 4; ++n)
                acc[m][n] = __builtin_amdgcn_mfma_f32_16x16x32_bf16(
                    af[m], bfr[n], acc[m][n], 0, 0, 0);
        __builtin_amdgcn_s_setprio(0);
        if (kt + 1 < NSTEP) {
            if (kt + 2 < NSTEP) asm volatile("s_waitcnt vmcnt(3)" ::: "memory");
            else                asm volatile("s_waitcnt vmcnt(0)" ::: "memory");
            __builtin_amdgcn_s_barrier();
            asm volatile("" ::: "memory");
        }
        cur = (cur == 2) ? 0 : cur + 1;
        b2  = (b2 == 2) ? 0 : b2 + 1;
    }

    size_t obase = ((g < NEXP) ? (size_t)g * CAP : (size_t)ECAP) + m0;
#pragma unroll
    for (int m = 0; m < 4; ++m) {
#pragma unroll
        for (int r = 0; r < 4; ++r) {
            int grow = wm + m * 16 + q * 4 + r;
            ushort_t* orow = h_buf + (obase + grow) * FDIM + n0 + wn + l15;
#pragma unroll
            for (int n = 0; n < 4; ++n)
                orow[n * 16] = f2b(gelu_fast(acc[m][n][r]));
        }
    }
}

// ================= MFMA grouped GEMM 2: out = H @ W2 =================
// 256x128 tile, 8 waves, BK=32, 2-buffer (48KB, occupancy), setprio, T1+T2.
#define G2_NWG (G1_GX * (DIM / 128))        /* 896 */
__global__ __launch_bounds__(512) void gemm2_mfma(
    const ushort_t* __restrict__ h_buf,     // [TOTROW][FDIM] bf16
    const ushort_t* __restrict__ w2t,       // [16][DIM][FDIM] bf16 n-major
    const ushort_t* __restrict__ sw2t,      // [DIM][FDIM]
    const int* __restrict__ counts_cap,
    const float* __restrict__ g_shared,
    ushort_t* __restrict__ out_buf,         // [ECAP][DIM] bf16
    ushort_t* __restrict__ sh_out)          // [N_TOK][DIM] bf16 (x_bf reuse)
{
    __shared__ ushort_t As[2][256 * 32];
    __shared__ ushort_t Bs[2][128 * 32];

    int flat = blockIdx.x;
    int wg = (flat & 7) * (G2_NWG / 8) + (flat >> 3);
    int by = wg & 7;
    int bxg = wg >> 3;

    int g, rb;
    if (bxg < NEXP * 5) { g = bxg / 5; rb = bxg % 5; }
    else { g = NEXP; rb = bxg - NEXP * 5; }
    int Mg = (g < NEXP) ? counts_cap[g] : N_TOK;
    int m0 = rb * 256;
    if (m0 >= Mg) return;
    size_t abase = ((g < NEXP) ? (size_t)g * CAP : (size_t)ECAP) + m0;
    const ushort_t* Bt = (g < NEXP) ? (w2t + (size_t)g * FDIM * DIM) : sw2t;
    int n0 = by * 128;
    int t = threadIdx.x;

    const ushort_t* asrc[2];
    const ushort_t* bsrc;
#pragma unroll
    for (int i = 0; i < 2; ++i) {
        int s = t + i * 512;
        int lr = ((s >> 3) << 1) | ((s >> 2) & 1);
        int qq = (s & 3) ^ ((s >> 3) & 3);
        asrc[i] = h_buf + (abase + lr) * FDIM + qq * 8;
    }
    {
        int s = t;
        int lr = ((s >> 3) << 1) | ((s >> 2) & 1);
        int qq = (s & 3) ^ ((s >> 3) & 3);
        bsrc = Bt + (size_t)(n0 + lr) * FDIM + qq * 8;
    }

    int lane = t & 63;
    int w = t >> 6;
    int wm = (w & 3) * 64, wn = (w >> 2) * 64;
    int l15 = lane & 15, q = lane >> 4;

    int aoff[4], boff[4];
#pragma unroll
    for (int m = 0; m < 4; ++m) aoff[m] = swz_addr16(wm + m * 16 + l15, q) << 3;
#pragma unroll
    for (int n = 0; n < 4; ++n) boff[n] = swz_addr16(wn + n * 16 + l15, q) << 3;

    f32x4 acc[4][4];
#pragma unroll
    for (int m = 0; m < 4; ++m)
#pragma unroll
        for (int n = 0; n < 4; ++n) acc[m][n] = (f32x4){0.f, 0.f, 0.f, 0.f};

    auto STAGE = [&](int buf, int koff) {
        gload16(asrc[0] + koff, &As[buf][t * 8]);
        gload16(asrc[1] + koff, &As[buf][t * 8 + 4096]);
        gload16(bsrc + koff, &Bs[buf][t * 8]);
    };

    const int NSTEP = FDIM / 32;  // 16
    STAGE(0, 0);
    __syncthreads();

    int cur = 0;
    for (int kt = 0; kt < NSTEP; ++kt) {
        if (kt + 1 < NSTEP) STAGE(cur ^ 1, (kt + 1) * 32);
        const ushort_t* asb = &As[cur][0];
        const ushort_t* bsb = &Bs[cur][0];
        bf16x8 af[4], bfr[4];
#pragma unroll
        for (int m = 0; m < 4; ++m)
            af[m] = *reinterpret_cast<const bf16x8*>(asb + aoff[m]);
#pragma unroll
        for (int n = 0; n < 4; ++n)
            bfr[n] = *reinterpret_cast<const bf16x8*>(bsb + boff[n]);
        __builtin_amdgcn_s_setprio(1);
#pragma unroll
        for (int m = 0; m < 4; ++m)
#pragma unroll
            for (int n = 0; n < 4; ++n)
                acc[m][n] = __builtin_amdgcn_mfma_f32_16x16x32_bf16(
                    af[m], bfr[n], acc[m][n], 0, 0, 0);
        __builtin_amdgcn_s_setprio(0);
        __syncthreads();
        cur ^= 1;
    }

    if (g < NEXP) {
#pragma unroll
        for (int m = 0; m < 4; ++m) {
#pragma unroll
            for (int r = 0; r < 4; ++r) {
                int grow = wm + m * 16 + q * 4 + r;
                ushort_t* orow = out_buf + (abase + grow) * DIM + n0 + wn + l15;
#pragma unroll
                for (int n = 0; n < 4; ++n)
                    orow[n * 16] = f2b(acc[m][n][r]);
            }
        }
    } else {
#pragma unroll
        for (int m = 0; m < 4; ++m) {
#pragma unroll
            for (int r = 0; r < 4; ++r) {
                int tok = m0 + wm + m * 16 + q * 4 + r;
                float gs = g_shared[tok];
                ushort_t* orow = sh_out + (size_t)tok * DIM + n0 + wn + l15;
#pragma unroll
                for (int n = 0; n < 4; ++n)
                    orow[n * 16] = f2b(gs * acc[m][n][r]);
            }
        }
    }
}

// ---------------- combine: y = sh_out + sum(gate * expert_out), write-only ----------------
__global__ __launch_bounds__(256) void combine_kernel(
    const ushort_t* __restrict__ out_buf, const ushort_t* __restrict__ sh_out,
    const int* __restrict__ route_slot, const float* __restrict__ topk_val,
    float* __restrict__ y)
{
    int token = blockIdx.x;
    int c = threadIdx.x * 4;
    ushort4 sv = *reinterpret_cast<const ushort4*>(sh_out + (size_t)token * DIM + c);
    float y0 = bf2f(sv.x), y1 = bf2f(sv.y), y2 = bf2f(sv.z), y3 = bf2f(sv.w);
#pragma unroll
    for (int k = 0; k < 2; ++k) {
        int s = route_slot[2 * token + k];
        if (s >= 0) {
            float gate = topk_val[2 * token + k];
            ushort4 rv = *reinterpret_cast<const ushort4*>(out_buf + (size_t)s * DIM + c);
            y0 += gate * bf2f(rv.x); y1 += gate * bf2f(rv.y);
            y2 += gate * bf2f(rv.z); y3 += gate * bf2f(rv.w);
        }
    }
    float4 o; o.x = y0; o.y = y1; o.z = y2; o.w = y3;
    *reinterpret_cast<float4*>(y + (size_t)token * DIM + c) = o;
}

extern "C" void kernel_launch(void* const* d_in, const int* in_sizes, int n_in,
                              void* d_out, int out_size, void* d_ws, size_t ws_size,
                              hipStream_t stream) {
    const float* x   = (const float*)d_in[0];
    const float* rw  = (const float*)d_in[1];
    const float* sgw = (const float*)d_in[2];
    const float* w1  = (const float*)d_in[3];
    const float* w2  = (const float*)d_in[4];
    const float* sw1 = (const float*)d_in[5];
    const float* sw2 = (const float*)d_in[6];
    float* y = (float*)d_out;
    float* out_tail = y + (size_t)N_TOK * DIM;

    size_t off = 0;
    char* wsb = (char*)d_ws;
    auto alloc = [&](size_t bytes) -> void* {
        void* p = wsb + off;
        off += (bytes + 255) & ~(size_t)255;
        return p;
    };
    float*    scores     = (float*)alloc((size_t)N_TOK * NEXP * 4);
    int*      topk_idx   = (int*)alloc((size_t)NROUTE * 4);
    float*    topk_val   = (float*)alloc((size_t)NROUTE * 4);
    float*    g_shared   = (float*)alloc((size_t)N_TOK * 4);
    int*      chunk_hist = (int*)alloc((size_t)NCHUNK * NEXP * 4);
    int*      chunk_off  = (int*)alloc((size_t)NCHUNK * NEXP * 4);
    int*      counts_cap = (int*)alloc((size_t)NEXP * 4);
    int*      route_slot = (int*)alloc((size_t)NROUTE * 4);
    int*      slot_token = (int*)alloc((size_t)ECAP * 4);
    ushort_t* out_buf    = (ushort_t*)alloc((size_t)ECAP * DIM * 2);
    // x_bf [N_TOK][DIM] reused as sh_out after gemm1 (x_bf dead post-gemm1).
    ushort_t* x_bf       = (ushort_t*)alloc((size_t)N_TOK * DIM * 2);
    ushort_t* sh_out     = x_bf;
    ushort_t* w1t        = (ushort_t*)alloc((size_t)NEXP * DIM * FDIM * 2);
    ushort_t* w2t        = (ushort_t*)alloc((size_t)NEXP * DIM * FDIM * 2);
    ushort_t* sw1t       = (ushort_t*)alloc((size_t)DIM * FDIM * 2);
    ushort_t* sw2t       = (ushort_t*)alloc((size_t)DIM * FDIM * 2);
    ushort_t* h_buf      = (ushort_t*)alloc((size_t)TOTROW * FDIM * 2);
    (void)ws_size; (void)in_sizes; (void)n_in; (void)out_size;

    prep_kernel<<<PREP_NWG, 256, 0, stream>>>(
        x, rw, sgw, w1, sw1,
        scores, topk_idx, topk_val, g_shared, x_bf, w1t, sw1t);
    hist_kernel<<<NCHUNK, 256, 0, stream>>>(topk_idx, chunk_hist);
    scan_kernel<<<1, 64, 0, stream>>>(chunk_hist, chunk_off, counts_cap, out_tail);
    assign_kernel<<<NCHUNK, 256, 0, stream>>>(topk_idx, topk_val, chunk_off, route_slot, slot_token);
    importance_kernel<<<NEXP, 256, 0, stream>>>(scores, out_tail);

    gemm1x_kernel<<<G1X_NWG, 512, 0, stream>>>(
        x_bf, w1t, sw1t, slot_token, counts_cap, h_buf, w2, sw2, w2t, sw2t);
    gemm2_mfma<<<G2_NWG, 512, 0, stream>>>(h_buf, w2t, sw2t, counts_cap, g_shared, out_buf, sh_out);

    combine_kernel<<<N_TOK, 256, 0, stream>>>(out_buf, sh_out, route_slot, topk_val, y);
}

// Round 23
// 144.852 us; speedup vs baseline: 1.3909x; 1.0126x over previous
//
#include <hip/hip_runtime.h>
#include <hip/hip_bf16.h>
#include <math.h>

#define N_TOK 8192
#define DIM 1024
#define NEXP 16
#define CAP 1280
#define FDIM 512
#define NROUTE (N_TOK * 2)
#define NCHUNK 64
#define ECAP (NEXP * CAP)        /* 20480 */
#define TOTROW (ECAP + N_TOK)    /* 28672 */

typedef __hip_bfloat16 bf16;
typedef unsigned short ushort_t;
typedef __attribute__((ext_vector_type(8))) short bf16x8;
typedef __attribute__((ext_vector_type(4))) float f32x4;

// xl layout constants (anti-bank-conflict, 2-way uniform):
// flat = tok*1104 + chunk*68 + (d&63), chunk = d>>6 (16 chunks of 64 floats)
#define XL_CH 68
#define XL_TOK 1104

// tanh-approx gelu via sigmoid; |err| vs erf-gelu ~1e-3 << tolerance.
__device__ __forceinline__ float gelu_fast(float x) {
    float u = 1.5957691216057308f * (x + 0.044715f * x * x * x);
    return x / (1.f + __expf(-u));
}

__device__ __forceinline__ float bf2f(unsigned short u) {
    union { float f; unsigned int i; } v; v.i = ((unsigned int)u) << 16; return v.f;
}

__device__ __forceinline__ unsigned short f2b(float f) {
    union { __hip_bfloat16 h; unsigned short u; } v;
    v.h = __float2bfloat16(f);
    return v.u;
}

__device__ __forceinline__ void gload16(const void* g, void* l) {
    __builtin_amdgcn_global_load_lds(
        (const __attribute__((address_space(1))) unsigned int*)g,
        (__attribute__((address_space(3))) unsigned int*)l,
        16, 0, 0);
}

// T2 both-sides swizzle (verified: SQ_LDS_BANK_CONFLICT -> 0 in GEMMs, rounds 5-22)
__device__ __forceinline__ int swz_addr16(int r, int q) {
    return ((r >> 1) << 3) + ((r & 1) << 2) + (q ^ ((r >> 1) & 3));
}

// ========== prep: router (blocks 0-2047) + w1/sw1 transpose (2048-3135) ==========
#define PREP_RTR_BLOCKS 2048
#define PREP_NWG (PREP_RTR_BLOCKS + 1088)
__global__ __launch_bounds__(256) void prep_kernel(
    const float* __restrict__ x, const float* __restrict__ rw,
    const float* __restrict__ sgw,
    const float* __restrict__ w1, const float* __restrict__ sw1,
    float* __restrict__ scores,
    int* __restrict__ topk_idx,
    float* __restrict__ topk_val,
    float* __restrict__ g_shared,
    ushort_t* __restrict__ x_bf,
    ushort_t* __restrict__ w1t, ushort_t* __restrict__ sw1t)
{
    __shared__ union {
        ushort_t tileB[64][129];             // transpose [n][k] bf16 (16.5KB)
        struct {
            float xl[4 * XL_TOK];            // router x tile, chunked (17.7KB)
            float racc[4][4][4][4];          // [wave][tok][e4][4]
            float g[4][4];
        } r;
    } sm;

    if (blockIdx.x < PREP_RTR_BLOCKS) {
        // ---------------- router v7 (4 tokens/block, chunked xl) ----------------
        int tid = threadIdx.x;
        int w = tid >> 6;
        int lane = tid & 63;
        int tok0 = blockIdx.x * 4;

        // pass 1: stage x rows -> LDS + bf16 emit + shared-gate partials
        {
            int dq = w * 256 + lane * 4;
            int xoff = (dq >> 6) * XL_CH + (dq & 63);
            float4 gv = *reinterpret_cast<const float4*>(sgw + dq);
#pragma unroll
            for (int tt = 0; tt < 4; ++tt) {
                const float* xr = x + (size_t)(tok0 + tt) * DIM + dq;
                float4 xv = *reinterpret_cast<const float4*>(xr);
                *reinterpret_cast<float4*>(&sm.r.xl[tt * XL_TOK + xoff]) = xv;
                ushort4 o;
                o.x = f2b(xv.x); o.y = f2b(xv.y); o.z = f2b(xv.z); o.w = f2b(xv.w);
                *reinterpret_cast<ushort4*>(x_bf + (size_t)(tok0 + tt) * DIM + dq) = o;
                float dg = xv.x * gv.x + xv.y * gv.y + xv.z * gv.z + xv.w * gv.w;
#pragma unroll
                for (int m = 1; m < 64; m <<= 1) dg += __shfl_xor(dg, m, 64);
                if (lane == 0) sm.r.g[w][tt] = dg;
            }
        }
        __syncthreads();

        // pass 2: logits from LDS. lane = (tok:2 | dup:2 | e4:2), dup covers 64 d.
        int tok = lane >> 4;
        int dup = (lane >> 2) & 3;
        int e4 = lane & 3;
        {
            int base_d = w * 256 + dup * 64;
            const float* xc = &sm.r.xl[tok * XL_TOK + (base_d >> 6) * XL_CH];
            const float* rwb = rw + (size_t)base_d * NEXP + e4 * 4;
            float4 a0 = {0,0,0,0}, a1 = {0,0,0,0}, a2 = {0,0,0,0}, a3 = {0,0,0,0};
#pragma unroll 4
            for (int i = 0; i < 16; ++i) {
                float4 xv = *reinterpret_cast<const float4*>(xc + i * 4);
                const float* rp = rwb + (size_t)i * 4 * NEXP;
                float4 w0 = *reinterpret_cast<const float4*>(rp);
                float4 w1v = *reinterpret_cast<const float4*>(rp + NEXP);
                float4 w2v = *reinterpret_cast<const float4*>(rp + 2 * NEXP);
                float4 w3v = *reinterpret_cast<const float4*>(rp + 3 * NEXP);
                a0.x += xv.x * w0.x;  a0.y += xv.x * w0.y;  a0.z += xv.x * w0.z;  a0.w += xv.x * w0.w;
                a1.x += xv.y * w1v.x; a1.y += xv.y * w1v.y; a1.z += xv.y * w1v.z; a1.w += xv.y * w1v.w;
                a2.x += xv.z * w2v.x; a2.y += xv.z * w2v.y; a2.z += xv.z * w2v.z; a2.w += xv.z * w2v.w;
                a3.x += xv.w * w3v.x; a3.y += xv.w * w3v.y; a3.z += xv.w * w3v.z; a3.w += xv.w * w3v.w;
            }
            float s0 = (a0.x + a1.x) + (a2.x + a3.x);
            float s1 = (a0.y + a1.y) + (a2.y + a3.y);
            float s2 = (a0.z + a1.z) + (a2.z + a3.z);
            float s3 = (a0.w + a1.w) + (a2.w + a3.w);
            s0 += __shfl_xor(s0, 4, 64);  s0 += __shfl_xor(s0, 8, 64);
            s1 += __shfl_xor(s1, 4, 64);  s1 += __shfl_xor(s1, 8, 64);
            s2 += __shfl_xor(s2, 4, 64);  s2 += __shfl_xor(s2, 8, 64);
            s3 += __shfl_xor(s3, 4, 64);  s3 += __shfl_xor(s3, 8, 64);
            if (dup == 0) {
                sm.r.racc[w][tok][e4][0] = s0;
                sm.r.racc[w][tok][e4][1] = s1;
                sm.r.racc[w][tok][e4][2] = s2;
                sm.r.racc[w][tok][e4][3] = s3;
            }
        }
        __syncthreads();

        if (tid >= 16) return;
        int tk = tid >> 2;
        int eq = tid & 3;
        int token = tok0 + tk;
        float L0 = sm.r.racc[0][tk][eq][0] + sm.r.racc[1][tk][eq][0]
                 + sm.r.racc[2][tk][eq][0] + sm.r.racc[3][tk][eq][0];
        float L1 = sm.r.racc[0][tk][eq][1] + sm.r.racc[1][tk][eq][1]
                 + sm.r.racc[2][tk][eq][1] + sm.r.racc[3][tk][eq][1];
        float L2 = sm.r.racc[0][tk][eq][2] + sm.r.racc[1][tk][eq][2]
                 + sm.r.racc[2][tk][eq][2] + sm.r.racc[3][tk][eq][2];
        float L3 = sm.r.racc[0][tk][eq][3] + sm.r.racc[1][tk][eq][3]
                 + sm.r.racc[2][tk][eq][3] + sm.r.racc[3][tk][eq][3];

        float mx = fmaxf(fmaxf(L0, L1), fmaxf(L2, L3));
        mx = fmaxf(mx, __shfl_xor(mx, 1, 4));
        mx = fmaxf(mx, __shfl_xor(mx, 2, 4));
        float P0 = expf(L0 - mx), P1 = expf(L1 - mx);
        float P2 = expf(L2 - mx), P3 = expf(L3 - mx);
        float s = (P0 + P1) + (P2 + P3);
        s += __shfl_xor(s, 1, 4);
        s += __shfl_xor(s, 2, 4);
        float inv = 1.f / s;
        P0 *= inv; P1 *= inv; P2 *= inv; P3 *= inv;

        float4 Pv = {P0, P1, P2, P3};
        *reinterpret_cast<float4*>(scores + (size_t)token * NEXP + eq * 4) = Pv;

        int base = eq * 4;
        float v = P0; int idx = base;
        if (P1 > v) { v = P1; idx = base + 1; }
        if (P2 > v) { v = P2; idx = base + 2; }
        if (P3 > v) { v = P3; idx = base + 3; }
#pragma unroll
        for (int m = 1; m < 4; m <<= 1) {
            float vo = __shfl_xor(v, m, 4);
            int io = __shfl_xor(idx, m, 4);
            if (vo > v || (vo == v && io < idx)) { v = vo; idx = io; }
        }
        int i0 = idx; float v0 = v;
        float q0 = (base + 0 == i0) ? -1.f : P0;
        float q1 = (base + 1 == i0) ? -1.f : P1;
        float q2 = (base + 2 == i0) ? -1.f : P2;
        float q3 = (base + 3 == i0) ? -1.f : P3;
        v = q0; idx = base;
        if (q1 > v) { v = q1; idx = base + 1; }
        if (q2 > v) { v = q2; idx = base + 2; }
        if (q3 > v) { v = q3; idx = base + 3; }
#pragma unroll
        for (int m = 1; m < 4; m <<= 1) {
            float vo = __shfl_xor(v, m, 4);
            int io = __shfl_xor(idx, m, 4);
            if (vo > v || (vo == v && io < idx)) { v = vo; idx = io; }
        }
        if (eq == 0) {
            topk_idx[2 * token] = i0; topk_idx[2 * token + 1] = idx;
            topk_val[2 * token] = v0; topk_val[2 * token + 1] = v;
            float ag = (sm.r.g[0][tk] + sm.r.g[1][tk]) + (sm.r.g[2][tk] + sm.r.g[3][tk]);
            g_shared[token] = 1.f / (1.f + expf(-ag));
        }
        return;
    }

    // ---------- w1/sw1 transpose, 64n x 128k tile: fp32 [K][N] -> bf16 [N][K] ----------
    int bx = blockIdx.x - PREP_RTR_BLOCKS;
    const float* src; ushort_t* dst; int K, N, kt, nt;
    if (bx < 1024) {                      // w1: per-expert [1024][512], 64 tiles
        int e = bx >> 6, r = bx & 63;
        K = 1024; N = 512; kt = r >> 3; nt = r & 7;
        src = w1 + (size_t)e * K * N; dst = w1t + (size_t)e * K * N;
    } else {                              // sw1 [1024][512], 64 tiles
        int r = bx - 1024;
        K = 1024; N = 512; kt = r >> 3; nt = r & 7;
        src = sw1; dst = sw1t;
    }
    int t = threadIdx.x;
#pragma unroll 4
    for (int i = 0; i < 8; ++i) {
        int u = t + 256 * i;
        int r = u >> 4;                 // k-local 0..127
        int c4 = (u & 15) * 4;          // n-local 0..60
        float4 v = *reinterpret_cast<const float4*>(
            src + (size_t)(kt * 128 + r) * N + nt * 64 + c4);
        sm.tileB[c4 + 0][r] = f2b(v.x);
        sm.tileB[c4 + 1][r] = f2b(v.y);
        sm.tileB[c4 + 2][r] = f2b(v.z);
        sm.tileB[c4 + 3][r] = f2b(v.w);
    }
    __syncthreads();
#pragma unroll 4
    for (int i2 = 0; i2 < 4; ++i2) {
        int u = t + 256 * i2;
        int n = u >> 4;                 // n-local 0..63
        int kc = (u & 15) * 8;          // k-chunk 0..120
        bf16x8 o;
#pragma unroll
        for (int j = 0; j < 8; ++j) o[j] = (short)sm.tileB[n][kc + j];
        *reinterpret_cast<bf16x8*>(dst + (size_t)(nt * 64 + n) * K + kt * 128 + kc) = o;
    }
}

// ---------------- stats: per-chunk expert histogram (blocks 0-63) +
//                  importance reduction (blocks 64-79), fused ----------------
__global__ __launch_bounds__(256) void stats_kernel(
    const int* __restrict__ topk_idx, int* __restrict__ chunk_hist,
    const float* __restrict__ scores, float* __restrict__ out_tail)
{
    __shared__ union {
        int h[NEXP];
        float red[256];
    } sm;
    int tid = threadIdx.x;
    if (blockIdx.x < NCHUNK) {
        // histogram over this block's 256 routes
        if (tid < NEXP) sm.h[tid] = 0;
        __syncthreads();
        int r = blockIdx.x * 256 + tid;
        atomicAdd(&sm.h[topk_idx[r]], 1);
        __syncthreads();
        if (tid < NEXP) chunk_hist[blockIdx.x * NEXP + tid] = sm.h[tid];
        return;
    }
    // importance: expert e = blockIdx.x - NCHUNK
    int e = blockIdx.x - NCHUNK;
    float s = 0.f;
    for (int t = tid; t < N_TOK; t += 256) s += scores[t * NEXP + e];
    sm.red[tid] = s;
    __syncthreads();
    for (int st = 128; st > 0; st >>= 1) {
        if (tid < st) sm.red[tid] += sm.red[tid + st];
        __syncthreads();
    }
    if (tid == 0) out_tail[e] = sm.red[0] / (float)N_TOK;
}

// ---------------- scan chunk histograms ----------------
__global__ __launch_bounds__(64) void scan_kernel(
    const int* __restrict__ chunk_hist, int* __restrict__ chunk_off,
    int* __restrict__ counts_cap, float* __restrict__ out_tail)
{
    int e = threadIdx.x;
    if (e >= NEXP) return;
    int run = 0;
    for (int b = 0; b < NCHUNK; ++b) {
        chunk_off[b * NEXP + e] = run;
        run += chunk_hist[b * NEXP + e];
    }
    counts_cap[e] = run < CAP ? run : CAP;
    out_tail[NEXP + e] = (float)((double)run / 16384.0);
}

// ---------------- deterministic slot assignment ----------------
__global__ __launch_bounds__(256) void assign_kernel(
    const int* __restrict__ topk_idx, const float* __restrict__ topk_val,
    const int* __restrict__ chunk_off,
    int* __restrict__ route_slot, int* __restrict__ slot_token)
{
    __shared__ int wave_cnt[4][NEXP];
    int tid = threadIdx.x;
    int lane = tid & 63;
    int w = tid >> 6;
    int r = blockIdx.x * 256 + tid;
    int e = topk_idx[r];
    float gate = topk_val[r];
    int rank_w = 0;
#pragma unroll
    for (int e16 = 0; e16 < NEXP; ++e16) {
        unsigned long long bal = __ballot(e == e16);
        if (e == e16) rank_w = __popcll(bal & ((1ull << lane) - 1ull));
        if (lane == 0) wave_cnt[w][e16] = __popcll(bal);
    }
    __syncthreads();
    int rank = rank_w;
#pragma unroll
    for (int w2 = 0; w2 < 3; ++w2)
        if (w2 < w) rank += wave_cnt[w2][e];
    int pos = chunk_off[blockIdx.x * NEXP + e] + rank;
    int slot = -1;
    if (pos < CAP && gate != 0.f) {
        slot = e * CAP + pos;
        slot_token[slot] = r >> 1;
    }
    route_slot[r] = slot;
}

// ============ gemm1x: gemm1 (blocks 0-447) + w2/sw2 transpose (448-1535) ============
#define G1_GX (NEXP * 5 + N_TOK / 256)      /* 112 */
#define G1_NWG (G1_GX * (FDIM / 128))       /* 448 */
#define G1X_NWG (G1_NWG + 1088)
__global__ __launch_bounds__(512) void gemm1x_kernel(
    const ushort_t* __restrict__ x_bf,      // [N_TOK][DIM] bf16
    const ushort_t* __restrict__ w1t,       // [16][FDIM][DIM] bf16 n-major
    const ushort_t* __restrict__ sw1t,      // [FDIM][DIM]
    const int* __restrict__ slot_token,     // [ECAP]
    const int* __restrict__ counts_cap,
    ushort_t* __restrict__ h_buf,           // [TOTROW][FDIM] bf16
    const float* __restrict__ w2, const float* __restrict__ sw2,
    ushort_t* __restrict__ w2t, ushort_t* __restrict__ sw2t)
{
    __shared__ union {
        struct {
            ushort_t As[3][256 * 32];
            ushort_t Bs[3][128 * 32];
        } g;
        ushort_t tileB[64][129];
    } sm;

    int t = threadIdx.x;

    if (blockIdx.x >= G1_NWG) {
        // ---------- w2/sw2 transpose, 64n x 128k tile, 512 threads ----------
        int bx = blockIdx.x - G1_NWG;
        const float* src; ushort_t* dst; int K, N, kt, nt;
        if (bx < 1024) {                  // w2: per-expert [512][1024], 64 tiles
            int e = bx >> 6, r = bx & 63;
            K = 512; N = 1024; kt = r >> 4; nt = r & 15;
            src = w2 + (size_t)e * K * N; dst = w2t + (size_t)e * K * N;
        } else {                          // sw2 [512][1024], 64 tiles
            int r = bx - 1024;
            K = 512; N = 1024; kt = r >> 4; nt = r & 15;
            src = sw2; dst = sw2t;
        }
#pragma unroll 4
        for (int i = 0; i < 4; ++i) {
            int u = t + 512 * i;
            int r = u >> 4;               // k-local 0..127
            int c4 = (u & 15) * 4;        // n-local 0..60
            float4 v = *reinterpret_cast<const float4*>(
                src + (size_t)(kt * 128 + r) * N + nt * 64 + c4);
            sm.tileB[c4 + 0][r] = f2b(v.x);
            sm.tileB[c4 + 1][r] = f2b(v.y);
            sm.tileB[c4 + 2][r] = f2b(v.z);
            sm.tileB[c4 + 3][r] = f2b(v.w);
        }
        __syncthreads();
#pragma unroll 2
        for (int i2 = 0; i2 < 2; ++i2) {
            int u = t + 512 * i2;
            int n = u >> 4;               // n-local 0..63
            int kc = (u & 15) * 8;        // k-chunk 0..120
            bf16x8 o;
#pragma unroll
            for (int j = 0; j < 8; ++j) o[j] = (short)sm.tileB[n][kc + j];
            *reinterpret_cast<bf16x8*>(dst + (size_t)(nt * 64 + n) * K + kt * 128 + kc) = o;
        }
        return;
    }

    // ---------------- gemm1 ----------------
    int flat = blockIdx.x;
    int wg = (flat & 7) * (G1_NWG / 8) + (flat >> 3);   // T1 (448 % 8 == 0)
    int by = wg & 3;
    int bxg = wg >> 2;

    int g, rb;
    if (bxg < NEXP * 5) { g = bxg / 5; rb = bxg % 5; }
    else { g = NEXP; rb = bxg - NEXP * 5; }
    int Mg = (g < NEXP) ? counts_cap[g] : N_TOK;
    int m0 = rb * 256;
    if (m0 >= Mg) return;
    const ushort_t* Bt = (g < NEXP) ? (w1t + (size_t)g * DIM * FDIM) : sw1t;
    int n0 = by * 128;

    const ushort_t* asrc[2];
    const ushort_t* bsrc;
#pragma unroll
    for (int i = 0; i < 2; ++i) {
        int s = t + i * 512;
        int lr = ((s >> 3) << 1) | ((s >> 2) & 1);
        int qq = (s & 3) ^ ((s >> 3) & 3);
        int row = m0 + lr;
        const ushort_t* base;
        if (g < NEXP) {
            int tok = (row < Mg) ? slot_token[g * CAP + row] : 0;
            if ((unsigned)tok >= N_TOK) tok = 0;   // poison guard
            base = x_bf + (size_t)tok * DIM;
        } else {
            base = x_bf + (size_t)row * DIM;
        }
        asrc[i] = base + qq * 8;
    }
    {
        int s = t;
        int lr = ((s >> 3) << 1) | ((s >> 2) & 1);
        int qq = (s & 3) ^ ((s >> 3) & 3);
        bsrc = Bt + (size_t)(n0 + lr) * DIM + qq * 8;
    }

    int lane = t & 63;
    int w = t >> 6;
    int wm = (w & 3) * 64, wn = (w >> 2) * 64;
    int l15 = lane & 15, q = lane >> 4;

    int aoff[4], boff[4];
#pragma unroll
    for (int m = 0; m < 4; ++m) aoff[m] = swz_addr16(wm + m * 16 + l15, q) << 3;
#pragma unroll
    for (int n = 0; n < 4; ++n) boff[n] = swz_addr16(wn + n * 16 + l15, q) << 3;

    f32x4 acc[4][4];
#pragma unroll
    for (int m = 0; m < 4; ++m)
#pragma unroll
        for (int n = 0; n < 4; ++n) acc[m][n] = (f32x4){0.f, 0.f, 0.f, 0.f};

    auto STAGE = [&](int buf, int koff) {
        gload16(asrc[0] + koff, &sm.g.As[buf][t * 8]);
        gload16(asrc[1] + koff, &sm.g.As[buf][t * 8 + 4096]);
        gload16(bsrc + koff, &sm.g.Bs[buf][t * 8]);
    };

    const int NSTEP = DIM / 32;   // 32
    STAGE(0, 0);
    STAGE(1, 32);
    asm volatile("s_waitcnt vmcnt(3)" ::: "memory");
    __builtin_amdgcn_s_barrier();
    asm volatile("" ::: "memory");

    int cur = 0, b2 = 2;
    for (int kt = 0; kt < NSTEP; ++kt) {
        if (kt + 2 < NSTEP) STAGE(b2, (kt + 2) * 32);
        const ushort_t* asb = &sm.g.As[cur][0];
        const ushort_t* bsb = &sm.g.Bs[cur][0];
        bf16x8 af[4], bfr[4];
#pragma unroll
        for (int m = 0; m < 4; ++m)
            af[m] = *reinterpret_cast<const bf16x8*>(asb + aoff[m]);
#pragma unroll
        for (int n = 0; n < 4; ++n)
            bfr[n] = *reinterpret_cast<const bf16x8*>(bsb + boff[n]);
        __builtin_amdgcn_s_setprio(1);
#pragma unroll
        for (int m = 0; m < 4; ++m)
#pragma unroll
            for (int n = 0; n < 4; ++n)
                acc[m][n] = __builtin_amdgcn_mfma_f32_16x16x32_bf16(
                    af[m], bfr[n], acc[m][n], 0, 0, 0);
        __builtin_amdgcn_s_setprio(0);
        if (kt + 1 < NSTEP) {
            if (kt + 2 < NSTEP) asm volatile("s_waitcnt vmcnt(3)" ::: "memory");
            else                asm volatile("s_waitcnt vmcnt(0)" ::: "memory");
            __builtin_amdgcn_s_barrier();
            asm volatile("" ::: "memory");
        }
        cur = (cur == 2) ? 0 : cur + 1;
        b2  = (b2 == 2) ? 0 : b2 + 1;
    }

    size_t obase = ((g < NEXP) ? (size_t)g * CAP : (size_t)ECAP) + m0;
#pragma unroll
    for (int m = 0; m < 4; ++m) {
#pragma unroll
        for (int r = 0; r < 4; ++r) {
            int grow = wm + m * 16 + q * 4 + r;
            ushort_t* orow = h_buf + (obase + grow) * FDIM + n0 + wn + l15;
#pragma unroll
            for (int n = 0; n < 4; ++n)
                orow[n * 16] = f2b(gelu_fast(acc[m][n][r]));
        }
    }
}

// ================= MFMA grouped GEMM 2: out = H @ W2 =================
#define G2_NWG (G1_GX * (DIM / 128))        /* 896 */
__global__ __launch_bounds__(512) void gemm2_mfma(
    const ushort_t* __restrict__ h_buf,     // [TOTROW][FDIM] bf16
    const ushort_t* __restrict__ w2t,       // [16][DIM][FDIM] bf16 n-major
    const ushort_t* __restrict__ sw2t,      // [DIM][FDIM]
    const int* __restrict__ counts_cap,
    const float* __restrict__ g_shared,
    ushort_t* __restrict__ out_buf,         // [ECAP][DIM] bf16
    ushort_t* __restrict__ sh_out)          // [N_TOK][DIM] bf16 (x_bf reuse)
{
    __shared__ ushort_t As[2][256 * 32];
    __shared__ ushort_t Bs[2][128 * 32];

    int flat = blockIdx.x;
    int wg = (flat & 7) * (G2_NWG / 8) + (flat >> 3);
    int by = wg & 7;
    int bxg = wg >> 3;

    int g, rb;
    if (bxg < NEXP * 5) { g = bxg / 5; rb = bxg % 5; }
    else { g = NEXP; rb = bxg - NEXP * 5; }
    int Mg = (g < NEXP) ? counts_cap[g] : N_TOK;
    int m0 = rb * 256;
    if (m0 >= Mg) return;
    size_t abase = ((g < NEXP) ? (size_t)g * CAP : (size_t)ECAP) + m0;
    const ushort_t* Bt = (g < NEXP) ? (w2t + (size_t)g * FDIM * DIM) : sw2t;
    int n0 = by * 128;
    int t = threadIdx.x;

    const ushort_t* asrc[2];
    const ushort_t* bsrc;
#pragma unroll
    for (int i = 0; i < 2; ++i) {
        int s = t + i * 512;
        int lr = ((s >> 3) << 1) | ((s >> 2) & 1);
        int qq = (s & 3) ^ ((s >> 3) & 3);
        asrc[i] = h_buf + (abase + lr) * FDIM + qq * 8;
    }
    {
        int s = t;
        int lr = ((s >> 3) << 1) | ((s >> 2) & 1);
        int qq = (s & 3) ^ ((s >> 3) & 3);
        bsrc = Bt + (size_t)(n0 + lr) * FDIM + qq * 8;
    }

    int lane = t & 63;
    int w = t >> 6;
    int wm = (w & 3) * 64, wn = (w >> 2) * 64;
    int l15 = lane & 15, q = lane >> 4;

    int aoff[4], boff[4];
#pragma unroll
    for (int m = 0; m < 4; ++m) aoff[m] = swz_addr16(wm + m * 16 + l15, q) << 3;
#pragma unroll
    for (int n = 0; n < 4; ++n) boff[n] = swz_addr16(wn + n * 16 + l15, q) << 3;

    f32x4 acc[4][4];
#pragma unroll
    for (int m = 0; m < 4; ++m)
#pragma unroll
        for (int n = 0; n < 4; ++n) acc[m][n] = (f32x4){0.f, 0.f, 0.f, 0.f};

    auto STAGE = [&](int buf, int koff) {
        gload16(asrc[0] + koff, &As[buf][t * 8]);
        gload16(asrc[1] + koff, &As[buf][t * 8 + 4096]);
        gload16(bsrc + koff, &Bs[buf][t * 8]);
    };

    const int NSTEP = FDIM / 32;  // 16
    STAGE(0, 0);
    __syncthreads();

    int cur = 0;
    for (int kt = 0; kt < NSTEP; ++kt) {
        if (kt + 1 < NSTEP) STAGE(cur ^ 1, (kt + 1) * 32);
        const ushort_t* asb = &As[cur][0];
        const ushort_t* bsb = &Bs[cur][0];
        bf16x8 af[4], bfr[4];
#pragma unroll
        for (int m = 0; m < 4; ++m)
            af[m] = *reinterpret_cast<const bf16x8*>(asb + aoff[m]);
#pragma unroll
        for (int n = 0; n < 4; ++n)
            bfr[n] = *reinterpret_cast<const bf16x8*>(bsb + boff[n]);
        __builtin_amdgcn_s_setprio(1);
#pragma unroll
        for (int m = 0; m < 4; ++m)
#pragma unroll
            for (int n = 0; n < 4; ++n)
                acc[m][n] = __builtin_amdgcn_mfma_f32_16x16x32_bf16(
                    af[m], bfr[n], acc[m][n], 0, 0, 0);
        __builtin_amdgcn_s_setprio(0);
        __syncthreads();
        cur ^= 1;
    }

    if (g < NEXP) {
#pragma unroll
        for (int m = 0; m < 4; ++m) {
#pragma unroll
            for (int r = 0; r < 4; ++r) {
                int grow = wm + m * 16 + q * 4 + r;
                ushort_t* orow = out_buf + (abase + grow) * DIM + n0 + wn + l15;
#pragma unroll
                for (int n = 0; n < 4; ++n)
                    orow[n * 16] = f2b(acc[m][n][r]);
            }
        }
    } else {
#pragma unroll
        for (int m = 0; m < 4; ++m) {
#pragma unroll
            for (int r = 0; r < 4; ++r) {
                int tok = m0 + wm + m * 16 + q * 4 + r;
                float gs = g_shared[tok];
                ushort_t* orow = sh_out + (size_t)tok * DIM + n0 + wn + l15;
#pragma unroll
                for (int n = 0; n < 4; ++n)
                    orow[n * 16] = f2b(gs * acc[m][n][r]);
            }
        }
    }
}

// ---------------- combine: y = sh_out + sum(gate * expert_out), write-only ----------------
__global__ __launch_bounds__(256) void combine_kernel(
    const ushort_t* __restrict__ out_buf, const ushort_t* __restrict__ sh_out,
    const int* __restrict__ route_slot, const float* __restrict__ topk_val,
    float* __restrict__ y)
{
    int token = blockIdx.x;
    int c = threadIdx.x * 4;
    ushort4 sv = *reinterpret_cast<const ushort4*>(sh_out + (size_t)token * DIM + c);
    float y0 = bf2f(sv.x), y1 = bf2f(sv.y), y2 = bf2f(sv.z), y3 = bf2f(sv.w);
#pragma unroll
    for (int k = 0; k < 2; ++k) {
        int s = route_slot[2 * token + k];
        if (s >= 0) {
            float gate = topk_val[2 * token + k];
            ushort4 rv = *reinterpret_cast<const ushort4*>(out_buf + (size_t)s * DIM + c);
            y0 += gate * bf2f(rv.x); y1 += gate * bf2f(rv.y);
            y2 += gate * bf2f(rv.z); y3 += gate * bf2f(rv.w);
        }
    }
    float4 o; o.x = y0; o.y = y1; o.z = y2; o.w = y3;
    *reinterpret_cast<float4*>(y + (size_t)token * DIM + c) = o;
}

extern "C" void kernel_launch(void* const* d_in, const int* in_sizes, int n_in,
                              void* d_out, int out_size, void* d_ws, size_t ws_size,
                              hipStream_t stream) {
    const float* x   = (const float*)d_in[0];
    const float* rw  = (const float*)d_in[1];
    const float* sgw = (const float*)d_in[2];
    const float* w1  = (const float*)d_in[3];
    const float* w2  = (const float*)d_in[4];
    const float* sw1 = (const float*)d_in[5];
    const float* sw2 = (const float*)d_in[6];
    float* y = (float*)d_out;
    float* out_tail = y + (size_t)N_TOK * DIM;

    size_t off = 0;
    char* wsb = (char*)d_ws;
    auto alloc = [&](size_t bytes) -> void* {
        void* p = wsb + off;
        off += (bytes + 255) & ~(size_t)255;
        return p;
    };
    float*    scores     = (float*)alloc((size_t)N_TOK * NEXP * 4);
    int*      topk_idx   = (int*)alloc((size_t)NROUTE * 4);
    float*    topk_val   = (float*)alloc((size_t)NROUTE * 4);
    float*    g_shared   = (float*)alloc((size_t)N_TOK * 4);
    int*      chunk_hist = (int*)alloc((size_t)NCHUNK * NEXP * 4);
    int*      chunk_off  = (int*)alloc((size_t)NCHUNK * NEXP * 4);
    int*      counts_cap = (int*)alloc((size_t)NEXP * 4);
    int*      route_slot = (int*)alloc((size_t)NROUTE * 4);
    int*      slot_token = (int*)alloc((size_t)ECAP * 4);
    ushort_t* out_buf    = (ushort_t*)alloc((size_t)ECAP * DIM * 2);
    // x_bf [N_TOK][DIM] reused as sh_out after gemm1 (x_bf dead post-gemm1).
    ushort_t* x_bf       = (ushort_t*)alloc((size_t)N_TOK * DIM * 2);
    ushort_t* sh_out     = x_bf;
    ushort_t* w1t        = (ushort_t*)alloc((size_t)NEXP * DIM * FDIM * 2);
    ushort_t* w2t        = (ushort_t*)alloc((size_t)NEXP * DIM * FDIM * 2);
    ushort_t* sw1t       = (ushort_t*)alloc((size_t)DIM * FDIM * 2);
    ushort_t* sw2t       = (ushort_t*)alloc((size_t)DIM * FDIM * 2);
    ushort_t* h_buf      = (ushort_t*)alloc((size_t)TOTROW * FDIM * 2);
    (void)ws_size; (void)in_sizes; (void)n_in; (void)out_size;

    prep_kernel<<<PREP_NWG, 256, 0, stream>>>(
        x, rw, sgw, w1, sw1,
        scores, topk_idx, topk_val, g_shared, x_bf, w1t, sw1t);
    stats_kernel<<<NCHUNK + NEXP, 256, 0, stream>>>(topk_idx, chunk_hist, scores, out_tail);
    scan_kernel<<<1, 64, 0, stream>>>(chunk_hist, chunk_off, counts_cap, out_tail);
    assign_kernel<<<NCHUNK, 256, 0, stream>>>(topk_idx, topk_val, chunk_off, route_slot, slot_token);

    gemm1x_kernel<<<G1X_NWG, 512, 0, stream>>>(
        x_bf, w1t, sw1t, slot_token, counts_cap, h_buf, w2, sw2, w2t, sw2t);
    gemm2_mfma<<<G2_NWG, 512, 0, stream>>>(h_buf, w2t, sw2t, counts_cap, g_shared, out_buf, sh_out);

    combine_kernel<<<N_TOK, 256, 0, stream>>>(out_buf, sh_out, route_slot, topk_val, y);
}